// Round 1
// baseline (6645.387 us; speedup 1.0000x reference)
//
#include <hip/hip_runtime.h>
#include <hip/hip_bf16.h>
#include <math.h>
#include <stddef.h>

#define NN 8192
#define FF 128
#define HH 512
#define DDIM 256
#define EE 131072
#define ET (2*EE + NN)     // 270336 edges after symmetrize + self loops
#define FEPS 1e-8f

// ======================= stage 0: global mean/std normalize =======================
__global__ void k_reduce(const float* __restrict__ x, int n, double* __restrict__ out) {
  __shared__ double s1[256], s2[256];
  double a = 0.0, b = 0.0;
  for (int i = blockIdx.x * blockDim.x + threadIdx.x; i < n; i += gridDim.x * blockDim.x) {
    double v = (double)x[i];
    a += v; b += v * v;
  }
  s1[threadIdx.x] = a; s2[threadIdx.x] = b;
  __syncthreads();
  for (int w = 128; w > 0; w >>= 1) {
    if (threadIdx.x < w) { s1[threadIdx.x] += s1[threadIdx.x + w]; s2[threadIdx.x] += s2[threadIdx.x + w]; }
    __syncthreads();
  }
  if (threadIdx.x == 0) { atomicAdd(&out[0], s1[0]); atomicAdd(&out[1], s2[0]); }
}

__global__ void k_normalize(const float* __restrict__ x, float* __restrict__ y, int n,
                            const double* __restrict__ s) {
  double mean = s[0] / (double)n;
  double var = (s[1] - (double)n * mean * mean) / (double)(n - 1);  // ddof=1
  float mu = (float)mean;
  float inv = (float)(1.0 / sqrt(var));
  for (int i = blockIdx.x * blockDim.x + threadIdx.x; i < n; i += gridDim.x * blockDim.x)
    y[i] = (x[i] - mu) * inv;
}

// ======================= GAT: CSR build =======================
// edge t: src[t] = t<2E ? ei[t] : t-2E ;  dst[t] = t<E ? ei[E+t] : (t<2E ? ei[t-E] : t-2E)
__global__ void k_hist(const int* __restrict__ ei, int* __restrict__ deg) {
  int t = blockIdx.x * blockDim.x + threadIdx.x;
  if (t >= ET) return;
  int dst = (t < EE) ? ei[EE + t] : ((t < 2*EE) ? ei[t - EE] : (t - 2*EE));
  atomicAdd(&deg[dst], 1);
}

__global__ void k_scan(const int* __restrict__ deg, int* __restrict__ offs, int* __restrict__ cursor) {
  __shared__ int ts[256];
  int tid = threadIdx.x;
  int loc[32];
  int s = 0;
  #pragma unroll
  for (int i = 0; i < 32; ++i) { loc[i] = s; s += deg[tid * 32 + i]; }
  ts[tid] = s;
  __syncthreads();
  for (int off = 1; off < 256; off <<= 1) {
    int v = (tid >= off) ? ts[tid - off] : 0;
    __syncthreads();
    ts[tid] += v;
    __syncthreads();
  }
  int pre = ts[tid] - s;   // exclusive prefix for this thread's chunk
  #pragma unroll
  for (int i = 0; i < 32; ++i) {
    int o = pre + loc[i];
    offs[tid * 32 + i] = o;
    cursor[tid * 32 + i] = o;
  }
  if (tid == 255) offs[NN] = ts[255];
}

__global__ void k_scatter(const int* __restrict__ ei, int* __restrict__ cursor, int* __restrict__ srcs) {
  int t = blockIdx.x * blockDim.x + threadIdx.x;
  if (t >= ET) return;
  int src = (t < 2*EE) ? ei[t] : (t - 2*EE);
  int dst = (t < EE) ? ei[EE + t] : ((t < 2*EE) ? ei[t - EE] : (t - 2*EE));
  int pos = atomicAdd(&cursor[dst], 1);
  srcs[pos] = src;
}

// ======================= simple tiled f32 GEMM: C[M,N] = A[M,K] @ B[K,N] =======================
__global__ __launch_bounds__(256) void k_gemm(const float* __restrict__ A, const float* __restrict__ B,
                                              float* __restrict__ C, int M, int K, int N) {
  __shared__ float As[32][33];
  __shared__ float Bs[32][33];
  int tx = threadIdx.x & 15, ty = threadIdx.x >> 4;
  int r0 = blockIdx.y * 32, c0 = blockIdx.x * 32;
  float acc00 = 0.f, acc01 = 0.f, acc10 = 0.f, acc11 = 0.f;
  for (int k0 = 0; k0 < K; k0 += 32) {
    for (int l = threadIdx.x; l < 32 * 32; l += 256) {
      int r = l >> 5, c = l & 31;
      As[r][c] = A[(size_t)(r0 + r) * K + k0 + c];
      Bs[r][c] = B[(size_t)(k0 + r) * N + c0 + c];
    }
    __syncthreads();
    #pragma unroll
    for (int k = 0; k < 32; ++k) {
      float a0 = As[2 * ty][k], a1 = As[2 * ty + 1][k];
      float b0 = Bs[k][2 * tx], b1 = Bs[k][2 * tx + 1];
      acc00 += a0 * b0; acc01 += a0 * b1; acc10 += a1 * b0; acc11 += a1 * b1;
    }
    __syncthreads();
  }
  C[(size_t)(r0 + 2 * ty) * N + c0 + 2 * tx] = acc00;
  C[(size_t)(r0 + 2 * ty) * N + c0 + 2 * tx + 1] = acc01;
  C[(size_t)(r0 + 2 * ty + 1) * N + c0 + 2 * tx] = acc10;
  C[(size_t)(r0 + 2 * ty + 1) * N + c0 + 2 * tx + 1] = acc11;
}

// ======================= GAT: attention =======================
__global__ void k_node_dots(const float* __restrict__ H, const float* __restrict__ as_,
                            const float* __restrict__ ad_, float* __restrict__ hs,
                            float* __restrict__ hd, int D) {
  int wid = (blockIdx.x * blockDim.x + threadIdx.x) >> 6;
  int lane = threadIdx.x & 63;
  if (wid >= NN) return;
  float s = 0.f, d = 0.f;
  for (int c = lane; c < D; c += 64) {
    float h = H[(size_t)wid * D + c];
    s += h * as_[c]; d += h * ad_[c];
  }
  #pragma unroll
  for (int o = 32; o > 0; o >>= 1) { s += __shfl_xor(s, o); d += __shfl_xor(d, o); }
  if (!lane) { hs[wid] = s; hd[wid] = d; }
}

__global__ void k_alpha(const int* __restrict__ offs, const int* __restrict__ srcs,
                        const float* __restrict__ hs, const float* __restrict__ hd,
                        float* __restrict__ alpha) {
  int wid = (blockIdx.x * blockDim.x + threadIdx.x) >> 6;
  int lane = threadIdx.x & 63;
  if (wid >= NN) return;
  int b = offs[wid], e = offs[wid + 1];
  float hdn = hd[wid];
  float m = -3.4e38f;
  for (int p = b + lane; p < e; p += 64) {
    float v = hs[srcs[p]] + hdn;
    v = v > 0.f ? v : 0.2f * v;        // leaky_relu 0.2
    m = fmaxf(m, v);
  }
  #pragma unroll
  for (int o = 32; o > 0; o >>= 1) m = fmaxf(m, __shfl_xor(m, o));
  float den = 0.f;
  for (int p = b + lane; p < e; p += 64) {
    float v = hs[srcs[p]] + hdn;
    v = v > 0.f ? v : 0.2f * v;
    float ex = expf(v - m);
    alpha[p] = ex;
    den += ex;
  }
  #pragma unroll
  for (int o = 32; o > 0; o >>= 1) den += __shfl_xor(den, o);
  float sc = 1.f / (den + 1e-16f);
  for (int p = b + lane; p < e; p += 64) alpha[p] *= sc;
}

__global__ void k_aggregate(const int* __restrict__ offs, const int* __restrict__ srcs,
                            const float* __restrict__ alpha, const float* __restrict__ H,
                            float* __restrict__ out, int D, int elu) {
  int n = blockIdx.x;
  int b = offs[n], e = offs[n + 1];
  for (int d = threadIdx.x; d < D; d += 256) {
    float acc = 0.f;
    for (int p = b; p < e; ++p)
      acc += alpha[p] * H[(size_t)srcs[p] * D + d];
    if (elu) acc = acc > 0.f ? acc : (expf(acc) - 1.f);
    out[(size_t)n * D + d] = acc;
  }
}

// ======================= mutual: norms, C row/col sums, fused apply =======================
__global__ void k_rownorms(const float* __restrict__ h, float* __restrict__ nr) {
  int wid = (blockIdx.x * blockDim.x + threadIdx.x) >> 6;
  int lane = threadIdx.x & 63;
  if (wid >= NN) return;
  float a = 0.f;
  for (int c = lane; c < DDIM; c += 64) { float v = h[(size_t)wid * DDIM + c]; a += v * v; }
  #pragma unroll
  for (int o = 32; o > 0; o >>= 1) a += __shfl_xor(a, o);
  if (!lane) nr[wid] = sqrtf(a);
}

// R[i] += sum_j cos(i,j); S[j] += sum_i cos(i,j);  cos = dot(A_i,B_j)/max(na_i*nb_j,eps)
__global__ __launch_bounds__(256) void k_mutual_sums(
    const float* __restrict__ A, const float* __restrict__ B,
    const float* __restrict__ na, const float* __restrict__ nb,
    float* __restrict__ R, float* __restrict__ S) {
  __shared__ float As[64][65];   // [k][i]
  __shared__ float Bs[64][65];   // [k][j]
  __shared__ float rs[64], cs[64];
  int i0 = blockIdx.y * 64, j0 = blockIdx.x * 64;
  int tx = threadIdx.x & 15, ty = threadIdx.x >> 4;
  float acc[4][4];
  #pragma unroll
  for (int u = 0; u < 4; ++u)
    #pragma unroll
    for (int vv = 0; vv < 4; ++vv) acc[u][vv] = 0.f;
  for (int k0 = 0; k0 < DDIM; k0 += 64) {
    __syncthreads();
    for (int l = threadIdx.x; l < 64 * 64; l += 256) {
      int rr = l >> 6, kk = l & 63;
      As[kk][rr] = A[(size_t)(i0 + rr) * DDIM + k0 + kk];
      Bs[kk][rr] = B[(size_t)(j0 + rr) * DDIM + k0 + kk];
    }
    __syncthreads();
    #pragma unroll 4
    for (int k = 0; k < 64; ++k) {
      float a[4], b[4];
      #pragma unroll
      for (int u = 0; u < 4; ++u) a[u] = As[k][4 * tx + u];
      #pragma unroll
      for (int vv = 0; vv < 4; ++vv) b[vv] = Bs[k][4 * ty + vv];
      #pragma unroll
      for (int u = 0; u < 4; ++u)
        #pragma unroll
        for (int vv = 0; vv < 4; ++vv) acc[u][vv] += a[u] * b[vv];
    }
  }
  if (threadIdx.x < 64) { rs[threadIdx.x] = 0.f; cs[threadIdx.x] = 0.f; }
  __syncthreads();
  float nai[4], nbj[4];
  #pragma unroll
  for (int u = 0; u < 4; ++u) nai[u] = na[i0 + 4 * tx + u];
  #pragma unroll
  for (int vv = 0; vv < 4; ++vv) nbj[vv] = nb[j0 + 4 * ty + vv];
  float rp[4] = {0, 0, 0, 0}, cp[4] = {0, 0, 0, 0};
  #pragma unroll
  for (int u = 0; u < 4; ++u)
    #pragma unroll
    for (int vv = 0; vv < 4; ++vv) {
      float cv = acc[u][vv] / fmaxf(nai[u] * nbj[vv], FEPS);
      rp[u] += cv; cp[vv] += cv;
    }
  #pragma unroll
  for (int u = 0; u < 4; ++u) atomicAdd(&rs[4 * tx + u], rp[u]);
  #pragma unroll
  for (int vv = 0; vv < 4; ++vv) atomicAdd(&cs[4 * ty + vv], cp[vv]);
  __syncthreads();
  if (threadIdx.x < 64) {
    atomicAdd(&R[i0 + threadIdx.x], rs[threadIdx.x]);
    atomicAdd(&S[j0 + threadIdx.x], cs[threadIdx.x]);
  }
}

// out[i,:] += sum_j ( dot(A_i,B_j)/max(na_i*nb_j,eps)/w[j] ) * B[j,:]
__global__ __launch_bounds__(256) void k_mutual_apply(
    const float* __restrict__ A, const float* __restrict__ B,
    const float* __restrict__ na, const float* __restrict__ nb,
    const float* __restrict__ w, float* __restrict__ out) {
  __shared__ __align__(16) float At[256][33];  // At[k][i]
  __shared__ __align__(16) float Bt[256][36];  // Bt[k][j]; row stride 144B (16B aligned)
  __shared__ float st[32][33];
  int i0 = blockIdx.y * 32;
  int il = threadIdx.x & 31;
  int grp = threadIdx.x >> 5;    // 0..7
  for (int l = threadIdx.x; l < 32 * 256; l += 256) {
    int ii = l >> 8, kk = l & 255;
    At[kk][ii] = A[(size_t)(i0 + ii) * DDIM + kk];
  }
  float nai = na[i0 + il];
  float acc[32];
  #pragma unroll
  for (int t = 0; t < 32; ++t) acc[t] = 0.f;
  int jt0 = blockIdx.x * (NN / 2 / 32);       // 2 j-chunks of 128 tiles
  for (int jt = jt0; jt < jt0 + NN / 2 / 32; ++jt) {
    int j0 = jt * 32;
    __syncthreads();   // protect Bt from previous phase-B readers (covers At stage on iter 0)
    for (int l = threadIdx.x; l < 32 * 256; l += 256) {
      int jj = l >> 8, kk = l & 255;
      Bt[kk][jj] = B[(size_t)(j0 + jj) * DDIM + kk];
    }
    __syncthreads();
    // phase A: scores s[il][4*grp+q]
    float s0 = 0.f, s1 = 0.f, s2 = 0.f, s3 = 0.f;
    #pragma unroll 4
    for (int k = 0; k < 256; ++k) {
      float a = At[k][il];
      s0 += a * Bt[k][4 * grp + 0];
      s1 += a * Bt[k][4 * grp + 1];
      s2 += a * Bt[k][4 * grp + 2];
      s3 += a * Bt[k][4 * grp + 3];
    }
    {
      int j = j0 + 4 * grp;
      st[il][4 * grp + 0] = s0 / fmaxf(nai * nb[j + 0], FEPS) / w[j + 0];
      st[il][4 * grp + 1] = s1 / fmaxf(nai * nb[j + 1], FEPS) / w[j + 1];
      st[il][4 * grp + 2] = s2 / fmaxf(nai * nb[j + 2], FEPS) / w[j + 2];
      st[il][4 * grp + 3] = s3 / fmaxf(nai * nb[j + 3], FEPS) / w[j + 3];
    }
    __syncthreads();
    // phase B: PV — thread (il, grp) owns d = grp*32 + 0..31
    float svr[32];
    #pragma unroll
    for (int j = 0; j < 32; ++j) svr[j] = st[il][j];
    #pragma unroll
    for (int dd = 0; dd < 32; ++dd) {
      const float4* brow = (const float4*)(&Bt[grp * 32 + dd][0]);
      float t0 = 0.f;
      #pragma unroll
      for (int j4 = 0; j4 < 8; ++j4) {
        float4 bv = brow[j4];
        t0 += svr[4 * j4 + 0] * bv.x + svr[4 * j4 + 1] * bv.y +
              svr[4 * j4 + 2] * bv.z + svr[4 * j4 + 3] * bv.w;
      }
      acc[dd] += t0;
    }
  }
  #pragma unroll
  for (int dd = 0; dd < 32; ++dd)
    atomicAdd(&out[(size_t)(i0 + il) * DDIM + grp * 32 + dd], acc[dd]);
}

// ======================= match: out = ((x*y)@W2) / max(sqrt((x*x)@W2)*sqrt((y*y)@W2), eps) =======================
__global__ __launch_bounds__(256) void k_match(const float* __restrict__ X, const float* __restrict__ Y,
                                               const float* __restrict__ W2, float* __restrict__ out,
                                               int nout, int bx, int by) {
  __shared__ float u[4][256], p[4][256], q[4][256];
  int nl = threadIdx.x >> 6;
  int ml = threadIdx.x & 63;
  int n = blockIdx.y * 4 + nl;
  int m = blockIdx.x * 64 + ml;
  for (int l = threadIdx.x; l < 4 * 256; l += 256) {
    int rr = l >> 8, dd = l & 255;
    int nn = blockIdx.y * 4 + rr;
    if (nn < nout) {
      float xv = X[(size_t)(bx ? 0 : nn) * DDIM + dd];
      float yv = Y[(size_t)(by ? 0 : nn) * DDIM + dd];
      u[rr][dd] = xv * yv; p[rr][dd] = xv * xv; q[rr][dd] = yv * yv;
    }
  }
  __syncthreads();
  if (n >= nout) return;
  float a = 0.f, b = 0.f, c = 0.f;
  #pragma unroll 4
  for (int d = 0; d < 256; ++d) {
    float wv = W2[(size_t)d * DDIM + m];
    a += u[nl][d] * wv; b += p[nl][d] * wv; c += q[nl][d] * wv;
  }
  out[(size_t)n * DDIM + m] = a / fmaxf(sqrtf(b) * sqrtf(c), FEPS);
}

__global__ void k_w2(const float* __restrict__ Wm, float* __restrict__ W2, int n) {
  int i = blockIdx.x * blockDim.x + threadIdx.x;
  if (i < n) { float v = Wm[i]; W2[i] = v * v; }
}

// ======================= readout =======================
__global__ void k_colsum(const float* __restrict__ h, const float* __restrict__ wt,
                         float* __restrict__ out) {
  int d = threadIdx.x;
  int r0 = blockIdx.x * 32;
  float acc = 0.f;
  for (int r = 0; r < 32; ++r) {
    float v = h[(size_t)(r0 + r) * DDIM + d];
    if (wt) v *= wt[r0 + r];
    acc += v;
  }
  atomicAdd(&out[d], acc);
}

__global__ void k_gvec(const float* __restrict__ mu, const float* __restrict__ Wr,
                       float* __restrict__ g) {
  __shared__ float ls[256];
  int m = threadIdx.x;
  ls[m] = mu[m] * (1.f / (float)NN);
  __syncthreads();
  float acc = 0.f;
  #pragma unroll 4
  for (int d = 0; d < 256; ++d) acc += ls[d] * Wr[(size_t)d * DDIM + m];
  g[m] = tanhf(acc);
}

__global__ void k_svec(const float* __restrict__ h, const float* __restrict__ g,
                       float* __restrict__ s) {
  int wid = (blockIdx.x * blockDim.x + threadIdx.x) >> 6;
  int lane = threadIdx.x & 63;
  if (wid >= NN) return;
  float acc = 0.f;
  for (int c = lane; c < DDIM; c += 64) acc += h[(size_t)wid * DDIM + c] * g[c];
  #pragma unroll
  for (int o = 32; o > 0; o >>= 1) acc += __shfl_xor(acc, o);
  if (!lane) s[wid] = 1.f / (1.f + expf(-acc));
}

// ======================= MLP =======================
__global__ void k_mlp(const float* __restrict__ v, const float* __restrict__ w,
                      const float* __restrict__ b, float* __restrict__ out,
                      int K, int M, int act) {
  __shared__ float lv[2048];
  for (int i = threadIdx.x; i < K; i += blockDim.x) lv[i] = v[i];
  __syncthreads();
  int m = blockIdx.x * blockDim.x + threadIdx.x;
  if (m >= M) return;
  float acc = b[m];
  for (int k = 0; k < K; ++k) acc += lv[k] * w[(size_t)k * M + m];
  if (act == 1) acc = fmaxf(acc, 0.f);
  out[m] = acc;
}

__global__ void k_final(const float* __restrict__ l3, const float* __restrict__ w4,
                        const float* __restrict__ b4, const int* __restrict__ label,
                        float* __restrict__ out) {
  __shared__ float ls[128];
  int t = threadIdx.x;
  ls[t] = l3[t] * w4[t];
  __syncthreads();
  for (int w = 64; w > 0; w >>= 1) { if (t < w) ls[t] += ls[t + w]; __syncthreads(); }
  if (t == 0) {
    float z = 1.f / (1.f + expf(-(ls[0] + b4[0])));
    out[0] = z;
    float lb = (float)label[0];
    out[1] = lb;
    out[2] = expf(-lb);
  }
}

// ======================= host =======================
extern "C" void kernel_launch(void* const* d_in, const int* in_sizes, int n_in,
                              void* d_out, int out_size, void* d_ws, size_t ws_size,
                              hipStream_t stream) {
  (void)in_sizes; (void)n_in; (void)out_size;
  const float* x_s   = (const float*)d_in[0];
  const float* x_t   = (const float*)d_in[1];
  const int*   ei_s  = (const int*)d_in[2];
  const int*   ei_t  = (const int*)d_in[3];
  const int*   label = (const int*)d_in[4];
  const float* W_g1  = (const float*)d_in[5];
  const float* a1s   = (const float*)d_in[6];
  const float* a1d   = (const float*)d_in[7];
  const float* W_g2  = (const float*)d_in[8];
  const float* a2s   = (const float*)d_in[9];
  const float* a2d   = (const float*)d_in[10];
  const float* W_read  = (const float*)d_in[11];
  const float* W_match = (const float*)d_in[12];
  const float* w1 = (const float*)d_in[13]; const float* b1 = (const float*)d_in[14];
  const float* w2 = (const float*)d_in[15]; const float* b2 = (const float*)d_in[16];
  const float* w3 = (const float*)d_in[17]; const float* b3 = (const float*)d_in[18];
  const float* w4 = (const float*)d_in[19]; const float* b4 = (const float*)d_in[20];
  float* out = (float*)d_out;

  char* base = (char*)d_ws;
  size_t off = 0;
  auto alloc = [&](size_t bytes) -> void* {
    void* pp = base + off;
    off = (off + bytes + 255) & ~(size_t)255;
    return pp;
  };
  double* dsum = (double*)alloc(4 * sizeof(double));
  float* f1   = (float*)alloc((size_t)NN * FF * 4);
  float* f2   = (float*)alloc((size_t)NN * FF * 4);
  float* hbuf = (float*)alloc((size_t)NN * HH * 4);
  float* agg  = (float*)alloc((size_t)NN * HH * 4);
  float* h1   = (float*)alloc((size_t)NN * DDIM * 4);
  float* h2   = (float*)alloc((size_t)NN * DDIM * 4);
  float* h1m  = (float*)alloc((size_t)NN * DDIM * 4);
  float* h2m  = (float*)alloc((size_t)NN * DDIM * 4);
  float* mtmp = (float*)alloc((size_t)NN * DDIM * 4);
  float* alpha= (float*)alloc((size_t)ET * 4);
  int*   srcs = (int*)alloc((size_t)ET * 4);
  int*   deg  = (int*)alloc(NN * 4);
  int*   curs = (int*)alloc(NN * 4);
  int*   offs = (int*)alloc((NN + 1) * 4);
  float* nrm1 = (float*)alloc(NN * 4);
  float* nrm2 = (float*)alloc(NN * 4);
  float* Rr   = (float*)alloc(NN * 4);
  float* Ss   = (float*)alloc(NN * 4);
  float* hsb  = (float*)alloc(NN * 4);
  float* hdb  = (float*)alloc(NN * 4);
  float* sv   = (float*)alloc(NN * 4);
  float* mu   = (float*)alloc(DDIM * 4);
  float* gv   = (float*)alloc(DDIM * 4);
  float* W2   = (float*)alloc((size_t)DDIM * DDIM * 4);
  float* h1g  = (float*)alloc(DDIM * 4);
  float* h2g  = (float*)alloc(DDIM * 4);
  float* h1mg = (float*)alloc(DDIM * 4);
  float* h2mg = (float*)alloc(DDIM * 4);
  float* v    = (float*)alloc(2048 * 4);
  float* l1o  = (float*)alloc(512 * 4);
  float* l2o  = (float*)alloc(256 * 4);
  float* l3o  = (float*)alloc(128 * 4);
  if (off > ws_size) return;  // workspace too small — bail (will show as absmax failure)

  // ---- stage 0 ----
  hipMemsetAsync(dsum, 0, 4 * sizeof(double), stream);
  k_reduce<<<1024, 256, 0, stream>>>(x_s, NN * FF, dsum);
  k_reduce<<<1024, 256, 0, stream>>>(x_t, NN * FF, dsum + 2);
  k_normalize<<<1024, 256, 0, stream>>>(x_s, f1, NN * FF, dsum);
  k_normalize<<<1024, 256, 0, stream>>>(x_t, f2, NN * FF, dsum + 2);

  // ---- GAT ----
  auto run_gat = [&](const float* fin, const int* ei, float* hout) {
    hipMemsetAsync(deg, 0, NN * 4, stream);
    k_hist<<<dim3((ET + 255) / 256), 256, 0, stream>>>(ei, deg);
    k_scan<<<1, 256, 0, stream>>>(deg, offs, curs);
    k_scatter<<<dim3((ET + 255) / 256), 256, 0, stream>>>(ei, curs, srcs);
    k_gemm<<<dim3(HH / 32, NN / 32), 256, 0, stream>>>(fin, W_g1, hbuf, NN, FF, HH);
    k_node_dots<<<dim3(NN / 4), 256, 0, stream>>>(hbuf, a1s, a1d, hsb, hdb, HH);
    k_alpha<<<dim3(NN / 4), 256, 0, stream>>>(offs, srcs, hsb, hdb, alpha);
    k_aggregate<<<dim3(NN), 256, 0, stream>>>(offs, srcs, alpha, hbuf, agg, HH, 1);
    k_gemm<<<dim3(DDIM / 32, NN / 32), 256, 0, stream>>>(agg, W_g2, hbuf, NN, HH, DDIM);
    k_node_dots<<<dim3(NN / 4), 256, 0, stream>>>(hbuf, a2s, a2d, hsb, hdb, DDIM);
    k_alpha<<<dim3(NN / 4), 256, 0, stream>>>(offs, srcs, hsb, hdb, alpha);
    k_aggregate<<<dim3(NN), 256, 0, stream>>>(offs, srcs, alpha, hbuf, hout, DDIM, 0);
  };
  run_gat(f1, ei_s, h1);
  run_gat(f2, ei_t, h2);

  // ---- mutual ----
  k_rownorms<<<dim3(NN / 4), 256, 0, stream>>>(h1, nrm1);
  k_rownorms<<<dim3(NN / 4), 256, 0, stream>>>(h2, nrm2);
  hipMemsetAsync(Rr, 0, NN * 4, stream);
  hipMemsetAsync(Ss, 0, NN * 4, stream);
  k_mutual_sums<<<dim3(NN / 64, NN / 64), 256, 0, stream>>>(h1, h2, nrm1, nrm2, Rr, Ss);
  hipMemsetAsync(h1m, 0, (size_t)NN * DDIM * 4, stream);
  k_mutual_apply<<<dim3(2, NN / 32), 256, 0, stream>>>(h1, h2, nrm1, nrm2, Ss, h1m);
  hipMemsetAsync(h2m, 0, (size_t)NN * DDIM * 4, stream);
  k_mutual_apply<<<dim3(2, NN / 32), 256, 0, stream>>>(h2, h1, nrm2, nrm1, Rr, h2m);

  // ---- readouts ----
  auto readout = [&](const float* h, float* og) {
    hipMemsetAsync(mu, 0, DDIM * 4, stream);
    k_colsum<<<dim3(NN / 32), 256, 0, stream>>>(h, nullptr, mu);
    k_gvec<<<1, 256, 0, stream>>>(mu, W_read, gv);
    k_svec<<<dim3(NN / 4), 256, 0, stream>>>(h, gv, sv);
    hipMemsetAsync(og, 0, DDIM * 4, stream);
    k_colsum<<<dim3(NN / 32), 256, 0, stream>>>(h, sv, og);
  };
  readout(h1, h1g);
  readout(h2, h2g);
  readout(h1m, h1mg);
  readout(h2m, h2mg);

  k_w2<<<dim3((DDIM * DDIM + 255) / 256), 256, 0, stream>>>(W_match, W2, DDIM * DDIM);

  auto match = [&](const float* X, int bx, const float* Y, int by, float* o, int nout) {
    k_match<<<dim3(DDIM / 64, (nout + 3) / 4), 256, 0, stream>>>(X, Y, W2, o, nout, bx, by);
  };
  // z order: [miu1g, phi1g, psi1g, om1, miu2g, phi2g, psi2g, om2]
  match(h1, 0, h1m, 0, mtmp, NN);  readout(mtmp, v + 0);
  match(h1, 0, h1mg, 1, mtmp, NN); readout(mtmp, v + 256);
  match(h1g, 1, h1m, 0, mtmp, NN); readout(mtmp, v + 512);
  match(h1g, 1, h1mg, 1, v + 768, 1);
  match(h2, 0, h2m, 0, mtmp, NN);  readout(mtmp, v + 1024);
  match(h2, 0, h2mg, 1, mtmp, NN); readout(mtmp, v + 1280);
  match(h2g, 1, h2m, 0, mtmp, NN); readout(mtmp, v + 1536);
  match(h2g, 1, h2mg, 1, v + 1792, 1);

  // ---- MLP ----
  k_mlp<<<dim3(2), 256, 0, stream>>>(v, w1, b1, l1o, 2048, 512, 1);
  k_mlp<<<dim3(1), 256, 0, stream>>>(l1o, w2, b2, l2o, 512, 256, 1);
  k_mlp<<<dim3(1), 256, 0, stream>>>(l2o, w3, b3, l3o, 256, 128, 1);
  k_final<<<1, 128, 0, stream>>>(l3o, w4, b4, label, out);
}

// Round 2
// 1985.391 us; speedup vs baseline: 3.3471x; 3.3471x over previous
//
#include <hip/hip_runtime.h>
#include <hip/hip_bf16.h>
#include <math.h>
#include <stddef.h>

#define NN 8192
#define FF 128
#define HH 512
#define DDIM 256
#define EE 131072
#define ET (2*EE + NN)     // 270336 edges after symmetrize + self loops
#define FEPS 1e-8f

typedef float f32x4 __attribute__((ext_vector_type(4)));
typedef __bf16 bf16x8 __attribute__((ext_vector_type(8)));
typedef unsigned short u16;

static __device__ __forceinline__ u16 f2bf(float f) {
  union { float f; unsigned u; } v; v.f = f;
  return (u16)((v.u + 0x7fffu + ((v.u >> 16) & 1u)) >> 16);
}
static __device__ __forceinline__ float bf2f(u16 h) {
  union { unsigned u; float f; } v; v.u = ((unsigned)h) << 16;
  return v.f;
}
static __device__ __forceinline__ f32x4 mfma16(bf16x8 a, bf16x8 b, f32x4 c) {
  return __builtin_amdgcn_mfma_f32_16x16x32_bf16(a, b, c, 0, 0, 0);
}

// ======================= stage 0: global mean/std normalize =======================
__global__ void k_reduce(const float* __restrict__ x, int n, double* __restrict__ out) {
  __shared__ double s1[256], s2[256];
  double a = 0.0, b = 0.0;
  for (int i = blockIdx.x * blockDim.x + threadIdx.x; i < n; i += gridDim.x * blockDim.x) {
    double v = (double)x[i];
    a += v; b += v * v;
  }
  s1[threadIdx.x] = a; s2[threadIdx.x] = b;
  __syncthreads();
  for (int w = 128; w > 0; w >>= 1) {
    if (threadIdx.x < w) { s1[threadIdx.x] += s1[threadIdx.x + w]; s2[threadIdx.x] += s2[threadIdx.x + w]; }
    __syncthreads();
  }
  if (threadIdx.x == 0) { atomicAdd(&out[0], s1[0]); atomicAdd(&out[1], s2[0]); }
}

__global__ void k_normalize(const float* __restrict__ x, u16* __restrict__ y, int n,
                            const double* __restrict__ s) {
  double mean = s[0] / (double)n;
  double var = (s[1] - (double)n * mean * mean) / (double)(n - 1);  // ddof=1
  float mu = (float)mean;
  float inv = (float)(1.0 / sqrt(var));
  for (int i = blockIdx.x * blockDim.x + threadIdx.x; i < n; i += gridDim.x * blockDim.x)
    y[i] = f2bf((x[i] - mu) * inv);
}

// ======================= GAT: CSR build =======================
__global__ void k_hist(const int* __restrict__ ei, int* __restrict__ deg) {
  int t = blockIdx.x * blockDim.x + threadIdx.x;
  if (t >= ET) return;
  int dst = (t < EE) ? ei[EE + t] : ((t < 2*EE) ? ei[t - EE] : (t - 2*EE));
  atomicAdd(&deg[dst], 1);
}

__global__ void k_scan(const int* __restrict__ deg, int* __restrict__ offs, int* __restrict__ cursor) {
  __shared__ int ts[256];
  int tid = threadIdx.x;
  int loc[32];
  int s = 0;
  #pragma unroll
  for (int i = 0; i < 32; ++i) { loc[i] = s; s += deg[tid * 32 + i]; }
  ts[tid] = s;
  __syncthreads();
  for (int off = 1; off < 256; off <<= 1) {
    int v = (tid >= off) ? ts[tid - off] : 0;
    __syncthreads();
    ts[tid] += v;
    __syncthreads();
  }
  int pre = ts[tid] - s;
  #pragma unroll
  for (int i = 0; i < 32; ++i) {
    int o = pre + loc[i];
    offs[tid * 32 + i] = o;
    cursor[tid * 32 + i] = o;
  }
  if (tid == 255) offs[NN] = ts[255];
}

__global__ void k_scatter(const int* __restrict__ ei, int* __restrict__ cursor, int* __restrict__ srcs) {
  int t = blockIdx.x * blockDim.x + threadIdx.x;
  if (t >= ET) return;
  int src = (t < 2*EE) ? ei[t] : (t - 2*EE);
  int dst = (t < EE) ? ei[EE + t] : ((t < 2*EE) ? ei[t - EE] : (t - 2*EE));
  int pos = atomicAdd(&cursor[dst], 1);
  srcs[pos] = src;
}

// ======================= transpose f32 -> bf16 (optionally squared) =======================
__global__ __launch_bounds__(256) void k_tr_bf16(const float* __restrict__ src, u16* __restrict__ dst,
                                                 int R, int C, int sq) {
  __shared__ float T[32][33];
  int tx = threadIdx.x & 31, ty = threadIdx.x >> 5;  // ty 0..7
  int r0 = blockIdx.y * 32, c0 = blockIdx.x * 32;
  #pragma unroll
  for (int p = 0; p < 4; ++p)
    T[ty + 8 * p][tx] = src[(size_t)(r0 + ty + 8 * p) * C + c0 + tx];
  __syncthreads();
  #pragma unroll
  for (int p = 0; p < 4; ++p) {
    float v = T[tx][ty + 8 * p];
    if (sq) v *= v;
    dst[(size_t)(c0 + ty + 8 * p) * R + r0 + tx] = f2bf(v);
  }
}

// ======================= generic MFMA GEMM: C[M,N] = A[M,K] @ Bt[N,K]^T =======================
// grid (N/128, M/64), block 256 (4 waves, 16 rows each). No LDS (B is small & L2-hot).
__global__ __launch_bounds__(256) void k_gemm_bf(const u16* __restrict__ A, const u16* __restrict__ Bt,
                                                 float* __restrict__ Cf, u16* __restrict__ Cb,
                                                 int K, int N) {
  int w = threadIdx.x >> 6, l = threadIdx.x & 63, r15 = l & 15, g = l >> 4;
  int i0 = blockIdx.y * 64 + w * 16;
  int n0 = blockIdx.x * 128;
  f32x4 zero = {0.f, 0.f, 0.f, 0.f};
  f32x4 acc[8];
  #pragma unroll
  for (int n = 0; n < 8; ++n) acc[n] = zero;
  int kcN = K >> 5;
  const u16* arow = A + (size_t)(i0 + r15) * K + g * 8;
  for (int kc = 0; kc < kcN; ++kc) {
    bf16x8 a = *reinterpret_cast<const bf16x8*>(arow + kc * 32);
    #pragma unroll
    for (int n = 0; n < 8; ++n) {
      bf16x8 b = *reinterpret_cast<const bf16x8*>(Bt + (size_t)(n0 + n * 16 + r15) * K + kc * 32 + g * 8);
      acc[n] = mfma16(a, b, acc[n]);
    }
  }
  int io = i0 + g * 4;
  #pragma unroll
  for (int n = 0; n < 8; ++n) {
    int c = n0 + n * 16 + r15;
    #pragma unroll
    for (int q = 0; q < 4; ++q) {
      float vv = acc[n][q];
      Cf[(size_t)(io + q) * N + c] = vv;
      if (Cb) Cb[(size_t)(io + q) * N + c] = f2bf(vv);
    }
  }
}

// ======================= GAT: attention =======================
__global__ void k_node_dots(const float* __restrict__ H, const float* __restrict__ as_,
                            const float* __restrict__ ad_, float* __restrict__ hs,
                            float* __restrict__ hd, int D) {
  int wid = (blockIdx.x * blockDim.x + threadIdx.x) >> 6;
  int lane = threadIdx.x & 63;
  if (wid >= NN) return;
  float s = 0.f, d = 0.f;
  for (int c = lane; c < D; c += 64) {
    float h = H[(size_t)wid * D + c];
    s += h * as_[c]; d += h * ad_[c];
  }
  #pragma unroll
  for (int o = 32; o > 0; o >>= 1) { s += __shfl_xor(s, o); d += __shfl_xor(d, o); }
  if (!lane) { hs[wid] = s; hd[wid] = d; }
}

__global__ void k_alpha(const int* __restrict__ offs, const int* __restrict__ srcs,
                        const float* __restrict__ hs, const float* __restrict__ hd,
                        float* __restrict__ alpha) {
  int wid = (blockIdx.x * blockDim.x + threadIdx.x) >> 6;
  int lane = threadIdx.x & 63;
  if (wid >= NN) return;
  int b = offs[wid], e = offs[wid + 1];
  float hdn = hd[wid];
  float m = -3.4e38f;
  for (int p = b + lane; p < e; p += 64) {
    float v = hs[srcs[p]] + hdn;
    v = v > 0.f ? v : 0.2f * v;
    m = fmaxf(m, v);
  }
  #pragma unroll
  for (int o = 32; o > 0; o >>= 1) m = fmaxf(m, __shfl_xor(m, o));
  float den = 0.f;
  for (int p = b + lane; p < e; p += 64) {
    float v = hs[srcs[p]] + hdn;
    v = v > 0.f ? v : 0.2f * v;
    float ex = expf(v - m);
    alpha[p] = ex;
    den += ex;
  }
  #pragma unroll
  for (int o = 32; o > 0; o >>= 1) den += __shfl_xor(den, o);
  float sc = 1.f / (den + 1e-16f);
  for (int p = b + lane; p < e; p += 64) alpha[p] *= sc;
}

__global__ void k_aggregate_bf(const int* __restrict__ offs, const int* __restrict__ srcs,
                               const float* __restrict__ alpha, const u16* __restrict__ Hb,
                               float* __restrict__ outF, u16* __restrict__ outB, int D, int elu) {
  int n = blockIdx.x;
  int b = offs[n], e = offs[n + 1];
  for (int d = threadIdx.x; d < D; d += 256) {
    float acc = 0.f;
    for (int p = b; p < e; ++p)
      acc += alpha[p] * bf2f(Hb[(size_t)srcs[p] * D + d]);
    if (elu) acc = acc > 0.f ? acc : (expf(acc) - 1.f);
    if (outF) outF[(size_t)n * D + d] = acc;
    if (outB) outB[(size_t)n * D + d] = f2bf(acc);
  }
}

// ======================= mutual: inverse row norms =======================
__global__ void k_rninv(const float* __restrict__ h, float* __restrict__ nrinv) {
  int wid = (blockIdx.x * blockDim.x + threadIdx.x) >> 6;
  int lane = threadIdx.x & 63;
  if (wid >= NN) return;
  float a = 0.f;
  for (int c = lane; c < DDIM; c += 64) { float v = h[(size_t)wid * DDIM + c]; a += v * v; }
  #pragma unroll
  for (int o = 32; o > 0; o >>= 1) a += __shfl_xor(a, o);
  if (!lane) nrinv[wid] = 1.f / sqrtf(a);
}

// ======================= mutual sums: R[i]=sum_j cos, S[j]=sum_i cos (MFMA) =======================
// grid (4 j-chunks of 2048, 128 i-blocks of 64), block 256.
__global__ __launch_bounds__(256) void k_sums_bf(const u16* __restrict__ Ab, const u16* __restrict__ Bb,
                                                 const float* __restrict__ nainv, const float* __restrict__ nbinv,
                                                 float* __restrict__ R, float* __restrict__ S) {
  __shared__ uint4 BsU[2048];
  __shared__ float Scol[2048];
  int tid = threadIdx.x;
  int w = tid >> 6, l = tid & 63, r15 = l & 15, g = l >> 4;
  int i0 = blockIdx.y * 64;
  int jc0 = blockIdx.x * 2048;
  for (int s = tid; s < 2048; s += 256) Scol[s] = 0.f;
  bf16x8 qf[8];
  const u16* arow = Ab + (size_t)(i0 + w * 16 + r15) * 256 + g * 8;
  #pragma unroll
  for (int kc = 0; kc < 8; ++kc) qf[kc] = *reinterpret_cast<const bf16x8*>(arow + kc * 32);
  float ni[4];
  #pragma unroll
  for (int q = 0; q < 4; ++q) ni[q] = nainv[i0 + w * 16 + g * 4 + q];
  float rowacc[4] = {0.f, 0.f, 0.f, 0.f};
  f32x4 zero = {0.f, 0.f, 0.f, 0.f};
  for (int t = 0; t < 32; ++t) {
    int j0 = jc0 + t * 64;
    __syncthreads();
    #pragma unroll
    for (int p = 0; p < 8; ++p) {
      int c = p * 256 + tid;
      int frag = c >> 6, n = frag >> 3, kc = frag & 7;
      int ll = c & 63, gg = ll >> 4, jr = ll & 15;
      BsU[c] = *reinterpret_cast<const uint4*>(Bb + (size_t)(j0 + n * 16 + jr) * 256 + kc * 32 + gg * 8);
    }
    __syncthreads();
    f32x4 sacc[4];
    #pragma unroll
    for (int n = 0; n < 4; ++n) sacc[n] = zero;
    #pragma unroll
    for (int kc = 0; kc < 8; ++kc)
      #pragma unroll
      for (int n = 0; n < 4; ++n) {
        bf16x8 b = *reinterpret_cast<const bf16x8*>(&BsU[(n * 8 + kc) * 64 + l]);
        sacc[n] = mfma16(qf[kc], b, sacc[n]);
      }
    #pragma unroll
    for (int n = 0; n < 4; ++n) {
      float nb = nbinv[j0 + n * 16 + r15];
      float cs = 0.f;
      #pragma unroll
      for (int q = 0; q < 4; ++q) {
        float cv = sacc[n][q] * ni[q] * nb;
        rowacc[q] += cv;
        cs += cv;
      }
      cs += __shfl_xor(cs, 16);
      cs += __shfl_xor(cs, 32);
      if (l < 16) atomicAdd(&Scol[t * 64 + n * 16 + l], cs);
    }
  }
  #pragma unroll
  for (int q = 0; q < 4; ++q) {
    float v = rowacc[q];
    v += __shfl_xor(v, 1); v += __shfl_xor(v, 2); v += __shfl_xor(v, 4); v += __shfl_xor(v, 8);
    if (r15 == 0) atomicAdd(&R[i0 + w * 16 + g * 4 + q], v);
  }
  __syncthreads();
  for (int s = tid; s < 2048; s += 256) atomicAdd(&S[jc0 + s], Scol[s]);
}

// sc1[j] = nbinv2[j]/S[j]; sc2[j] = nbinv1[j]/R[j]
__global__ void k_scj(const float* __restrict__ S, const float* __restrict__ R,
                      const float* __restrict__ n1inv, const float* __restrict__ n2inv,
                      float* __restrict__ scj1, float* __restrict__ scj2) {
  int j = blockIdx.x * blockDim.x + threadIdx.x;
  if (j >= NN) return;
  scj1[j] = n2inv[j] / S[j];
  scj2[j] = n1inv[j] / R[j];
}

// ======================= mutual apply (flash, MFMA): Out[i,:] += sum_j P[i,j]*B[j,:] =======================
// P[i,j] = dot(A_i,B_j)*nainv[i]*scj[j].  grid (4 j-chunks, 128 i-blocks), block 256.
__global__ __launch_bounds__(256) void k_apply_bf(const u16* __restrict__ Ab, const u16* __restrict__ Bb,
                                                  const u16* __restrict__ Btg, const float* __restrict__ nainv,
                                                  const float* __restrict__ scj, float* __restrict__ Out) {
  __shared__ uint4 BsU[2048];                 // S-orientation frags (B[j][k])
  __shared__ uint4 BtU[2048];                 // PV-orientation frags (B[j][d] via Bt global)
  __shared__ __align__(16) u16 Ps[4 * 16 * 72];  // per-wave P tile (16 x 64, padded to 72)
  int tid = threadIdx.x;
  int w = tid >> 6, l = tid & 63, r15 = l & 15, g = l >> 4;
  int i0 = blockIdx.y * 64;
  int jc0 = blockIdx.x * 2048;
  bf16x8 qf[8];
  const u16* arow = Ab + (size_t)(i0 + w * 16 + r15) * 256 + g * 8;
  #pragma unroll
  for (int kc = 0; kc < 8; ++kc) qf[kc] = *reinterpret_cast<const bf16x8*>(arow + kc * 32);
  float ni[4];
  #pragma unroll
  for (int q = 0; q < 4; ++q) ni[q] = nainv[i0 + w * 16 + g * 4 + q];
  f32x4 zero = {0.f, 0.f, 0.f, 0.f};
  f32x4 oacc[16];
  #pragma unroll
  for (int n = 0; n < 16; ++n) oacc[n] = zero;
  u16* PsW = Ps + w * 16 * 72;
  for (int t = 0; t < 32; ++t) {
    int j0 = jc0 + t * 64;
    __syncthreads();
    #pragma unroll
    for (int p = 0; p < 8; ++p) {
      int c = p * 256 + tid;
      int frag = c >> 6, n = frag >> 3, kc = frag & 7;
      int ll = c & 63, gg = ll >> 4, jr = ll & 15;
      BsU[c] = *reinterpret_cast<const uint4*>(Bb + (size_t)(j0 + n * 16 + jr) * 256 + kc * 32 + gg * 8);
    }
    #pragma unroll
    for (int p = 0; p < 8; ++p) {
      int c = p * 256 + tid;
      int frag = c >> 6, n2 = frag >> 1, kc2 = frag & 1;
      int ll = c & 63, gg = ll >> 4, jr = ll & 15;
      BtU[c] = *reinterpret_cast<const uint4*>(Btg + (size_t)(n2 * 16 + jr) * (size_t)NN + j0 + kc2 * 32 + gg * 8);
    }
    __syncthreads();
    f32x4 sacc[4];
    #pragma unroll
    for (int n = 0; n < 4; ++n) sacc[n] = zero;
    #pragma unroll
    for (int kc = 0; kc < 8; ++kc)
      #pragma unroll
      for (int n = 0; n < 4; ++n) {
        bf16x8 b = *reinterpret_cast<const bf16x8*>(&BsU[(n * 8 + kc) * 64 + l]);
        sacc[n] = mfma16(qf[kc], b, sacc[n]);
      }
    #pragma unroll
    for (int n = 0; n < 4; ++n) {
      float sc = scj[j0 + n * 16 + r15];
      #pragma unroll
      for (int q = 0; q < 4; ++q) {
        float val = sacc[n][q] * ni[q] * sc;
        PsW[(g * 4 + q) * 72 + n * 16 + r15] = f2bf(val);
      }
    }
    #pragma unroll
    for (int kc2 = 0; kc2 < 2; ++kc2) {
      bf16x8 pa = *reinterpret_cast<const bf16x8*>(PsW + r15 * 72 + kc2 * 32 + g * 8);
      #pragma unroll
      for (int n2 = 0; n2 < 16; ++n2) {
        bf16x8 b = *reinterpret_cast<const bf16x8*>(&BtU[(n2 * 2 + kc2) * 64 + l]);
        oacc[n2] = mfma16(pa, b, oacc[n2]);
      }
    }
  }
  int io = i0 + w * 16 + g * 4;
  #pragma unroll
  for (int n2 = 0; n2 < 16; ++n2) {
    int c = n2 * 16 + r15;
    #pragma unroll
    for (int q = 0; q < 4; ++q)
      atomicAdd(&Out[(size_t)(io + q) * 256 + c], oacc[n2][q]);
  }
}

// ======================= match prep: U=x*y, P=x*x, Q=y*y (bf16) =======================
__global__ void k_prep_match(const float* __restrict__ X, const float* __restrict__ Y,
                             int bx, int by, u16* __restrict__ U, u16* __restrict__ P,
                             u16* __restrict__ Q) {
  int idx = blockIdx.x * blockDim.x + threadIdx.x;  // float4 units
  if (idx >= NN * 64) return;
  int n = idx >> 6, d4 = idx & 63;
  float4 xv = reinterpret_cast<const float4*>(X + (size_t)(bx ? 0 : n) * 256)[d4];
  float4 yv = reinterpret_cast<const float4*>(Y + (size_t)(by ? 0 : n) * 256)[d4];
  ushort4 uu, pp, qq;
  uu.x = f2bf(xv.x * yv.x); uu.y = f2bf(xv.y * yv.y); uu.z = f2bf(xv.z * yv.z); uu.w = f2bf(xv.w * yv.w);
  pp.x = f2bf(xv.x * xv.x); pp.y = f2bf(xv.y * xv.y); pp.z = f2bf(xv.z * xv.z); pp.w = f2bf(xv.w * xv.w);
  qq.x = f2bf(yv.x * yv.x); qq.y = f2bf(yv.y * yv.y); qq.z = f2bf(yv.z * yv.z); qq.w = f2bf(yv.w * yv.w);
  size_t o = (size_t)n * 256 + d4 * 4;
  *reinterpret_cast<ushort4*>(U + o) = uu;
  *reinterpret_cast<ushort4*>(P + o) = pp;
  *reinterpret_cast<ushort4*>(Q + o) = qq;
}

// ======================= match MFMA: out = (U@W2t^T)/max(sqrt(P@)*sqrt(Q@), eps) =======================
// grid (2, 128), block 256. K=256, N=256.
__global__ __launch_bounds__(256) void k_match_bf(const u16* __restrict__ U, const u16* __restrict__ P,
                                                  const u16* __restrict__ Q, const u16* __restrict__ W2t,
                                                  float* __restrict__ out) {
  int w = threadIdx.x >> 6, l = threadIdx.x & 63, r15 = l & 15, g = l >> 4;
  int i0 = blockIdx.y * 64 + w * 16;
  int n0 = blockIdx.x * 128;
  f32x4 zero = {0.f, 0.f, 0.f, 0.f};
  f32x4 aU[8], aP[8], aQ[8];
  #pragma unroll
  for (int n = 0; n < 8; ++n) { aU[n] = zero; aP[n] = zero; aQ[n] = zero; }
  size_t abase = (size_t)(i0 + r15) * 256 + g * 8;
  #pragma unroll 2
  for (int kc = 0; kc < 8; ++kc) {
    bf16x8 fu = *reinterpret_cast<const bf16x8*>(U + abase + kc * 32);
    bf16x8 fp = *reinterpret_cast<const bf16x8*>(P + abase + kc * 32);
    bf16x8 fq = *reinterpret_cast<const bf16x8*>(Q + abase + kc * 32);
    #pragma unroll
    for (int n = 0; n < 8; ++n) {
      bf16x8 b = *reinterpret_cast<const bf16x8*>(W2t + (size_t)(n0 + n * 16 + r15) * 256 + kc * 32 + g * 8);
      aU[n] = mfma16(fu, b, aU[n]);
      aP[n] = mfma16(fp, b, aP[n]);
      aQ[n] = mfma16(fq, b, aQ[n]);
    }
  }
  int io = i0 + g * 4;
  #pragma unroll
  for (int n = 0; n < 8; ++n) {
    int c = n0 + n * 16 + r15;
    #pragma unroll
    for (int q = 0; q < 4; ++q) {
      float s = sqrtf(aP[n][q]) * sqrtf(aQ[n][q]);
      out[(size_t)(io + q) * 256 + c] = aU[n][q] / fmaxf(s, FEPS);
    }
  }
}

// ======================= old f32 match (nout==1 only) =======================
__global__ __launch_bounds__(256) void k_match(const float* __restrict__ X, const float* __restrict__ Y,
                                               const float* __restrict__ W2, float* __restrict__ out,
                                               int nout, int bx, int by) {
  __shared__ float u[4][256], p[4][256], q[4][256];
  int nl = threadIdx.x >> 6;
  int ml = threadIdx.x & 63;
  int n = blockIdx.y * 4 + nl;
  int m = blockIdx.x * 64 + ml;
  for (int li = threadIdx.x; li < 4 * 256; li += 256) {
    int rr = li >> 8, dd = li & 255;
    int nn2 = blockIdx.y * 4 + rr;
    if (nn2 < nout) {
      float xv = X[(size_t)(bx ? 0 : nn2) * DDIM + dd];
      float yv = Y[(size_t)(by ? 0 : nn2) * DDIM + dd];
      u[rr][dd] = xv * yv; p[rr][dd] = xv * xv; q[rr][dd] = yv * yv;
    }
  }
  __syncthreads();
  if (n >= nout) return;
  float a = 0.f, b = 0.f, c = 0.f;
  #pragma unroll 4
  for (int d = 0; d < 256; ++d) {
    float wv = W2[(size_t)d * DDIM + m];
    a += u[nl][d] * wv; b += p[nl][d] * wv; c += q[nl][d] * wv;
  }
  out[(size_t)n * DDIM + m] = a / fmaxf(sqrtf(b) * sqrtf(c), FEPS);
}

__global__ void k_w2(const float* __restrict__ Wm, float* __restrict__ W2, int n) {
  int i = blockIdx.x * blockDim.x + threadIdx.x;
  if (i < n) { float v = Wm[i]; W2[i] = v * v; }
}

// ======================= readout =======================
__global__ void k_colsum(const float* __restrict__ h, const float* __restrict__ wt,
                         float* __restrict__ out) {
  int d = threadIdx.x;
  int r0 = blockIdx.x * 32;
  float acc = 0.f;
  for (int r = 0; r < 32; ++r) {
    float v = h[(size_t)(r0 + r) * DDIM + d];
    if (wt) v *= wt[r0 + r];
    acc += v;
  }
  atomicAdd(&out[d], acc);
}

__global__ void k_gvec(const float* __restrict__ mu, const float* __restrict__ Wr,
                       float* __restrict__ g) {
  __shared__ float ls[256];
  int m = threadIdx.x;
  ls[m] = mu[m] * (1.f / (float)NN);
  __syncthreads();
  float acc = 0.f;
  #pragma unroll 4
  for (int d = 0; d < 256; ++d) acc += ls[d] * Wr[(size_t)d * DDIM + m];
  g[m] = tanhf(acc);
}

__global__ void k_svec(const float* __restrict__ h, const float* __restrict__ g,
                       float* __restrict__ s) {
  int wid = (blockIdx.x * blockDim.x + threadIdx.x) >> 6;
  int lane = threadIdx.x & 63;
  if (wid >= NN) return;
  float acc = 0.f;
  for (int c = lane; c < DDIM; c += 64) acc += h[(size_t)wid * DDIM + c] * g[c];
  #pragma unroll
  for (int o = 32; o > 0; o >>= 1) acc += __shfl_xor(acc, o);
  if (!lane) s[wid] = 1.f / (1.f + expf(-acc));
}

// ======================= MLP =======================
__global__ void k_mlp(const float* __restrict__ v, const float* __restrict__ w,
                      const float* __restrict__ b, float* __restrict__ out,
                      int K, int M, int act) {
  __shared__ float lv[2048];
  for (int i = threadIdx.x; i < K; i += blockDim.x) lv[i] = v[i];
  __syncthreads();
  int m = blockIdx.x * blockDim.x + threadIdx.x;
  if (m >= M) return;
  float acc = b[m];
  for (int k = 0; k < K; ++k) acc += lv[k] * w[(size_t)k * M + m];
  if (act == 1) acc = fmaxf(acc, 0.f);
  out[m] = acc;
}

__global__ void k_final(const float* __restrict__ l3, const float* __restrict__ w4,
                        const float* __restrict__ b4, const int* __restrict__ label,
                        float* __restrict__ out) {
  __shared__ float ls[128];
  int t = threadIdx.x;
  ls[t] = l3[t] * w4[t];
  __syncthreads();
  for (int w = 64; w > 0; w >>= 1) { if (t < w) ls[t] += ls[t + w]; __syncthreads(); }
  if (t == 0) {
    float z = 1.f / (1.f + expf(-(ls[0] + b4[0])));
    out[0] = z;
    float lb = (float)label[0];
    out[1] = lb;
    out[2] = expf(-lb);
  }
}

// ======================= host =======================
extern "C" void kernel_launch(void* const* d_in, const int* in_sizes, int n_in,
                              void* d_out, int out_size, void* d_ws, size_t ws_size,
                              hipStream_t stream) {
  (void)in_sizes; (void)n_in; (void)out_size;
  const float* x_s   = (const float*)d_in[0];
  const float* x_t   = (const float*)d_in[1];
  const int*   ei_s  = (const int*)d_in[2];
  const int*   ei_t  = (const int*)d_in[3];
  const int*   label = (const int*)d_in[4];
  const float* W_g1  = (const float*)d_in[5];
  const float* a1s   = (const float*)d_in[6];
  const float* a1d   = (const float*)d_in[7];
  const float* W_g2  = (const float*)d_in[8];
  const float* a2s   = (const float*)d_in[9];
  const float* a2d   = (const float*)d_in[10];
  const float* W_read  = (const float*)d_in[11];
  const float* W_match = (const float*)d_in[12];
  const float* w1 = (const float*)d_in[13]; const float* b1 = (const float*)d_in[14];
  const float* w2 = (const float*)d_in[15]; const float* b2 = (const float*)d_in[16];
  const float* w3 = (const float*)d_in[17]; const float* b3 = (const float*)d_in[18];
  const float* w4 = (const float*)d_in[19]; const float* b4 = (const float*)d_in[20];
  float* out = (float*)d_out;

  char* base = (char*)d_ws;
  size_t off = 0;
  auto alloc = [&](size_t bytes) -> void* {
    void* pp = base + off;
    off = (off + bytes + 255) & ~(size_t)255;
    return pp;
  };
  double* dsum = (double*)alloc(4 * sizeof(double));
  float* hbuf = (float*)alloc((size_t)NN * HH * 4);       // 16MB (layer outputs f32)
  u16*   hb_bf= (u16*)alloc((size_t)NN * HH * 2);         // 8MB
  u16*   aggb = (u16*)alloc((size_t)NN * HH * 2);         // 8MB
  float* h1   = (float*)alloc((size_t)NN * DDIM * 4);
  float* h2   = (float*)alloc((size_t)NN * DDIM * 4);
  float* h1m  = (float*)alloc((size_t)NN * DDIM * 4);
  float* h2m  = (float*)alloc((size_t)NN * DDIM * 4);
  float* mtmp = (float*)alloc((size_t)NN * DDIM * 4);
  u16*   f1b  = (u16*)alloc((size_t)NN * FF * 2);
  u16*   f2b  = (u16*)alloc((size_t)NN * FF * 2);
  u16*   h1b  = (u16*)alloc((size_t)NN * DDIM * 2);
  u16*   h2b  = (u16*)alloc((size_t)NN * DDIM * 2);
  u16*   h1t  = (u16*)alloc((size_t)NN * DDIM * 2);
  u16*   h2t  = (u16*)alloc((size_t)NN * DDIM * 2);
  u16*   Ub   = (u16*)alloc((size_t)NN * DDIM * 2);
  u16*   Pb   = (u16*)alloc((size_t)NN * DDIM * 2);
  u16*   Qb   = (u16*)alloc((size_t)NN * DDIM * 2);
  float* alpha= (float*)alloc((size_t)ET * 4);
  int*   srcs = (int*)alloc((size_t)ET * 4);
  int*   deg  = (int*)alloc(NN * 4);
  int*   curs = (int*)alloc(NN * 4);
  int*   offs = (int*)alloc((NN + 1) * 4);
  float* n1inv= (float*)alloc(NN * 4);
  float* n2inv= (float*)alloc(NN * 4);
  float* Rr   = (float*)alloc(NN * 4);
  float* Ss   = (float*)alloc(NN * 4);
  float* scj1 = (float*)alloc(NN * 4);
  float* scj2 = (float*)alloc(NN * 4);
  float* hsb  = (float*)alloc(NN * 4);
  float* hdb  = (float*)alloc(NN * 4);
  float* sv   = (float*)alloc(NN * 4);
  float* mu   = (float*)alloc(DDIM * 4);
  float* gv   = (float*)alloc(DDIM * 4);
  float* W2   = (float*)alloc((size_t)DDIM * DDIM * 4);
  u16*   Wg1t = (u16*)alloc((size_t)HH * FF * 2);
  u16*   Wg2t = (u16*)alloc((size_t)DDIM * HH * 2);
  u16*   W2t  = (u16*)alloc((size_t)DDIM * DDIM * 2);
  float* h1g  = (float*)alloc(DDIM * 4);
  float* h2g  = (float*)alloc(DDIM * 4);
  float* h1mg = (float*)alloc(DDIM * 4);
  float* h2mg = (float*)alloc(DDIM * 4);
  float* v    = (float*)alloc(2048 * 4);
  float* l1o  = (float*)alloc(512 * 4);
  float* l2o  = (float*)alloc(256 * 4);
  float* l3o  = (float*)alloc(128 * 4);
  if (off > ws_size) return;

  // ---- stage 0 ----
  hipMemsetAsync(dsum, 0, 4 * sizeof(double), stream);
  k_reduce<<<1024, 256, 0, stream>>>(x_s, NN * FF, dsum);
  k_reduce<<<1024, 256, 0, stream>>>(x_t, NN * FF, dsum + 2);
  k_normalize<<<1024, 256, 0, stream>>>(x_s, f1b, NN * FF, dsum);
  k_normalize<<<1024, 256, 0, stream>>>(x_t, f2b, NN * FF, dsum + 2);

  // ---- weight preps ----
  k_tr_bf16<<<dim3(HH / 32, FF / 32), 256, 0, stream>>>(W_g1, Wg1t, FF, HH, 0);      // [512][128]
  k_tr_bf16<<<dim3(DDIM / 32, HH / 32), 256, 0, stream>>>(W_g2, Wg2t, HH, DDIM, 0);  // [256][512]
  k_tr_bf16<<<dim3(DDIM / 32, DDIM / 32), 256, 0, stream>>>(W_match, W2t, DDIM, DDIM, 1);
  k_w2<<<dim3((DDIM * DDIM + 255) / 256), 256, 0, stream>>>(W_match, W2, DDIM * DDIM);

  // ---- GAT ----
  auto run_gat = [&](const u16* finb, const int* ei, float* hout, u16* houtb) {
    hipMemsetAsync(deg, 0, NN * 4, stream);
    k_hist<<<dim3((ET + 255) / 256), 256, 0, stream>>>(ei, deg);
    k_scan<<<1, 256, 0, stream>>>(deg, offs, curs);
    k_scatter<<<dim3((ET + 255) / 256), 256, 0, stream>>>(ei, curs, srcs);
    k_gemm_bf<<<dim3(HH / 128, NN / 64), 256, 0, stream>>>(finb, Wg1t, hbuf, hb_bf, FF, HH);
    k_node_dots<<<dim3(NN / 4), 256, 0, stream>>>(hbuf, a1s, a1d, hsb, hdb, HH);
    k_alpha<<<dim3(NN / 4), 256, 0, stream>>>(offs, srcs, hsb, hdb, alpha);
    k_aggregate_bf<<<dim3(NN), 256, 0, stream>>>(offs, srcs, alpha, hb_bf, nullptr, aggb, HH, 1);
    k_gemm_bf<<<dim3(DDIM / 128, NN / 64), 256, 0, stream>>>(aggb, Wg2t, hbuf, hb_bf, HH, DDIM);
    k_node_dots<<<dim3(NN / 4), 256, 0, stream>>>(hbuf, a2s, a2d, hsb, hdb, DDIM);
    k_alpha<<<dim3(NN / 4), 256, 0, stream>>>(offs, srcs, hsb, hdb, alpha);
    k_aggregate_bf<<<dim3(NN), 256, 0, stream>>>(offs, srcs, alpha, hb_bf, hout, houtb, DDIM, 0);
  };
  run_gat(f1b, ei_s, h1, h1b);
  run_gat(f2b, ei_t, h2, h2b);

  // ---- mutual ----
  k_rninv<<<dim3(NN / 4), 256, 0, stream>>>(h1, n1inv);
  k_rninv<<<dim3(NN / 4), 256, 0, stream>>>(h2, n2inv);
  k_tr_bf16<<<dim3(DDIM / 32, NN / 32), 256, 0, stream>>>(h1, h1t, NN, DDIM, 0);
  k_tr_bf16<<<dim3(DDIM / 32, NN / 32), 256, 0, stream>>>(h2, h2t, NN, DDIM, 0);
  hipMemsetAsync(Rr, 0, NN * 4, stream);
  hipMemsetAsync(Ss, 0, NN * 4, stream);
  k_sums_bf<<<dim3(4, NN / 64), 256, 0, stream>>>(h1b, h2b, n1inv, n2inv, Rr, Ss);
  k_scj<<<dim3(NN / 256), 256, 0, stream>>>(Ss, Rr, n1inv, n2inv, scj1, scj2);
  hipMemsetAsync(h1m, 0, (size_t)NN * DDIM * 4, stream);
  k_apply_bf<<<dim3(4, NN / 64), 256, 0, stream>>>(h1b, h2b, h2t, n1inv, scj1, h1m);
  hipMemsetAsync(h2m, 0, (size_t)NN * DDIM * 4, stream);
  k_apply_bf<<<dim3(4, NN / 64), 256, 0, stream>>>(h2b, h1b, h1t, n2inv, scj2, h2m);

  // ---- readouts ----
  auto readout = [&](const float* h, float* og) {
    hipMemsetAsync(mu, 0, DDIM * 4, stream);
    k_colsum<<<dim3(NN / 32), 256, 0, stream>>>(h, nullptr, mu);
    k_gvec<<<1, 256, 0, stream>>>(mu, W_read, gv);
    k_svec<<<dim3(NN / 4), 256, 0, stream>>>(h, gv, sv);
    hipMemsetAsync(og, 0, DDIM * 4, stream);
    k_colsum<<<dim3(NN / 32), 256, 0, stream>>>(h, sv, og);
  };
  readout(h1, h1g);
  readout(h2, h2g);
  readout(h1m, h1mg);
  readout(h2m, h2mg);

  auto matchf = [&](const float* X, int bx, const float* Y, int by, float* o) {
    k_prep_match<<<dim3((NN * 64 + 255) / 256), 256, 0, stream>>>(X, Y, bx, by, Ub, Pb, Qb);
    k_match_bf<<<dim3(2, NN / 64), 256, 0, stream>>>(Ub, Pb, Qb, W2t, o);
  };
  // z order: [miu1g, phi1g, psi1g, om1, miu2g, phi2g, psi2g, om2]
  matchf(h1, 0, h1m, 0, mtmp);  readout(mtmp, v + 0);
  matchf(h1, 0, h1mg, 1, mtmp); readout(mtmp, v + 256);
  matchf(h1g, 1, h1m, 0, mtmp); readout(mtmp, v + 512);
  k_match<<<dim3(DDIM / 64, 1), 256, 0, stream>>>(h1g, h1mg, W2, v + 768, 1, 1, 1);
  matchf(h2, 0, h2m, 0, mtmp);  readout(mtmp, v + 1024);
  matchf(h2, 0, h2mg, 1, mtmp); readout(mtmp, v + 1280);
  matchf(h2g, 1, h2m, 0, mtmp); readout(mtmp, v + 1536);
  k_match<<<dim3(DDIM / 64, 1), 256, 0, stream>>>(h2g, h2mg, W2, v + 1792, 1, 1, 1);

  // ---- MLP ----
  k_mlp<<<dim3(2), 256, 0, stream>>>(v, w1, b1, l1o, 2048, 512, 1);
  k_mlp<<<dim3(1), 256, 0, stream>>>(l1o, w2, b2, l2o, 512, 256, 1);
  k_mlp<<<dim3(1), 256, 0, stream>>>(l2o, w3, b3, l3o, 256, 128, 1);
  k_final<<<1, 128, 0, stream>>>(l3o, w4, b4, label, out);
}

// Round 3
// 1771.191 us; speedup vs baseline: 3.7519x; 1.1209x over previous
//
#include <hip/hip_runtime.h>
#include <hip/hip_bf16.h>
#include <math.h>
#include <stddef.h>

#define NN 8192
#define FF 128
#define HH 512
#define DDIM 256
#define EE 131072
#define ET (2*EE + NN)     // 270336 edges after symmetrize + self loops
#define FEPS 1e-8f

typedef float f32x4 __attribute__((ext_vector_type(4)));
typedef __bf16 bf16x8 __attribute__((ext_vector_type(8)));
typedef unsigned short u16;

static __device__ __forceinline__ u16 f2bf(float f) {
  union { float f; unsigned u; } v; v.f = f;
  return (u16)((v.u + 0x7fffu + ((v.u >> 16) & 1u)) >> 16);
}
static __device__ __forceinline__ float bf2f(u16 h) {
  union { unsigned u; float f; } v; v.u = ((unsigned)h) << 16;
  return v.f;
}
static __device__ __forceinline__ f32x4 mfma16(bf16x8 a, bf16x8 b, f32x4 c) {
  return __builtin_amdgcn_mfma_f32_16x16x32_bf16(a, b, c, 0, 0, 0);
}

struct PLF { const float* p[4]; };
struct PLB { const u16* p[6]; int slot[6]; };

// ======================= stage 0: global mean/std normalize =======================
__global__ void k_reduce(const float* __restrict__ x, int n, double* __restrict__ out) {
  __shared__ double s1[256], s2[256];
  double a = 0.0, b = 0.0;
  for (int i = blockIdx.x * blockDim.x + threadIdx.x; i < n; i += gridDim.x * blockDim.x) {
    double v = (double)x[i];
    a += v; b += v * v;
  }
  s1[threadIdx.x] = a; s2[threadIdx.x] = b;
  __syncthreads();
  for (int w = 128; w > 0; w >>= 1) {
    if (threadIdx.x < w) { s1[threadIdx.x] += s1[threadIdx.x + w]; s2[threadIdx.x] += s2[threadIdx.x + w]; }
    __syncthreads();
  }
  if (threadIdx.x == 0) { atomicAdd(&out[0], s1[0]); atomicAdd(&out[1], s2[0]); }
}

__global__ void k_normalize(const float* __restrict__ x, u16* __restrict__ y, int n,
                            const double* __restrict__ s) {
  double mean = s[0] / (double)n;
  double var = (s[1] - (double)n * mean * mean) / (double)(n - 1);  // ddof=1
  float mu = (float)mean;
  float inv = (float)(1.0 / sqrt(var));
  for (int i = blockIdx.x * blockDim.x + threadIdx.x; i < n; i += gridDim.x * blockDim.x)
    y[i] = f2bf((x[i] - mu) * inv);
}

// ======================= GAT: CSR build =======================
__global__ void k_hist(const int* __restrict__ ei, int* __restrict__ deg) {
  int t = blockIdx.x * blockDim.x + threadIdx.x;
  if (t >= ET) return;
  int dst = (t < EE) ? ei[EE + t] : ((t < 2*EE) ? ei[t - EE] : (t - 2*EE));
  atomicAdd(&deg[dst], 1);
}

__global__ void k_scan(const int* __restrict__ deg, int* __restrict__ offs, int* __restrict__ cursor) {
  __shared__ int ts[256];
  int tid = threadIdx.x;
  int loc[32];
  int s = 0;
  #pragma unroll
  for (int i = 0; i < 32; ++i) { loc[i] = s; s += deg[tid * 32 + i]; }
  ts[tid] = s;
  __syncthreads();
  for (int off = 1; off < 256; off <<= 1) {
    int v = (tid >= off) ? ts[tid - off] : 0;
    __syncthreads();
    ts[tid] += v;
    __syncthreads();
  }
  int pre = ts[tid] - s;
  #pragma unroll
  for (int i = 0; i < 32; ++i) {
    int o = pre + loc[i];
    offs[tid * 32 + i] = o;
    cursor[tid * 32 + i] = o;
  }
  if (tid == 255) offs[NN] = ts[255];
}

__global__ void k_scatter(const int* __restrict__ ei, int* __restrict__ cursor, int* __restrict__ srcs) {
  int t = blockIdx.x * blockDim.x + threadIdx.x;
  if (t >= ET) return;
  int src = (t < 2*EE) ? ei[t] : (t - 2*EE);
  int dst = (t < EE) ? ei[EE + t] : ((t < 2*EE) ? ei[t - EE] : (t - 2*EE));
  int pos = atomicAdd(&cursor[dst], 1);
  srcs[pos] = src;
}

// ======================= transpose f32 -> bf16 (optionally squared) =======================
__global__ __launch_bounds__(256) void k_tr_bf16(const float* __restrict__ src, u16* __restrict__ dst,
                                                 int R, int C, int sq) {
  __shared__ float T[32][33];
  int tx = threadIdx.x & 31, ty = threadIdx.x >> 5;
  int r0 = blockIdx.y * 32, c0 = blockIdx.x * 32;
  #pragma unroll
  for (int p = 0; p < 4; ++p)
    T[ty + 8 * p][tx] = src[(size_t)(r0 + ty + 8 * p) * C + c0 + tx];
  __syncthreads();
  #pragma unroll
  for (int p = 0; p < 4; ++p) {
    float v = T[tx][ty + 8 * p];
    if (sq) v *= v;
    dst[(size_t)(c0 + ty + 8 * p) * R + r0 + tx] = f2bf(v);
  }
}

// ======================= generic MFMA GEMM: C[M,N] = A[M,K] @ Bt[N,K]^T =======================
__global__ __launch_bounds__(256) void k_gemm_bf(const u16* __restrict__ A, const u16* __restrict__ Bt,
                                                 float* __restrict__ Cf, u16* __restrict__ Cb,
                                                 int K, int N) {
  int w = threadIdx.x >> 6, l = threadIdx.x & 63, r15 = l & 15, g = l >> 4;
  int i0 = blockIdx.y * 64 + w * 16;
  int n0 = blockIdx.x * 128;
  f32x4 zero = {0.f, 0.f, 0.f, 0.f};
  f32x4 acc[8];
  #pragma unroll
  for (int n = 0; n < 8; ++n) acc[n] = zero;
  int kcN = K >> 5;
  const u16* arow = A + (size_t)(i0 + r15) * K + g * 8;
  for (int kc = 0; kc < kcN; ++kc) {
    bf16x8 a = *reinterpret_cast<const bf16x8*>(arow + kc * 32);
    #pragma unroll
    for (int n = 0; n < 8; ++n) {
      bf16x8 b = *reinterpret_cast<const bf16x8*>(Bt + (size_t)(n0 + n * 16 + r15) * K + kc * 32 + g * 8);
      acc[n] = mfma16(a, b, acc[n]);
    }
  }
  int io = i0 + g * 4;
  #pragma unroll
  for (int n = 0; n < 8; ++n) {
    int c = n0 + n * 16 + r15;
    #pragma unroll
    for (int q = 0; q < 4; ++q) {
      float vv = acc[n][q];
      if (Cf) Cf[(size_t)(io + q) * N + c] = vv;
      Cb[(size_t)(io + q) * N + c] = f2bf(vv);
    }
  }
}

// ======================= GAT: attention =======================
__global__ void k_node_dots_bf(const u16* __restrict__ Hb, const float* __restrict__ as_,
                               const float* __restrict__ ad_, float* __restrict__ hs,
                               float* __restrict__ hd, int D) {
  int wid = (blockIdx.x * blockDim.x + threadIdx.x) >> 6;
  int lane = threadIdx.x & 63;
  if (wid >= NN) return;
  float s = 0.f, d = 0.f;
  if (D == 512) {
    const u16* row = Hb + (size_t)wid * 512 + lane * 8;
    ushort4 v0 = *reinterpret_cast<const ushort4*>(row);
    ushort4 v1 = *reinterpret_cast<const ushort4*>(row + 4);
    const float4* ap = reinterpret_cast<const float4*>(as_ + lane * 8);
    const float4* dp = reinterpret_cast<const float4*>(ad_ + lane * 8);
    float4 a0 = ap[0], a1 = ap[1], e0 = dp[0], e1 = dp[1];
    float h0 = bf2f(v0.x), h1 = bf2f(v0.y), h2 = bf2f(v0.z), h3 = bf2f(v0.w);
    float h4 = bf2f(v1.x), h5 = bf2f(v1.y), h6 = bf2f(v1.z), h7 = bf2f(v1.w);
    s = h0*a0.x + h1*a0.y + h2*a0.z + h3*a0.w + h4*a1.x + h5*a1.y + h6*a1.z + h7*a1.w;
    d = h0*e0.x + h1*e0.y + h2*e0.z + h3*e0.w + h4*e1.x + h5*e1.y + h6*e1.z + h7*e1.w;
  } else {
    const u16* row = Hb + (size_t)wid * 256 + lane * 4;
    ushort4 v0 = *reinterpret_cast<const ushort4*>(row);
    float4 a0 = *reinterpret_cast<const float4*>(as_ + lane * 4);
    float4 e0 = *reinterpret_cast<const float4*>(ad_ + lane * 4);
    float h0 = bf2f(v0.x), h1 = bf2f(v0.y), h2 = bf2f(v0.z), h3 = bf2f(v0.w);
    s = h0*a0.x + h1*a0.y + h2*a0.z + h3*a0.w;
    d = h0*e0.x + h1*e0.y + h2*e0.z + h3*e0.w;
  }
  #pragma unroll
  for (int o = 32; o > 0; o >>= 1) { s += __shfl_xor(s, o); d += __shfl_xor(d, o); }
  if (!lane) { hs[wid] = s; hd[wid] = d; }
}

__global__ void k_alpha(const int* __restrict__ offs, const int* __restrict__ srcs,
                        const float* __restrict__ hs, const float* __restrict__ hd,
                        float* __restrict__ alpha) {
  int wid = (blockIdx.x * blockDim.x + threadIdx.x) >> 6;
  int lane = threadIdx.x & 63;
  if (wid >= NN) return;
  int b = offs[wid], e = offs[wid + 1];
  float hdn = hd[wid];
  float m = -3.4e38f;
  for (int p = b + lane; p < e; p += 64) {
    float v = hs[srcs[p]] + hdn;
    v = v > 0.f ? v : 0.2f * v;        // leaky_relu 0.2
    alpha[p] = v;
    m = fmaxf(m, v);
  }
  #pragma unroll
  for (int o = 32; o > 0; o >>= 1) m = fmaxf(m, __shfl_xor(m, o));
  float den = 0.f;
  for (int p = b + lane; p < e; p += 64) {
    float ex = expf(alpha[p] - m);
    alpha[p] = ex;
    den += ex;
  }
  #pragma unroll
  for (int o = 32; o > 0; o >>= 1) den += __shfl_xor(den, o);
  float sc = 1.f / (den + 1e-16f);
  for (int p = b + lane; p < e; p += 64) alpha[p] *= sc;
}

// wave-per-edge aggregate with 16B vector gathers; 4-wave LDS reduce
__global__ __launch_bounds__(256) void k_agg2(const int* __restrict__ offs, const int* __restrict__ srcs,
                                              const float* __restrict__ alpha, const u16* __restrict__ Hb,
                                              float* __restrict__ outF, u16* __restrict__ outB,
                                              int D, int elu) {
  __shared__ float red[4][512];
  int n = blockIdx.x;
  int b = offs[n], e = offs[n + 1];
  int w = threadIdx.x >> 6, lane = threadIdx.x & 63;
  float acc[8];
  #pragma unroll
  for (int j = 0; j < 8; ++j) acc[j] = 0.f;
  if (D == 512) {
    const u16* base = Hb + lane * 8;
    for (int p = b + w; p < e; p += 4) {
      float a = alpha[p];
      const u16* row = base + (size_t)srcs[p] * 512;
      ushort4 v0 = *reinterpret_cast<const ushort4*>(row);
      ushort4 v1 = *reinterpret_cast<const ushort4*>(row + 4);
      acc[0] += a * bf2f(v0.x); acc[1] += a * bf2f(v0.y);
      acc[2] += a * bf2f(v0.z); acc[3] += a * bf2f(v0.w);
      acc[4] += a * bf2f(v1.x); acc[5] += a * bf2f(v1.y);
      acc[6] += a * bf2f(v1.z); acc[7] += a * bf2f(v1.w);
    }
    #pragma unroll
    for (int j = 0; j < 8; ++j) red[w][lane * 8 + j] = acc[j];
  } else {
    const u16* base = Hb + lane * 4;
    for (int p = b + w; p < e; p += 4) {
      float a = alpha[p];
      const u16* row = base + (size_t)srcs[p] * 256;
      ushort4 v0 = *reinterpret_cast<const ushort4*>(row);
      acc[0] += a * bf2f(v0.x); acc[1] += a * bf2f(v0.y);
      acc[2] += a * bf2f(v0.z); acc[3] += a * bf2f(v0.w);
    }
    #pragma unroll
    for (int j = 0; j < 4; ++j) red[w][lane * 4 + j] = acc[j];
  }
  __syncthreads();
  for (int dd = threadIdx.x; dd < D; dd += 256) {
    float sres = red[0][dd] + red[1][dd] + red[2][dd] + red[3][dd];
    if (elu) sres = sres > 0.f ? sres : (expf(sres) - 1.f);
    if (outF) outF[(size_t)n * D + dd] = sres;
    outB[(size_t)n * D + dd] = f2bf(sres);
  }
}

// ======================= mutual: inverse row norms =======================
__global__ void k_rninv(const float* __restrict__ h, float* __restrict__ nrinv) {
  int wid = (blockIdx.x * blockDim.x + threadIdx.x) >> 6;
  int lane = threadIdx.x & 63;
  if (wid >= NN) return;
  float4 v = *reinterpret_cast<const float4*>(h + (size_t)wid * DDIM + lane * 4);
  float a = v.x * v.x + v.y * v.y + v.z * v.z + v.w * v.w;
  #pragma unroll
  for (int o = 32; o > 0; o >>= 1) a += __shfl_xor(a, o);
  if (!lane) nrinv[wid] = 1.f / sqrtf(a);
}

// ======================= mutual sums: R[i]=sum_j cos, S[j]=sum_i cos (MFMA, prefetched) =======================
__global__ __launch_bounds__(256, 4) void k_sums_bf(const u16* __restrict__ Ab, const u16* __restrict__ Bb,
                                                    const float* __restrict__ nainv, const float* __restrict__ nbinv,
                                                    float* __restrict__ R, float* __restrict__ S) {
  __shared__ uint4 BsU[2048];
  __shared__ float Scol[2048];
  int tid = threadIdx.x;
  int w = tid >> 6, l = tid & 63, r15 = l & 15, g = l >> 4;
  int i0 = blockIdx.y * 64;
  int jc0 = blockIdx.x * 2048;
  for (int s = tid; s < 2048; s += 256) Scol[s] = 0.f;
  bf16x8 qf[8];
  const u16* arow = Ab + (size_t)(i0 + w * 16 + r15) * 256 + g * 8;
  #pragma unroll
  for (int kc = 0; kc < 8; ++kc) qf[kc] = *reinterpret_cast<const bf16x8*>(arow + kc * 32);
  float ni[4];
  #pragma unroll
  for (int q = 0; q < 4; ++q) ni[q] = nainv[i0 + w * 16 + g * 4 + q];
  int offS[8];
  #pragma unroll
  for (int p = 0; p < 8; ++p) {
    int c = p * 256 + tid;
    int frag = c >> 6, n = frag >> 3, kc = frag & 7;
    int ll = c & 63, gg = ll >> 4, jr = ll & 15;
    offS[p] = (n * 16 + jr) * 256 + kc * 32 + gg * 8;
  }
  uint4 rs[8];
  #pragma unroll
  for (int p = 0; p < 8; ++p)
    rs[p] = *reinterpret_cast<const uint4*>(Bb + (size_t)jc0 * 256 + offS[p]);
  float rowacc[4] = {0.f, 0.f, 0.f, 0.f};
  f32x4 zero = {0.f, 0.f, 0.f, 0.f};
  for (int t = 0; t < 32; ++t) {
    __syncthreads();
    #pragma unroll
    for (int p = 0; p < 8; ++p) BsU[p * 256 + tid] = rs[p];
    __syncthreads();
    int jn = jc0 + ((t + 1) & 31) * 64;
    #pragma unroll
    for (int p = 0; p < 8; ++p)
      rs[p] = *reinterpret_cast<const uint4*>(Bb + (size_t)jn * 256 + offS[p]);
    int j0 = jc0 + t * 64;
    f32x4 sacc[4];
    #pragma unroll
    for (int n = 0; n < 4; ++n) sacc[n] = zero;
    #pragma unroll
    for (int kc = 0; kc < 8; ++kc)
      #pragma unroll
      for (int n = 0; n < 4; ++n) {
        bf16x8 b = *reinterpret_cast<const bf16x8*>(&BsU[(n * 8 + kc) * 64 + l]);
        sacc[n] = mfma16(qf[kc], b, sacc[n]);
      }
    #pragma unroll
    for (int n = 0; n < 4; ++n) {
      float nb = nbinv[j0 + n * 16 + r15];
      float cs = 0.f;
      #pragma unroll
      for (int q = 0; q < 4; ++q) {
        float cv = sacc[n][q] * ni[q] * nb;
        rowacc[q] += cv;
        cs += cv;
      }
      cs += __shfl_xor(cs, 16);
      cs += __shfl_xor(cs, 32);
      if (l < 16) atomicAdd(&Scol[t * 64 + n * 16 + l], cs);
    }
  }
  #pragma unroll
  for (int q = 0; q < 4; ++q) {
    float v = rowacc[q];
    v += __shfl_xor(v, 1); v += __shfl_xor(v, 2); v += __shfl_xor(v, 4); v += __shfl_xor(v, 8);
    if (r15 == 0) atomicAdd(&R[i0 + w * 16 + g * 4 + q], v);
  }
  __syncthreads();
  for (int s = tid; s < 2048; s += 256) atomicAdd(&S[jc0 + s], Scol[s]);
}

__global__ void k_scj(const float* __restrict__ S, const float* __restrict__ R,
                      const float* __restrict__ n1inv, const float* __restrict__ n2inv,
                      float* __restrict__ scj1, float* __restrict__ scj2) {
  int j = blockIdx.x * blockDim.x + threadIdx.x;
  if (j >= NN) return;
  scj1[j] = n2inv[j] / S[j];
  scj2[j] = n1inv[j] / R[j];
}

// ======================= mutual apply (flash, MFMA, reg-prefetch pipelined) =======================
__global__ __launch_bounds__(256, 2) void k_apply_bf(const u16* __restrict__ Ab, const u16* __restrict__ Bb,
                                                     const u16* __restrict__ Btg, const float* __restrict__ nainv,
                                                     const float* __restrict__ scj, float* __restrict__ Out) {
  __shared__ uint4 BsU[2048];                 // S-orientation frags (B[j][k])
  __shared__ uint4 BtU[2048];                 // PV-orientation frags (from Bt global)
  __shared__ __align__(16) u16 Ps[4 * 16 * 72];
  int tid = threadIdx.x;
  int w = tid >> 6, l = tid & 63, r15 = l & 15, g = l >> 4;
  int i0 = blockIdx.y * 64;
  int jc0 = blockIdx.x * 2048;
  bf16x8 qf[8];
  const u16* arow = Ab + (size_t)(i0 + w * 16 + r15) * 256 + g * 8;
  #pragma unroll
  for (int kc = 0; kc < 8; ++kc) qf[kc] = *reinterpret_cast<const bf16x8*>(arow + kc * 32);
  float ni[4];
  #pragma unroll
  for (int q = 0; q < 4; ++q) ni[q] = nainv[i0 + w * 16 + g * 4 + q];
  int offS[8], offT[8];
  #pragma unroll
  for (int p = 0; p < 8; ++p) {
    int c = p * 256 + tid;
    int ll = c & 63, gg = ll >> 4, jr = ll & 15;
    int frag = c >> 6;
    int n = frag >> 3, kc = frag & 7;
    offS[p] = (n * 16 + jr) * 256 + kc * 32 + gg * 8;
    int n2 = frag >> 1, kc2 = frag & 1;
    offT[p] = (n2 * 16 + jr) * NN + kc2 * 32 + gg * 8;
  }
  uint4 rs[8], rt[8];
  #pragma unroll
  for (int p = 0; p < 8; ++p) {
    rs[p] = *reinterpret_cast<const uint4*>(Bb + (size_t)jc0 * 256 + offS[p]);
    rt[p] = *reinterpret_cast<const uint4*>(Btg + (size_t)jc0 + offT[p]);
  }
  f32x4 zero = {0.f, 0.f, 0.f, 0.f};
  f32x4 oacc[16];
  #pragma unroll
  for (int n = 0; n < 16; ++n) oacc[n] = zero;
  u16* PsW = Ps + w * 16 * 72;
  for (int t = 0; t < 32; ++t) {
    __syncthreads();
    #pragma unroll
    for (int p = 0; p < 8; ++p) BsU[p * 256 + tid] = rs[p];
    #pragma unroll
    for (int p = 0; p < 8; ++p) BtU[p * 256 + tid] = rt[p];
    __syncthreads();
    int jn = jc0 + ((t + 1) & 31) * 64;
    #pragma unroll
    for (int p = 0; p < 8; ++p) {
      rs[p] = *reinterpret_cast<const uint4*>(Bb + (size_t)jn * 256 + offS[p]);
      rt[p] = *reinterpret_cast<const uint4*>(Btg + (size_t)jn + offT[p]);
    }
    int j0 = jc0 + t * 64;
    f32x4 sacc[4];
    #pragma unroll
    for (int n = 0; n < 4; ++n) sacc[n] = zero;
    #pragma unroll
    for (int kc = 0; kc < 8; ++kc)
      #pragma unroll
      for (int n = 0; n < 4; ++n) {
        bf16x8 b = *reinterpret_cast<const bf16x8*>(&BsU[(n * 8 + kc) * 64 + l]);
        sacc[n] = mfma16(qf[kc], b, sacc[n]);
      }
    #pragma unroll
    for (int n = 0; n < 4; ++n) {
      float sc = scj[j0 + n * 16 + r15];
      #pragma unroll
      for (int q = 0; q < 4; ++q) {
        float val = sacc[n][q] * ni[q] * sc;
        PsW[(g * 4 + q) * 72 + n * 16 + r15] = f2bf(val);
      }
    }
    #pragma unroll
    for (int kc2 = 0; kc2 < 2; ++kc2) {
      bf16x8 pa = *reinterpret_cast<const bf16x8*>(PsW + r15 * 72 + kc2 * 32 + g * 8);
      #pragma unroll
      for (int n2 = 0; n2 < 16; ++n2) {
        bf16x8 b = *reinterpret_cast<const bf16x8*>(&BtU[(n2 * 2 + kc2) * 64 + l]);
        oacc[n2] = mfma16(pa, b, oacc[n2]);
      }
    }
  }
  int io = i0 + w * 16 + g * 4;
  #pragma unroll
  for (int n2 = 0; n2 < 16; ++n2) {
    int c = n2 * 16 + r15;
    #pragma unroll
    for (int q = 0; q < 4; ++q)
      atomicAdd(&Out[(size_t)(io + q) * 256 + c], oacc[n2][q]);
  }
}

// ======================= match (fused prep, MFMA, bf16 out) =======================
__global__ __launch_bounds__(256) void k_match_bf2(const float* __restrict__ X, const float* __restrict__ Y,
                                                   int bx, int by, const u16* __restrict__ W2t,
                                                   u16* __restrict__ outb) {
  int w = threadIdx.x >> 6, l = threadIdx.x & 63, r15 = l & 15, g = l >> 4;
  int i0 = blockIdx.y * 64 + w * 16;
  int n0 = blockIdx.x * 128;
  f32x4 zero = {0.f, 0.f, 0.f, 0.f};
  f32x4 aU[8], aP[8], aQ[8];
  #pragma unroll
  for (int n = 0; n < 8; ++n) { aU[n] = zero; aP[n] = zero; aQ[n] = zero; }
  int row = i0 + r15;
  const float* xr = X + (size_t)(bx ? 0 : row) * 256;
  const float* yr = Y + (size_t)(by ? 0 : row) * 256;
  #pragma unroll 2
  for (int kc = 0; kc < 8; ++kc) {
    int base = kc * 32 + g * 8;
    float4 x0 = *reinterpret_cast<const float4*>(xr + base);
    float4 x1 = *reinterpret_cast<const float4*>(xr + base + 4);
    float4 y0 = *reinterpret_cast<const float4*>(yr + base);
    float4 y1 = *reinterpret_cast<const float4*>(yr + base + 4);
    bf16x8 fu, fp, fq;
    fu[0] = (__bf16)(x0.x * y0.x); fu[1] = (__bf16)(x0.y * y0.y);
    fu[2] = (__bf16)(x0.z * y0.z); fu[3] = (__bf16)(x0.w * y0.w);
    fu[4] = (__bf16)(x1.x * y1.x); fu[5] = (__bf16)(x1.y * y1.y);
    fu[6] = (__bf16)(x1.z * y1.z); fu[7] = (__bf16)(x1.w * y1.w);
    fp[0] = (__bf16)(x0.x * x0.x); fp[1] = (__bf16)(x0.y * x0.y);
    fp[2] = (__bf16)(x0.z * x0.z); fp[3] = (__bf16)(x0.w * x0.w);
    fp[4] = (__bf16)(x1.x * x1.x); fp[5] = (__bf16)(x1.y * x1.y);
    fp[6] = (__bf16)(x1.z * x1.z); fp[7] = (__bf16)(x1.w * x1.w);
    fq[0] = (__bf16)(y0.x * y0.x); fq[1] = (__bf16)(y0.y * y0.y);
    fq[2] = (__bf16)(y0.z * y0.z); fq[3] = (__bf16)(y0.w * y0.w);
    fq[4] = (__bf16)(y1.x * y1.x); fq[5] = (__bf16)(y1.y * y1.y);
    fq[6] = (__bf16)(y1.z * y1.z); fq[7] = (__bf16)(y1.w * y1.w);
    #pragma unroll
    for (int n = 0; n < 8; ++n) {
      bf16x8 b = *reinterpret_cast<const bf16x8*>(W2t + (size_t)(n0 + n * 16 + r15) * 256 + kc * 32 + g * 8);
      aU[n] = mfma16(fu, b, aU[n]);
      aP[n] = mfma16(fp, b, aP[n]);
      aQ[n] = mfma16(fq, b, aQ[n]);
    }
  }
  int io = i0 + g * 4;
  #pragma unroll
  for (int n = 0; n < 8; ++n) {
    int c = n0 + n * 16 + r15;
    #pragma unroll
    for (int q = 0; q < 4; ++q) {
      float s = sqrtf(aP[n][q]) * sqrtf(aQ[n][q]);
      outb[(size_t)(io + q) * 256 + c] = f2bf(aU[n][q] / fmaxf(s, FEPS));
    }
  }
}

// ======================= old f32 match (nout==1 only) =======================
__global__ __launch_bounds__(256) void k_match(const float* __restrict__ X, const float* __restrict__ Y,
                                               const float* __restrict__ W2, float* __restrict__ out,
                                               int nout, int bx, int by) {
  __shared__ float u[4][256], p[4][256], q[4][256];
  int nl = threadIdx.x >> 6;
  int ml = threadIdx.x & 63;
  int n = blockIdx.y * 4 + nl;
  int m = blockIdx.x * 64 + ml;
  for (int li = threadIdx.x; li < 4 * 256; li += 256) {
    int rr = li >> 8, dd = li & 255;
    int nn2 = blockIdx.y * 4 + rr;
    if (nn2 < nout) {
      float xv = X[(size_t)(bx ? 0 : nn2) * DDIM + dd];
      float yv = Y[(size_t)(by ? 0 : nn2) * DDIM + dd];
      u[rr][dd] = xv * yv; p[rr][dd] = xv * xv; q[rr][dd] = yv * yv;
    }
  }
  __syncthreads();
  if (n >= nout) return;
  float a = 0.f, b = 0.f, c = 0.f;
  #pragma unroll 4
  for (int d = 0; d < 256; ++d) {
    float wv = W2[(size_t)d * DDIM + m];
    a += u[nl][d] * wv; b += p[nl][d] * wv; c += q[nl][d] * wv;
  }
  out[(size_t)n * DDIM + m] = a / fmaxf(sqrtf(b) * sqrtf(c), FEPS);
}

__global__ void k_w2(const float* __restrict__ Wm, float* __restrict__ W2, int n) {
  int i = blockIdx.x * blockDim.x + threadIdx.x;
  if (i < n) { float v = Wm[i]; W2[i] = v * v; }
}

// ======================= batched readouts =======================
// colsum (f32 group): grid (64, nmat), 128 rows/block
__global__ void k_bmu_f(PLF L, float* __restrict__ mu) {
  const float* h = L.p[blockIdx.y];
  int d = threadIdx.x;
  int r0 = blockIdx.x * 128;
  float acc = 0.f;
  for (int r = 0; r < 128; ++r) acc += h[(size_t)(r0 + r) * 256 + d];
  atomicAdd(&mu[blockIdx.y * 256 + d], acc);
}

__global__ void k_bmu_b(PLB L, float* __restrict__ mu) {
  const u16* h = L.p[blockIdx.y];
  int d = threadIdx.x;
  int r0 = blockIdx.x * 128;
  float acc = 0.f;
  for (int r = 0; r < 128; ++r) acc += bf2f(h[(size_t)(r0 + r) * 256 + d]);
  atomicAdd(&mu[blockIdx.y * 256 + d], acc);
}

// g[m] = tanh(mean @ W_read): grid (nmat)
__global__ void k_bgv(const float* __restrict__ mu, const float* __restrict__ Wr,
                      float* __restrict__ g) {
  __shared__ float ls[256];
  int m = blockIdx.x, t = threadIdx.x;
  ls[t] = mu[m * 256 + t] * (1.f / (float)NN);
  __syncthreads();
  float acc = 0.f;
  #pragma unroll 4
  for (int d = 0; d < 256; ++d) acc += ls[d] * Wr[(size_t)d * 256 + t];
  g[m * 256 + t] = tanhf(acc);
}

// fused svec + weighted colsum (f32): grid (256, nmat), 32 rows/block
__global__ __launch_bounds__(256) void k_bsc_f(PLF L, const float* __restrict__ g,
                                               float* __restrict__ ogbase) {
  __shared__ __align__(16) float gs[256];
  __shared__ float sarr[32];
  int m = blockIdx.y;
  const float* h = L.p[m];
  int t = threadIdx.x, w = t >> 6, l = t & 63;
  gs[t] = g[m * 256 + t];
  __syncthreads();
  int r0 = blockIdx.x * 32;
  float4 gv4 = reinterpret_cast<const float4*>(gs)[l];
  for (int rr = w * 8; rr < w * 8 + 8; ++rr) {
    float4 hv = reinterpret_cast<const float4*>(h + (size_t)(r0 + rr) * 256)[l];
    float dot = hv.x * gv4.x + hv.y * gv4.y + hv.z * gv4.z + hv.w * gv4.w;
    #pragma unroll
    for (int o = 32; o > 0; o >>= 1) dot += __shfl_xor(dot, o);
    if (!l) sarr[rr] = 1.f / (1.f + expf(-dot));
  }
  __syncthreads();
  float acc = 0.f;
  for (int rr = 0; rr < 32; ++rr) acc += sarr[rr] * h[(size_t)(r0 + rr) * 256 + t];
  atomicAdd(&ogbase[m * 256 + t], acc);
}

__global__ __launch_bounds__(256) void k_bsc_b(PLB L, const float* __restrict__ g,
                                               float* __restrict__ v) {
  __shared__ __align__(16) float gs[256];
  __shared__ float sarr[32];
  int m = blockIdx.y;
  const u16* h = L.p[m];
  int t = threadIdx.x, w = t >> 6, l = t & 63;
  gs[t] = g[m * 256 + t];
  __syncthreads();
  int r0 = blockIdx.x * 32;
  float4 gv4 = reinterpret_cast<const float4*>(gs)[l];
  for (int rr = w * 8; rr < w * 8 + 8; ++rr) {
    ushort4 hv = *reinterpret_cast<const ushort4*>(h + (size_t)(r0 + rr) * 256 + l * 4);
    float dot = bf2f(hv.x) * gv4.x + bf2f(hv.y) * gv4.y + bf2f(hv.z) * gv4.z + bf2f(hv.w) * gv4.w;
    #pragma unroll
    for (int o = 32; o > 0; o >>= 1) dot += __shfl_xor(dot, o);
    if (!l) sarr[rr] = 1.f / (1.f + expf(-dot));
  }
  __syncthreads();
  float acc = 0.f;
  for (int rr = 0; rr < 32; ++rr) acc += sarr[rr] * bf2f(h[(size_t)(r0 + rr) * 256 + t]);
  atomicAdd(&v[L.slot[m] + t], acc);
}

// ======================= MLP =======================
__global__ void k_mlp(const float* __restrict__ v, const float* __restrict__ w,
                      const float* __restrict__ b, float* __restrict__ out,
                      int K, int M, int act) {
  __shared__ float lv[2048];
  for (int i = threadIdx.x; i < K; i += blockDim.x) lv[i] = v[i];
  __syncthreads();
  int m = blockIdx.x * blockDim.x + threadIdx.x;
  if (m >= M) return;
  float acc = b[m];
  for (int k = 0; k < K; ++k) acc += lv[k] * w[(size_t)k * M + m];
  if (act == 1) acc = fmaxf(acc, 0.f);
  out[m] = acc;
}

__global__ void k_final(const float* __restrict__ l3, const float* __restrict__ w4,
                        const float* __restrict__ b4, const int* __restrict__ label,
                        float* __restrict__ out) {
  __shared__ float ls[128];
  int t = threadIdx.x;
  ls[t] = l3[t] * w4[t];
  __syncthreads();
  for (int w = 64; w > 0; w >>= 1) { if (t < w) ls[t] += ls[t + w]; __syncthreads(); }
  if (t == 0) {
    float z = 1.f / (1.f + expf(-(ls[0] + b4[0])));
    out[0] = z;
    float lb = (float)label[0];
    out[1] = lb;
    out[2] = expf(-lb);
  }
}

// ======================= host =======================
extern "C" void kernel_launch(void* const* d_in, const int* in_sizes, int n_in,
                              void* d_out, int out_size, void* d_ws, size_t ws_size,
                              hipStream_t stream) {
  (void)in_sizes; (void)n_in; (void)out_size;
  const float* x_s   = (const float*)d_in[0];
  const float* x_t   = (const float*)d_in[1];
  const int*   ei_s  = (const int*)d_in[2];
  const int*   ei_t  = (const int*)d_in[3];
  const int*   label = (const int*)d_in[4];
  const float* W_g1  = (const float*)d_in[5];
  const float* a1s   = (const float*)d_in[6];
  const float* a1d   = (const float*)d_in[7];
  const float* W_g2  = (const float*)d_in[8];
  const float* a2s   = (const float*)d_in[9];
  const float* a2d   = (const float*)d_in[10];
  const float* W_read  = (const float*)d_in[11];
  const float* W_match = (const float*)d_in[12];
  const float* w1 = (const float*)d_in[13]; const float* b1 = (const float*)d_in[14];
  const float* w2 = (const float*)d_in[15]; const float* b2 = (const float*)d_in[16];
  const float* w3 = (const float*)d_in[17]; const float* b3 = (const float*)d_in[18];
  const float* w4 = (const float*)d_in[19]; const float* b4 = (const float*)d_in[20];
  float* out = (float*)d_out;

  char* base = (char*)d_ws;
  size_t off = 0;
  auto alloc = [&](size_t bytes) -> void* {
    void* pp = base + off;
    off = (off + bytes + 255) & ~(size_t)255;
    return pp;
  };
  double* dsum = (double*)alloc(4 * sizeof(double));
  u16*   hb_bf= (u16*)alloc((size_t)NN * HH * 2);         // 8MB
  u16*   aggb = (u16*)alloc((size_t)NN * HH * 2);         // 8MB
  float* h1   = (float*)alloc((size_t)NN * DDIM * 4);
  float* h2   = (float*)alloc((size_t)NN * DDIM * 4);
  float* h1m  = (float*)alloc((size_t)NN * DDIM * 4);
  float* h2m  = (float*)alloc((size_t)NN * DDIM * 4);
  u16*   f1b  = (u16*)alloc((size_t)NN * FF * 2);
  u16*   f2b  = (u16*)alloc((size_t)NN * FF * 2);
  u16*   h1b  = (u16*)alloc((size_t)NN * DDIM * 2);
  u16*   h2b  = (u16*)alloc((size_t)NN * DDIM * 2);
  u16*   h1t  = (u16*)alloc((size_t)NN * DDIM * 2);
  u16*   h2t  = (u16*)alloc((size_t)NN * DDIM * 2);
  u16*   mb0  = (u16*)alloc((size_t)NN * DDIM * 2);
  u16*   mb1  = (u16*)alloc((size_t)NN * DDIM * 2);
  u16*   mb2  = (u16*)alloc((size_t)NN * DDIM * 2);
  u16*   mb3  = (u16*)alloc((size_t)NN * DDIM * 2);
  u16*   mb4  = (u16*)alloc((size_t)NN * DDIM * 2);
  u16*   mb5  = (u16*)alloc((size_t)NN * DDIM * 2);
  float* alpha= (float*)alloc((size_t)ET * 4);
  int*   srcs = (int*)alloc((size_t)ET * 4);
  int*   deg  = (int*)alloc(NN * 4);
  int*   curs = (int*)alloc(NN * 4);
  int*   offs = (int*)alloc((NN + 1) * 4);
  float* n1inv= (float*)alloc(NN * 4);
  float* n2inv= (float*)alloc(NN * 4);
  float* Rr   = (float*)alloc(NN * 4);
  float* Ss   = (float*)alloc(NN * 4);
  float* scj1 = (float*)alloc(NN * 4);
  float* scj2 = (float*)alloc(NN * 4);
  float* hsb  = (float*)alloc(NN * 4);
  float* hdb  = (float*)alloc(NN * 4);
  float* W2   = (float*)alloc((size_t)DDIM * DDIM * 4);
  u16*   Wg1t = (u16*)alloc((size_t)HH * FF * 2);
  u16*   Wg2t = (u16*)alloc((size_t)DDIM * HH * 2);
  u16*   W2t  = (u16*)alloc((size_t)DDIM * DDIM * 2);
  float* mug1 = (float*)alloc(4 * 256 * 4);
  float* g1   = (float*)alloc(4 * 256 * 4);
  float* ogs  = (float*)alloc(4 * 256 * 4);
  float* mug2 = (float*)alloc(6 * 256 * 4);
  float* g2   = (float*)alloc(6 * 256 * 4);
  float* v    = (float*)alloc(2048 * 4);
  float* l1o  = (float*)alloc(512 * 4);
  float* l2o  = (float*)alloc(256 * 4);
  float* l3o  = (float*)alloc(128 * 4);
  if (off > ws_size) return;

  float* h1g  = ogs + 0;
  float* h2g  = ogs + 256;
  float* h1mg = ogs + 512;
  float* h2mg = ogs + 768;

  // ---- stage 0 ----
  hipMemsetAsync(dsum, 0, 4 * sizeof(double), stream);
  k_reduce<<<1024, 256, 0, stream>>>(x_s, NN * FF, dsum);
  k_reduce<<<1024, 256, 0, stream>>>(x_t, NN * FF, dsum + 2);
  k_normalize<<<1024, 256, 0, stream>>>(x_s, f1b, NN * FF, dsum);
  k_normalize<<<1024, 256, 0, stream>>>(x_t, f2b, NN * FF, dsum + 2);

  // ---- weight preps ----
  k_tr_bf16<<<dim3(HH / 32, FF / 32), 256, 0, stream>>>(W_g1, Wg1t, FF, HH, 0);
  k_tr_bf16<<<dim3(DDIM / 32, HH / 32), 256, 0, stream>>>(W_g2, Wg2t, HH, DDIM, 0);
  k_tr_bf16<<<dim3(DDIM / 32, DDIM / 32), 256, 0, stream>>>(W_match, W2t, DDIM, DDIM, 1);
  k_w2<<<dim3((DDIM * DDIM + 255) / 256), 256, 0, stream>>>(W_match, W2, DDIM * DDIM);

  // ---- GAT ----
  auto run_gat = [&](const u16* finb, const int* ei, float* hout, u16* houtb) {
    hipMemsetAsync(deg, 0, NN * 4, stream);
    k_hist<<<dim3((ET + 255) / 256), 256, 0, stream>>>(ei, deg);
    k_scan<<<1, 256, 0, stream>>>(deg, offs, curs);
    k_scatter<<<dim3((ET + 255) / 256), 256, 0, stream>>>(ei, curs, srcs);
    k_gemm_bf<<<dim3(HH / 128, NN / 64), 256, 0, stream>>>(finb, Wg1t, nullptr, hb_bf, FF, HH);
    k_node_dots_bf<<<dim3(NN / 4), 256, 0, stream>>>(hb_bf, a1s, a1d, hsb, hdb, HH);
    k_alpha<<<dim3(NN / 4), 256, 0, stream>>>(offs, srcs, hsb, hdb, alpha);
    k_agg2<<<dim3(NN), 256, 0, stream>>>(offs, srcs, alpha, hb_bf, nullptr, aggb, HH, 1);
    k_gemm_bf<<<dim3(DDIM / 128, NN / 64), 256, 0, stream>>>(aggb, Wg2t, nullptr, hb_bf, HH, DDIM);
    k_node_dots_bf<<<dim3(NN / 4), 256, 0, stream>>>(hb_bf, a2s, a2d, hsb, hdb, DDIM);
    k_alpha<<<dim3(NN / 4), 256, 0, stream>>>(offs, srcs, hsb, hdb, alpha);
    k_agg2<<<dim3(NN), 256, 0, stream>>>(offs, srcs, alpha, hb_bf, hout, houtb, DDIM, 0);
  };
  run_gat(f1b, ei_s, h1, h1b);
  run_gat(f2b, ei_t, h2, h2b);

  // ---- mutual ----
  k_rninv<<<dim3(NN / 4), 256, 0, stream>>>(h1, n1inv);
  k_rninv<<<dim3(NN / 4), 256, 0, stream>>>(h2, n2inv);
  k_tr_bf16<<<dim3(DDIM / 32, NN / 32), 256, 0, stream>>>(h1, h1t, NN, DDIM, 0);
  k_tr_bf16<<<dim3(DDIM / 32, NN / 32), 256, 0, stream>>>(h2, h2t, NN, DDIM, 0);
  hipMemsetAsync(Rr, 0, NN * 4, stream);
  hipMemsetAsync(Ss, 0, NN * 4, stream);
  k_sums_bf<<<dim3(4, NN / 64), 256, 0, stream>>>(h1b, h2b, n1inv, n2inv, Rr, Ss);
  k_scj<<<dim3(NN / 256), 256, 0, stream>>>(Ss, Rr, n1inv, n2inv, scj1, scj2);
  hipMemsetAsync(h1m, 0, (size_t)NN * DDIM * 4, stream);
  k_apply_bf<<<dim3(4, NN / 64), 256, 0, stream>>>(h1b, h2b, h2t, n1inv, scj1, h1m);
  hipMemsetAsync(h2m, 0, (size_t)NN * DDIM * 4, stream);
  k_apply_bf<<<dim3(4, NN / 64), 256, 0, stream>>>(h2b, h1b, h1t, n2inv, scj2, h2m);

  // ---- readout group 1: h1, h2, h1m, h2m ----
  PLF g1l; g1l.p[0] = h1; g1l.p[1] = h2; g1l.p[2] = h1m; g1l.p[3] = h2m;
  hipMemsetAsync(mug1, 0, 4 * 256 * 4, stream);
  hipMemsetAsync(ogs, 0, 4 * 256 * 4, stream);
  k_bmu_f<<<dim3(64, 4), 256, 0, stream>>>(g1l, mug1);
  k_bgv<<<dim3(4), 256, 0, stream>>>(mug1, W_read, g1);
  k_bsc_f<<<dim3(256, 4), 256, 0, stream>>>(g1l, g1, ogs);

  // ---- matches ----
  hipMemsetAsync(v, 0, 2048 * 4, stream);
  // order: [miu1g, phi1g, psi1g, om1, miu2g, phi2g, psi2g, om2]
  k_match_bf2<<<dim3(2, NN / 64), 256, 0, stream>>>(h1, h1m, 0, 0, W2t, mb0);
  k_match_bf2<<<dim3(2, NN / 64), 256, 0, stream>>>(h1, h1mg, 0, 1, W2t, mb1);
  k_match_bf2<<<dim3(2, NN / 64), 256, 0, stream>>>(h1g, h1m, 1, 0, W2t, mb2);
  k_match_bf2<<<dim3(2, NN / 64), 256, 0, stream>>>(h2, h2m, 0, 0, W2t, mb3);
  k_match_bf2<<<dim3(2, NN / 64), 256, 0, stream>>>(h2, h2mg, 0, 1, W2t, mb4);
  k_match_bf2<<<dim3(2, NN / 64), 256, 0, stream>>>(h2g, h2m, 1, 0, W2t, mb5);
  k_match<<<dim3(DDIM / 64, 1), 256, 0, stream>>>(h1g, h1mg, W2, v + 768, 1, 1, 1);
  k_match<<<dim3(DDIM / 64, 1), 256, 0, stream>>>(h2g, h2mg, W2, v + 1792, 1, 1, 1);

  // ---- readout group 2: 6 bf16 match outputs -> v slots ----
  PLB g2l;
  g2l.p[0] = mb0; g2l.slot[0] = 0;
  g2l.p[1] = mb1; g2l.slot[1] = 256;
  g2l.p[2] = mb2; g2l.slot[2] = 512;
  g2l.p[3] = mb3; g2l.slot[3] = 1024;
  g2l.p[4] = mb4; g2l.slot[4] = 1280;
  g2l.p[5] = mb5; g2l.slot[5] = 1536;
  hipMemsetAsync(mug2, 0, 6 * 256 * 4, stream);
  k_bmu_b<<<dim3(64, 6), 256, 0, stream>>>(g2l, mug2);
  k_bgv<<<dim3(6), 256, 0, stream>>>(mug2, W_read, g2);
  k_bsc_b<<<dim3(256, 6), 256, 0, stream>>>(g2l, g2, v);

  // ---- MLP ----
  k_mlp<<<dim3(2), 256, 0, stream>>>(v, w1, b1, l1o, 2048, 512, 1);
  k_mlp<<<dim3(1), 256, 0, stream>>>(l1o, w2, b2, l2o, 512, 256, 1);
  k_mlp<<<dim3(1), 256, 0, stream>>>(l2o, w3, b3, l3o, 256, 128, 1);
  k_final<<<1, 128, 0, stream>>>(l3o, w4, b4, label, out);
}

// Round 4
// 1316.835 us; speedup vs baseline: 5.0465x; 1.3450x over previous
//
#include <hip/hip_runtime.h>
#include <hip/hip_bf16.h>
#include <math.h>
#include <stddef.h>

#define NN 8192
#define FF 128
#define HH 512
#define DDIM 256
#define EE 131072
#define ET (2*EE + NN)     // 270336 edges after symmetrize + self loops
#define FEPS 1e-8f

typedef float f32x4 __attribute__((ext_vector_type(4)));
typedef __bf16 bf16x8 __attribute__((ext_vector_type(8)));
typedef unsigned short u16;

static __device__ __forceinline__ u16 f2bf(float f) {
  union { float f; unsigned u; } v; v.f = f;
  return (u16)((v.u + 0x7fffu + ((v.u >> 16) & 1u)) >> 16);
}
static __device__ __forceinline__ float bf2f(u16 h) {
  union { unsigned u; float f; } v; v.u = ((unsigned)h) << 16;
  return v.f;
}
static __device__ __forceinline__ f32x4 mfma16(bf16x8 a, bf16x8 b, f32x4 c) {
  return __builtin_amdgcn_mfma_f32_16x16x32_bf16(a, b, c, 0, 0, 0);
}
// async global->LDS, 16B per lane. AS casts via integer round-trip (generic LDS
// pointer's low 32 bits == LDS offset; flat addr == AS1 addr for global).
static __device__ __forceinline__ void gload16(const void* g, void* lds) {
  __builtin_amdgcn_global_load_lds(
      (const __attribute__((address_space(1))) void*)(unsigned long long)(uintptr_t)g,
      (__attribute__((address_space(3))) void*)(unsigned int)(uintptr_t)lds,
      16, 0, 0);
}

struct PLF { const float* p[4]; };
struct PLB { const u16* p[6]; int slot[6]; };

// ======================= stage 0: global mean/std normalize =======================
__global__ void k_reduce(const float* __restrict__ x, int n, double* __restrict__ out) {
  __shared__ double s1[256], s2[256];
  double a = 0.0, b = 0.0;
  for (int i = blockIdx.x * blockDim.x + threadIdx.x; i < n; i += gridDim.x * blockDim.x) {
    double v = (double)x[i];
    a += v; b += v * v;
  }
  s1[threadIdx.x] = a; s2[threadIdx.x] = b;
  __syncthreads();
  for (int w = 128; w > 0; w >>= 1) {
    if (threadIdx.x < w) { s1[threadIdx.x] += s1[threadIdx.x + w]; s2[threadIdx.x] += s2[threadIdx.x + w]; }
    __syncthreads();
  }
  if (threadIdx.x == 0) { atomicAdd(&out[0], s1[0]); atomicAdd(&out[1], s2[0]); }
}

__global__ void k_normalize(const float* __restrict__ x, u16* __restrict__ y, int n,
                            const double* __restrict__ s) {
  double mean = s[0] / (double)n;
  double var = (s[1] - (double)n * mean * mean) / (double)(n - 1);  // ddof=1
  float mu = (float)mean;
  float inv = (float)(1.0 / sqrt(var));
  for (int i = blockIdx.x * blockDim.x + threadIdx.x; i < n; i += gridDim.x * blockDim.x)
    y[i] = f2bf((x[i] - mu) * inv);
}

// ======================= GAT: CSR build =======================
__global__ void k_hist(const int* __restrict__ ei, int* __restrict__ deg) {
  int t = blockIdx.x * blockDim.x + threadIdx.x;
  if (t >= ET) return;
  int dst = (t < EE) ? ei[EE + t] : ((t < 2*EE) ? ei[t - EE] : (t - 2*EE));
  atomicAdd(&deg[dst], 1);
}

__global__ void k_scan(const int* __restrict__ deg, int* __restrict__ offs, int* __restrict__ cursor) {
  __shared__ int ts[256];
  int tid = threadIdx.x;
  int loc[32];
  int s = 0;
  #pragma unroll
  for (int i = 0; i < 32; ++i) { loc[i] = s; s += deg[tid * 32 + i]; }
  ts[tid] = s;
  __syncthreads();
  for (int off = 1; off < 256; off <<= 1) {
    int v = (tid >= off) ? ts[tid - off] : 0;
    __syncthreads();
    ts[tid] += v;
    __syncthreads();
  }
  int pre = ts[tid] - s;
  #pragma unroll
  for (int i = 0; i < 32; ++i) {
    int o = pre + loc[i];
    offs[tid * 32 + i] = o;
    cursor[tid * 32 + i] = o;
  }
  if (tid == 255) offs[NN] = ts[255];
}

__global__ void k_scatter(const int* __restrict__ ei, int* __restrict__ cursor, int* __restrict__ srcs) {
  int t = blockIdx.x * blockDim.x + threadIdx.x;
  if (t >= ET) return;
  int src = (t < 2*EE) ? ei[t] : (t - 2*EE);
  int dst = (t < EE) ? ei[EE + t] : ((t < 2*EE) ? ei[t - EE] : (t - 2*EE));
  int pos = atomicAdd(&cursor[dst], 1);
  srcs[pos] = src;
}

// ======================= transpose f32 -> bf16 (optionally squared) =======================
__global__ __launch_bounds__(256) void k_tr_bf16(const float* __restrict__ src, u16* __restrict__ dst,
                                                 int R, int C, int sq) {
  __shared__ float T[32][33];
  int tx = threadIdx.x & 31, ty = threadIdx.x >> 5;
  int r0 = blockIdx.y * 32, c0 = blockIdx.x * 32;
  #pragma unroll
  for (int p = 0; p < 4; ++p)
    T[ty + 8 * p][tx] = src[(size_t)(r0 + ty + 8 * p) * C + c0 + tx];
  __syncthreads();
  #pragma unroll
  for (int p = 0; p < 4; ++p) {
    float v = T[tx][ty + 8 * p];
    if (sq) v *= v;
    dst[(size_t)(c0 + ty + 8 * p) * R + r0 + tx] = f2bf(v);
  }
}

// ======================= generic MFMA GEMM: C[M,N] = A[M,K] @ Bt[N,K]^T =======================
__global__ __launch_bounds__(256) void k_gemm_bf(const u16* __restrict__ A, const u16* __restrict__ Bt,
                                                 float* __restrict__ Cf, u16* __restrict__ Cb,
                                                 int K, int N) {
  int w = threadIdx.x >> 6, l = threadIdx.x & 63, r15 = l & 15, g = l >> 4;
  int i0 = blockIdx.y * 64 + w * 16;
  int n0 = blockIdx.x * 128;
  f32x4 zero = {0.f, 0.f, 0.f, 0.f};
  f32x4 acc[8];
  #pragma unroll
  for (int n = 0; n < 8; ++n) acc[n] = zero;
  int kcN = K >> 5;
  const u16* arow = A + (size_t)(i0 + r15) * K + g * 8;
  for (int kc = 0; kc < kcN; ++kc) {
    bf16x8 a = *reinterpret_cast<const bf16x8*>(arow + kc * 32);
    #pragma unroll
    for (int n = 0; n < 8; ++n) {
      bf16x8 b = *reinterpret_cast<const bf16x8*>(Bt + (size_t)(n0 + n * 16 + r15) * K + kc * 32 + g * 8);
      acc[n] = mfma16(a, b, acc[n]);
    }
  }
  int io = i0 + g * 4;
  #pragma unroll
  for (int n = 0; n < 8; ++n) {
    int c = n0 + n * 16 + r15;
    #pragma unroll
    for (int q = 0; q < 4; ++q) {
      float vv = acc[n][q];
      if (Cf) Cf[(size_t)(io + q) * N + c] = vv;
      Cb[(size_t)(io + q) * N + c] = f2bf(vv);
    }
  }
}

// ======================= GAT: attention =======================
__global__ void k_node_dots_bf(const u16* __restrict__ Hb, const float* __restrict__ as_,
                               const float* __restrict__ ad_, float* __restrict__ hs,
                               float* __restrict__ hd, int D) {
  int wid = (blockIdx.x * blockDim.x + threadIdx.x) >> 6;
  int lane = threadIdx.x & 63;
  if (wid >= NN) return;
  float s = 0.f, d = 0.f;
  if (D == 512) {
    const u16* row = Hb + (size_t)wid * 512 + lane * 8;
    ushort4 v0 = *reinterpret_cast<const ushort4*>(row);
    ushort4 v1 = *reinterpret_cast<const ushort4*>(row + 4);
    const float4* ap = reinterpret_cast<const float4*>(as_ + lane * 8);
    const float4* dp = reinterpret_cast<const float4*>(ad_ + lane * 8);
    float4 a0 = ap[0], a1 = ap[1], e0 = dp[0], e1 = dp[1];
    float h0 = bf2f(v0.x), h1 = bf2f(v0.y), h2 = bf2f(v0.z), h3 = bf2f(v0.w);
    float h4 = bf2f(v1.x), h5 = bf2f(v1.y), h6 = bf2f(v1.z), h7 = bf2f(v1.w);
    s = h0*a0.x + h1*a0.y + h2*a0.z + h3*a0.w + h4*a1.x + h5*a1.y + h6*a1.z + h7*a1.w;
    d = h0*e0.x + h1*e0.y + h2*e0.z + h3*e0.w + h4*e1.x + h5*e1.y + h6*e1.z + h7*e1.w;
  } else {
    const u16* row = Hb + (size_t)wid * 256 + lane * 4;
    ushort4 v0 = *reinterpret_cast<const ushort4*>(row);
    float4 a0 = *reinterpret_cast<const float4*>(as_ + lane * 4);
    float4 e0 = *reinterpret_cast<const float4*>(ad_ + lane * 4);
    float h0 = bf2f(v0.x), h1 = bf2f(v0.y), h2 = bf2f(v0.z), h3 = bf2f(v0.w);
    s = h0*a0.x + h1*a0.y + h2*a0.z + h3*a0.w;
    d = h0*e0.x + h1*e0.y + h2*e0.z + h3*e0.w;
  }
  #pragma unroll
  for (int o = 32; o > 0; o >>= 1) { s += __shfl_xor(s, o); d += __shfl_xor(d, o); }
  if (!lane) { hs[wid] = s; hd[wid] = d; }
}

__global__ void k_alpha(const int* __restrict__ offs, const int* __restrict__ srcs,
                        const float* __restrict__ hs, const float* __restrict__ hd,
                        float* __restrict__ alpha) {
  int wid = (blockIdx.x * blockDim.x + threadIdx.x) >> 6;
  int lane = threadIdx.x & 63;
  if (wid >= NN) return;
  int b = offs[wid], e = offs[wid + 1];
  float hdn = hd[wid];
  float m = -3.4e38f;
  for (int p = b + lane; p < e; p += 64) {
    float v = hs[srcs[p]] + hdn;
    v = v > 0.f ? v : 0.2f * v;        // leaky_relu 0.2
    alpha[p] = v;
    m = fmaxf(m, v);
  }
  #pragma unroll
  for (int o = 32; o > 0; o >>= 1) m = fmaxf(m, __shfl_xor(m, o));
  float den = 0.f;
  for (int p = b + lane; p < e; p += 64) {
    float ex = expf(alpha[p] - m);
    alpha[p] = ex;
    den += ex;
  }
  #pragma unroll
  for (int o = 32; o > 0; o >>= 1) den += __shfl_xor(den, o);
  float sc = 1.f / (den + 1e-16f);
  for (int p = b + lane; p < e; p += 64) alpha[p] *= sc;
}

// wave-per-edge aggregate with 16B vector gathers; 4-wave LDS reduce
__global__ __launch_bounds__(256) void k_agg2(const int* __restrict__ offs, const int* __restrict__ srcs,
                                              const float* __restrict__ alpha, const u16* __restrict__ Hb,
                                              float* __restrict__ outF, u16* __restrict__ outB,
                                              int D, int elu) {
  __shared__ float red[4][512];
  int n = blockIdx.x;
  int b = offs[n], e = offs[n + 1];
  int w = threadIdx.x >> 6, lane = threadIdx.x & 63;
  float acc[8];
  #pragma unroll
  for (int j = 0; j < 8; ++j) acc[j] = 0.f;
  if (D == 512) {
    const u16* base = Hb + lane * 8;
    for (int p = b + w; p < e; p += 4) {
      float a = alpha[p];
      const u16* row = base + (size_t)srcs[p] * 512;
      ushort4 v0 = *reinterpret_cast<const ushort4*>(row);
      ushort4 v1 = *reinterpret_cast<const ushort4*>(row + 4);
      acc[0] += a * bf2f(v0.x); acc[1] += a * bf2f(v0.y);
      acc[2] += a * bf2f(v0.z); acc[3] += a * bf2f(v0.w);
      acc[4] += a * bf2f(v1.x); acc[5] += a * bf2f(v1.y);
      acc[6] += a * bf2f(v1.z); acc[7] += a * bf2f(v1.w);
    }
    #pragma unroll
    for (int j = 0; j < 8; ++j) red[w][lane * 8 + j] = acc[j];
  } else {
    const u16* base = Hb + lane * 4;
    for (int p = b + w; p < e; p += 4) {
      float a = alpha[p];
      const u16* row = base + (size_t)srcs[p] * 256;
      ushort4 v0 = *reinterpret_cast<const ushort4*>(row);
      acc[0] += a * bf2f(v0.x); acc[1] += a * bf2f(v0.y);
      acc[2] += a * bf2f(v0.z); acc[3] += a * bf2f(v0.w);
    }
    #pragma unroll
    for (int j = 0; j < 4; ++j) red[w][lane * 4 + j] = acc[j];
  }
  __syncthreads();
  for (int dd = threadIdx.x; dd < D; dd += 256) {
    float sres = red[0][dd] + red[1][dd] + red[2][dd] + red[3][dd];
    if (elu) sres = sres > 0.f ? sres : (expf(sres) - 1.f);
    if (outF) outF[(size_t)n * D + dd] = sres;
    outB[(size_t)n * D + dd] = f2bf(sres);
  }
}

// ======================= mutual: inverse row norms =======================
__global__ void k_rninv(const float* __restrict__ h, float* __restrict__ nrinv) {
  int wid = (blockIdx.x * blockDim.x + threadIdx.x) >> 6;
  int lane = threadIdx.x & 63;
  if (wid >= NN) return;
  float4 v = *reinterpret_cast<const float4*>(h + (size_t)wid * DDIM + lane * 4);
  float a = v.x * v.x + v.y * v.y + v.z * v.z + v.w * v.w;
  #pragma unroll
  for (int o = 32; o > 0; o >>= 1) a += __shfl_xor(a, o);
  if (!lane) nrinv[wid] = 1.f / sqrtf(a);
}

// ======================= mutual sums: R[i]=sum_j cos, S[j]=sum_i cos =======================
// 2-phase pipelined, global_load_lds double-buffered staging. grid (4, 128), block 256.
__global__ __launch_bounds__(256, 2) void k_sums_bf(const u16* __restrict__ Ab, const u16* __restrict__ Bb,
                                                    const float* __restrict__ nainv, const float* __restrict__ nbinv,
                                                    float* __restrict__ R, float* __restrict__ S) {
  __shared__ uint4 Bs2[2][2048];
  __shared__ float Scol[2048];
  int tid = threadIdx.x;
  int w = tid >> 6, l = tid & 63, r15 = l & 15, g = l >> 4;
  int i0 = blockIdx.y * 64;
  int jc0 = blockIdx.x * 2048;
  for (int s = tid; s < 2048; s += 256) Scol[s] = 0.f;
  bf16x8 qf[8];
  const u16* arow = Ab + (size_t)(i0 + w * 16 + r15) * 256 + g * 8;
  #pragma unroll
  for (int kc = 0; kc < 8; ++kc) qf[kc] = *reinterpret_cast<const bf16x8*>(arow + kc * 32);
  float ni[4];
  #pragma unroll
  for (int q = 0; q < 4; ++q) ni[q] = nainv[i0 + w * 16 + g * 4 + q];
  int offS[8];
  #pragma unroll
  for (int p = 0; p < 8; ++p) {
    int c = p * 256 + tid;
    int frag = c >> 6, n = frag >> 3, kc = frag & 7;
    int ll = c & 63, gg = ll >> 4, jr = ll & 15;
    offS[p] = (n * 16 + jr) * 256 + kc * 32 + gg * 8;
  }
  auto stage = [&](int buf, int j0) {
    const u16* bs = Bb + (size_t)j0 * 256;
    #pragma unroll
    for (int p = 0; p < 8; ++p)
      gload16(bs + offS[p], &Bs2[buf][p * 256 + tid]);
  };
  float rowacc[4] = {0.f, 0.f, 0.f, 0.f};
  f32x4 zero = {0.f, 0.f, 0.f, 0.f};
  stage(0, jc0);
  __syncthreads();
  int cur = 0;
  for (int t = 0; t < 32; ++t) {
    if (t < 31) stage(cur ^ 1, jc0 + (t + 1) * 64);
    int j0 = jc0 + t * 64;
    f32x4 sacc[4];
    #pragma unroll
    for (int n = 0; n < 4; ++n) sacc[n] = zero;
    #pragma unroll
    for (int kc = 0; kc < 8; ++kc)
      #pragma unroll
      for (int n = 0; n < 4; ++n) {
        bf16x8 b = *reinterpret_cast<const bf16x8*>(&Bs2[cur][(n * 8 + kc) * 64 + l]);
        sacc[n] = mfma16(qf[kc], b, sacc[n]);
      }
    #pragma unroll
    for (int n = 0; n < 4; ++n) {
      float nb = nbinv[j0 + n * 16 + r15];
      float cs = 0.f;
      #pragma unroll
      for (int q = 0; q < 4; ++q) {
        float cv = sacc[n][q] * ni[q] * nb;
        rowacc[q] += cv;
        cs += cv;
      }
      cs += __shfl_xor(cs, 16);
      cs += __shfl_xor(cs, 32);
      if (l < 16) atomicAdd(&Scol[t * 64 + n * 16 + l], cs);
    }
    __syncthreads();   // drains vmcnt: stage(t+1) complete; Scol atomics ordered
    cur ^= 1;
  }
  #pragma unroll
  for (int q = 0; q < 4; ++q) {
    float v = rowacc[q];
    v += __shfl_xor(v, 1); v += __shfl_xor(v, 2); v += __shfl_xor(v, 4); v += __shfl_xor(v, 8);
    if (r15 == 0) atomicAdd(&R[i0 + w * 16 + g * 4 + q], v);
  }
  for (int s = tid; s < 2048; s += 256) atomicAdd(&S[jc0 + s], Scol[s]);
}

__global__ void k_scj(const float* __restrict__ S, const float* __restrict__ R,
                      const float* __restrict__ n1inv, const float* __restrict__ n2inv,
                      float* __restrict__ scj1, float* __restrict__ scj2) {
  int j = blockIdx.x * blockDim.x + threadIdx.x;
  if (j >= NN) return;
  scj1[j] = n2inv[j] / S[j];
  scj2[j] = n1inv[j] / R[j];
}

// ======================= mutual apply (flash, MFMA, gload_lds 2-phase dbuf) =======================
// Out[i,:] += sum_j (dot(A_i,B_j)*nainv[i]*scj[j]) * B[j,:].  grid (4, 128), block 256.
__global__ __launch_bounds__(256, 1) void k_apply_bf(const u16* __restrict__ Ab, const u16* __restrict__ Bb,
                                                     const u16* __restrict__ Btg, const float* __restrict__ nainv,
                                                     const float* __restrict__ scj, float* __restrict__ Out) {
  __shared__ uint4 Bs2[2][2048];              // S-orientation frags (B[j][k]), dbuf
  __shared__ uint4 Bt2[2][2048];              // PV-orientation frags (B^T), dbuf
  __shared__ __align__(16) u16 Ps[4 * 16 * 72];
  int tid = threadIdx.x;
  int w = tid >> 6, l = tid & 63, r15 = l & 15, g = l >> 4;
  int i0 = blockIdx.y * 64;
  int jc0 = blockIdx.x * 2048;
  bf16x8 qf[8];
  const u16* arow = Ab + (size_t)(i0 + w * 16 + r15) * 256 + g * 8;
  #pragma unroll
  for (int kc = 0; kc < 8; ++kc) qf[kc] = *reinterpret_cast<const bf16x8*>(arow + kc * 32);
  float ni[4];
  #pragma unroll
  for (int q = 0; q < 4; ++q) ni[q] = nainv[i0 + w * 16 + g * 4 + q];
  int offS[8], offT[8];
  #pragma unroll
  for (int p = 0; p < 8; ++p) {
    int c = p * 256 + tid;
    int ll = c & 63, gg = ll >> 4, jr = ll & 15;
    int frag = c >> 6;
    int n = frag >> 3, kc = frag & 7;
    offS[p] = (n * 16 + jr) * 256 + kc * 32 + gg * 8;
    int n2 = frag >> 1, kc2 = frag & 1;
    offT[p] = (n2 * 16 + jr) * NN + kc2 * 32 + gg * 8;
  }
  auto stage = [&](int buf, int j0) {
    const u16* bs = Bb + (size_t)j0 * 256;
    const u16* ts = Btg + (size_t)j0;
    #pragma unroll
    for (int p = 0; p < 8; ++p) {
      gload16(bs + offS[p], &Bs2[buf][p * 256 + tid]);
      gload16(ts + offT[p], &Bt2[buf][p * 256 + tid]);
    }
  };
  f32x4 zero = {0.f, 0.f, 0.f, 0.f};
  f32x4 oacc[16];
  #pragma unroll
  for (int n = 0; n < 16; ++n) oacc[n] = zero;
  u16* PsW = Ps + w * 16 * 72;
  stage(0, jc0);
  __syncthreads();
  int cur = 0;
  for (int t = 0; t < 32; ++t) {
    if (t < 31) stage(cur ^ 1, jc0 + (t + 1) * 64);   // in flight during compute
    int j0 = jc0 + t * 64;
    // QK: scores for this wave's 16 rows x 64 j
    f32x4 sacc[4];
    #pragma unroll
    for (int n = 0; n < 4; ++n) sacc[n] = zero;
    #pragma unroll
    for (int kc = 0; kc < 8; ++kc)
      #pragma unroll
      for (int n = 0; n < 4; ++n) {
        bf16x8 b = *reinterpret_cast<const bf16x8*>(&Bs2[cur][(n * 8 + kc) * 64 + l]);
        sacc[n] = mfma16(qf[kc], b, sacc[n]);
      }
    // scale -> per-wave P tile (bf16) in LDS
    #pragma unroll
    for (int n = 0; n < 4; ++n) {
      float sc = scj[j0 + n * 16 + r15];
      #pragma unroll
      for (int q = 0; q < 4; ++q) {
        float val = sacc[n][q] * ni[q] * sc;
        PsW[(g * 4 + q) * 72 + n * 16 + r15] = f2bf(val);
      }
    }
    // PV: oacc[i, d] += P[i, j] * B[j, d]
    #pragma unroll
    for (int kc2 = 0; kc2 < 2; ++kc2) {
      bf16x8 pa = *reinterpret_cast<const bf16x8*>(PsW + r15 * 72 + kc2 * 32 + g * 8);
      #pragma unroll
      for (int n2 = 0; n2 < 16; ++n2) {
        bf16x8 b = *reinterpret_cast<const bf16x8*>(&Bt2[cur][(n2 * 2 + kc2) * 64 + l]);
        oacc[n2] = mfma16(pa, b, oacc[n2]);
      }
    }
    __syncthreads();   // drains vmcnt(0): next buffer staged & all reads of cur done
    cur ^= 1;
  }
  int io = i0 + w * 16 + g * 4;
  #pragma unroll
  for (int n2 = 0; n2 < 16; ++n2) {
    int c = n2 * 16 + r15;
    #pragma unroll
    for (int q = 0; q < 4; ++q)
      atomicAdd(&Out[(size_t)(io + q) * 256 + c], oacc[n2][q]);
  }
}

// ======================= match (fused prep, MFMA, bf16 out) =======================
__global__ __launch_bounds__(256) void k_match_bf2(const float* __restrict__ X, const float* __restrict__ Y,
                                                   int bx, int by, const u16* __restrict__ W2t,
                                                   u16* __restrict__ outb) {
  int w = threadIdx.x >> 6, l = threadIdx.x & 63, r15 = l & 15, g = l >> 4;
  int i0 = blockIdx.y * 64 + w * 16;
  int n0 = blockIdx.x * 128;
  f32x4 zero = {0.f, 0.f, 0.f, 0.f};
  f32x4 aU[8], aP[8], aQ[8];
  #pragma unroll
  for (int n = 0; n < 8; ++n) { aU[n] = zero; aP[n] = zero; aQ[n] = zero; }
  int row = i0 + r15;
  const float* xr = X + (size_t)(bx ? 0 : row) * 256;
  const float* yr = Y + (size_t)(by ? 0 : row) * 256;
  #pragma unroll 2
  for (int kc = 0; kc < 8; ++kc) {
    int base = kc * 32 + g * 8;
    float4 x0 = *reinterpret_cast<const float4*>(xr + base);
    float4 x1 = *reinterpret_cast<const float4*>(xr + base + 4);
    float4 y0 = *reinterpret_cast<const float4*>(yr + base);
    float4 y1 = *reinterpret_cast<const float4*>(yr + base + 4);
    bf16x8 fu, fp, fq;
    fu[0] = (__bf16)(x0.x * y0.x); fu[1] = (__bf16)(x0.y * y0.y);
    fu[2] = (__bf16)(x0.z * y0.z); fu[3] = (__bf16)(x0.w * y0.w);
    fu[4] = (__bf16)(x1.x * y1.x); fu[5] = (__bf16)(x1.y * y1.y);
    fu[6] = (__bf16)(x1.z * y1.z); fu[7] = (__bf16)(x1.w * y1.w);
    fp[0] = (__bf16)(x0.x * x0.x); fp[1] = (__bf16)(x0.y * x0.y);
    fp[2] = (__bf16)(x0.z * x0.z); fp[3] = (__bf16)(x0.w * x0.w);
    fp[4] = (__bf16)(x1.x * x1.x); fp[5] = (__bf16)(x1.y * x1.y);
    fp[6] = (__bf16)(x1.z * x1.z); fp[7] = (__bf16)(x1.w * x1.w);
    fq[0] = (__bf16)(y0.x * y0.x); fq[1] = (__bf16)(y0.y * y0.y);
    fq[2] = (__bf16)(y0.z * y0.z); fq[3] = (__bf16)(y0.w * y0.w);
    fq[4] = (__bf16)(y1.x * y1.x); fq[5] = (__bf16)(y1.y * y1.y);
    fq[6] = (__bf16)(y1.z * y1.z); fq[7] = (__bf16)(y1.w * y1.w);
    #pragma unroll
    for (int n = 0; n < 8; ++n) {
      bf16x8 b = *reinterpret_cast<const bf16x8*>(W2t + (size_t)(n0 + n * 16 + r15) * 256 + kc * 32 + g * 8);
      aU[n] = mfma16(fu, b, aU[n]);
      aP[n] = mfma16(fp, b, aP[n]);
      aQ[n] = mfma16(fq, b, aQ[n]);
    }
  }
  int io = i0 + g * 4;
  #pragma unroll
  for (int n = 0; n < 8; ++n) {
    int c = n0 + n * 16 + r15;
    #pragma unroll
    for (int q = 0; q < 4; ++q) {
      float s = sqrtf(aP[n][q]) * sqrtf(aQ[n][q]);
      outb[(size_t)(io + q) * 256 + c] = f2bf(aU[n][q] / fmaxf(s, FEPS));
    }
  }
}

// ======================= old f32 match (nout==1 only) =======================
__global__ __launch_bounds__(256) void k_match(const float* __restrict__ X, const float* __restrict__ Y,
                                               const float* __restrict__ W2, float* __restrict__ out,
                                               int nout, int bx, int by) {
  __shared__ float u[4][256], p[4][256], q[4][256];
  int nl = threadIdx.x >> 6;
  int ml = threadIdx.x & 63;
  int n = blockIdx.y * 4 + nl;
  int m = blockIdx.x * 64 + ml;
  for (int li = threadIdx.x; li < 4 * 256; li += 256) {
    int rr = li >> 8, dd = li & 255;
    int nn2 = blockIdx.y * 4 + rr;
    if (nn2 < nout) {
      float xv = X[(size_t)(bx ? 0 : nn2) * DDIM + dd];
      float yv = Y[(size_t)(by ? 0 : nn2) * DDIM + dd];
      u[rr][dd] = xv * yv; p[rr][dd] = xv * xv; q[rr][dd] = yv * yv;
    }
  }
  __syncthreads();
  if (n >= nout) return;
  float a = 0.f, b = 0.f, c = 0.f;
  #pragma unroll 4
  for (int d = 0; d < 256; ++d) {
    float wv = W2[(size_t)d * DDIM + m];
    a += u[nl][d] * wv; b += p[nl][d] * wv; c += q[nl][d] * wv;
  }
  out[(size_t)n * DDIM + m] = a / fmaxf(sqrtf(b) * sqrtf(c), FEPS);
}

__global__ void k_w2(const float* __restrict__ Wm, float* __restrict__ W2, int n) {
  int i = blockIdx.x * blockDim.x + threadIdx.x;
  if (i < n) { float v = Wm[i]; W2[i] = v * v; }
}

// ======================= batched readouts =======================
__global__ void k_bmu_f(PLF L, float* __restrict__ mu) {
  const float* h = L.p[blockIdx.y];
  int d = threadIdx.x;
  int r0 = blockIdx.x * 128;
  float acc = 0.f;
  for (int r = 0; r < 128; ++r) acc += h[(size_t)(r0 + r) * 256 + d];
  atomicAdd(&mu[blockIdx.y * 256 + d], acc);
}

__global__ void k_bmu_b(PLB L, float* __restrict__ mu) {
  const u16* h = L.p[blockIdx.y];
  int d = threadIdx.x;
  int r0 = blockIdx.x * 128;
  float acc = 0.f;
  for (int r = 0; r < 128; ++r) acc += bf2f(h[(size_t)(r0 + r) * 256 + d]);
  atomicAdd(&mu[blockIdx.y * 256 + d], acc);
}

__global__ void k_bgv(const float* __restrict__ mu, const float* __restrict__ Wr,
                      float* __restrict__ g) {
  __shared__ float ls[256];
  int m = blockIdx.x, t = threadIdx.x;
  ls[t] = mu[m * 256 + t] * (1.f / (float)NN);
  __syncthreads();
  float acc = 0.f;
  #pragma unroll 4
  for (int d = 0; d < 256; ++d) acc += ls[d] * Wr[(size_t)d * 256 + t];
  g[m * 256 + t] = tanhf(acc);
}

__global__ __launch_bounds__(256) void k_bsc_f(PLF L, const float* __restrict__ g,
                                               float* __restrict__ ogbase) {
  __shared__ __align__(16) float gs[256];
  __shared__ float sarr[32];
  int m = blockIdx.y;
  const float* h = L.p[m];
  int t = threadIdx.x, w = t >> 6, l = t & 63;
  gs[t] = g[m * 256 + t];
  __syncthreads();
  int r0 = blockIdx.x * 32;
  float4 gv4 = reinterpret_cast<const float4*>(gs)[l];
  for (int rr = w * 8; rr < w * 8 + 8; ++rr) {
    float4 hv = reinterpret_cast<const float4*>(h + (size_t)(r0 + rr) * 256)[l];
    float dot = hv.x * gv4.x + hv.y * gv4.y + hv.z * gv4.z + hv.w * gv4.w;
    #pragma unroll
    for (int o = 32; o > 0; o >>= 1) dot += __shfl_xor(dot, o);
    if (!l) sarr[rr] = 1.f / (1.f + expf(-dot));
  }
  __syncthreads();
  float acc = 0.f;
  for (int rr = 0; rr < 32; ++rr) acc += sarr[rr] * h[(size_t)(r0 + rr) * 256 + t];
  atomicAdd(&ogbase[m * 256 + t], acc);
}

__global__ __launch_bounds__(256) void k_bsc_b(PLB L, const float* __restrict__ g,
                                               float* __restrict__ v) {
  __shared__ __align__(16) float gs[256];
  __shared__ float sarr[32];
  int m = blockIdx.y;
  const u16* h = L.p[m];
  int t = threadIdx.x, w = t >> 6, l = t & 63;
  gs[t] = g[m * 256 + t];
  __syncthreads();
  int r0 = blockIdx.x * 32;
  float4 gv4 = reinterpret_cast<const float4*>(gs)[l];
  for (int rr = w * 8; rr < w * 8 + 8; ++rr) {
    ushort4 hv = *reinterpret_cast<const ushort4*>(h + (size_t)(r0 + rr) * 256 + l * 4);
    float dot = bf2f(hv.x) * gv4.x + bf2f(hv.y) * gv4.y + bf2f(hv.z) * gv4.z + bf2f(hv.w) * gv4.w;
    #pragma unroll
    for (int o = 32; o > 0; o >>= 1) dot += __shfl_xor(dot, o);
    if (!l) sarr[rr] = 1.f / (1.f + expf(-dot));
  }
  __syncthreads();
  float acc = 0.f;
  for (int rr = 0; rr < 32; ++rr) acc += sarr[rr] * bf2f(h[(size_t)(r0 + rr) * 256 + t]);
  atomicAdd(&v[L.slot[m] + t], acc);
}

// ======================= MLP =======================
__global__ void k_mlp(const float* __restrict__ v, const float* __restrict__ w,
                      const float* __restrict__ b, float* __restrict__ out,
                      int K, int M, int act) {
  __shared__ float lv[2048];
  for (int i = threadIdx.x; i < K; i += blockDim.x) lv[i] = v[i];
  __syncthreads();
  int m = blockIdx.x * blockDim.x + threadIdx.x;
  if (m >= M) return;
  float acc = b[m];
  for (int k = 0; k < K; ++k) acc += lv[k] * w[(size_t)k * M + m];
  if (act == 1) acc = fmaxf(acc, 0.f);
  out[m] = acc;
}

__global__ void k_final(const float* __restrict__ l3, const float* __restrict__ w4,
                        const float* __restrict__ b4, const int* __restrict__ label,
                        float* __restrict__ out) {
  __shared__ float ls[128];
  int t = threadIdx.x;
  ls[t] = l3[t] * w4[t];
  __syncthreads();
  for (int w = 64; w > 0; w >>= 1) { if (t < w) ls[t] += ls[t + w]; __syncthreads(); }
  if (t == 0) {
    float z = 1.f / (1.f + expf(-(ls[0] + b4[0])));
    out[0] = z;
    float lb = (float)label[0];
    out[1] = lb;
    out[2] = expf(-lb);
  }
}

// ======================= host =======================
extern "C" void kernel_launch(void* const* d_in, const int* in_sizes, int n_in,
                              void* d_out, int out_size, void* d_ws, size_t ws_size,
                              hipStream_t stream) {
  (void)in_sizes; (void)n_in; (void)out_size;
  const float* x_s   = (const float*)d_in[0];
  const float* x_t   = (const float*)d_in[1];
  const int*   ei_s  = (const int*)d_in[2];
  const int*   ei_t  = (const int*)d_in[3];
  const int*   label = (const int*)d_in[4];
  const float* W_g1  = (const float*)d_in[5];
  const float* a1s   = (const float*)d_in[6];
  const float* a1d   = (const float*)d_in[7];
  const float* W_g2  = (const float*)d_in[8];
  const float* a2s   = (const float*)d_in[9];
  const float* a2d   = (const float*)d_in[10];
  const float* W_read  = (const float*)d_in[11];
  const float* W_match = (const float*)d_in[12];
  const float* w1 = (const float*)d_in[13]; const float* b1 = (const float*)d_in[14];
  const float* w2 = (const float*)d_in[15]; const float* b2 = (const float*)d_in[16];
  const float* w3 = (const float*)d_in[17]; const float* b3 = (const float*)d_in[18];
  const float* w4 = (const float*)d_in[19]; const float* b4 = (const float*)d_in[20];
  float* out = (float*)d_out;

  char* base = (char*)d_ws;
  size_t off = 0;
  auto alloc = [&](size_t bytes) -> void* {
    void* pp = base + off;
    off = (off + bytes + 255) & ~(size_t)255;
    return pp;
  };
  double* dsum = (double*)alloc(4 * sizeof(double));
  u16*   hb_bf= (u16*)alloc((size_t)NN * HH * 2);
  u16*   aggb = (u16*)alloc((size_t)NN * HH * 2);
  float* h1   = (float*)alloc((size_t)NN * DDIM * 4);
  float* h2   = (float*)alloc((size_t)NN * DDIM * 4);
  float* h1m  = (float*)alloc((size_t)NN * DDIM * 4);
  float* h2m  = (float*)alloc((size_t)NN * DDIM * 4);
  u16*   f1b  = (u16*)alloc((size_t)NN * FF * 2);
  u16*   f2b  = (u16*)alloc((size_t)NN * FF * 2);
  u16*   h1b  = (u16*)alloc((size_t)NN * DDIM * 2);
  u16*   h2b  = (u16*)alloc((size_t)NN * DDIM * 2);
  u16*   h1t  = (u16*)alloc((size_t)NN * DDIM * 2);
  u16*   h2t  = (u16*)alloc((size_t)NN * DDIM * 2);
  u16*   mb0  = (u16*)alloc((size_t)NN * DDIM * 2);
  u16*   mb1  = (u16*)alloc((size_t)NN * DDIM * 2);
  u16*   mb2  = (u16*)alloc((size_t)NN * DDIM * 2);
  u16*   mb3  = (u16*)alloc((size_t)NN * DDIM * 2);
  u16*   mb4  = (u16*)alloc((size_t)NN * DDIM * 2);
  u16*   mb5  = (u16*)alloc((size_t)NN * DDIM * 2);
  float* alpha= (float*)alloc((size_t)ET * 4);
  int*   srcs = (int*)alloc((size_t)ET * 4);
  int*   deg  = (int*)alloc(NN * 4);
  int*   curs = (int*)alloc(NN * 4);
  int*   offs = (int*)alloc((NN + 1) * 4);
  float* n1inv= (float*)alloc(NN * 4);
  float* n2inv= (float*)alloc(NN * 4);
  float* Rr   = (float*)alloc(NN * 4);
  float* Ss   = (float*)alloc(NN * 4);
  float* scj1 = (float*)alloc(NN * 4);
  float* scj2 = (float*)alloc(NN * 4);
  float* hsb  = (float*)alloc(NN * 4);
  float* hdb  = (float*)alloc(NN * 4);
  float* W2   = (float*)alloc((size_t)DDIM * DDIM * 4);
  u16*   Wg1t = (u16*)alloc((size_t)HH * FF * 2);
  u16*   Wg2t = (u16*)alloc((size_t)DDIM * HH * 2);
  u16*   W2t  = (u16*)alloc((size_t)DDIM * DDIM * 2);
  float* mug1 = (float*)alloc(4 * 256 * 4);
  float* g1   = (float*)alloc(4 * 256 * 4);
  float* ogs  = (float*)alloc(4 * 256 * 4);
  float* mug2 = (float*)alloc(6 * 256 * 4);
  float* g2   = (float*)alloc(6 * 256 * 4);
  float* v    = (float*)alloc(2048 * 4);
  float* l1o  = (float*)alloc(512 * 4);
  float* l2o  = (float*)alloc(256 * 4);
  float* l3o  = (float*)alloc(128 * 4);
  if (off > ws_size) return;

  float* h1g  = ogs + 0;
  float* h2g  = ogs + 256;
  float* h1mg = ogs + 512;
  float* h2mg = ogs + 768;

  // ---- stage 0 ----
  hipMemsetAsync(dsum, 0, 4 * sizeof(double), stream);
  k_reduce<<<1024, 256, 0, stream>>>(x_s, NN * FF, dsum);
  k_reduce<<<1024, 256, 0, stream>>>(x_t, NN * FF, dsum + 2);
  k_normalize<<<1024, 256, 0, stream>>>(x_s, f1b, NN * FF, dsum);
  k_normalize<<<1024, 256, 0, stream>>>(x_t, f2b, NN * FF, dsum + 2);

  // ---- weight preps ----
  k_tr_bf16<<<dim3(HH / 32, FF / 32), 256, 0, stream>>>(W_g1, Wg1t, FF, HH, 0);
  k_tr_bf16<<<dim3(DDIM / 32, HH / 32), 256, 0, stream>>>(W_g2, Wg2t, HH, DDIM, 0);
  k_tr_bf16<<<dim3(DDIM / 32, DDIM / 32), 256, 0, stream>>>(W_match, W2t, DDIM, DDIM, 1);
  k_w2<<<dim3((DDIM * DDIM + 255) / 256), 256, 0, stream>>>(W_match, W2, DDIM * DDIM);

  // ---- GAT ----
  auto run_gat = [&](const u16* finb, const int* ei, float* hout, u16* houtb) {
    hipMemsetAsync(deg, 0, NN * 4, stream);
    k_hist<<<dim3((ET + 255) / 256), 256, 0, stream>>>(ei, deg);
    k_scan<<<1, 256, 0, stream>>>(deg, offs, curs);
    k_scatter<<<dim3((ET + 255) / 256), 256, 0, stream>>>(ei, curs, srcs);
    k_gemm_bf<<<dim3(HH / 128, NN / 64), 256, 0, stream>>>(finb, Wg1t, nullptr, hb_bf, FF, HH);
    k_node_dots_bf<<<dim3(NN / 4), 256, 0, stream>>>(hb_bf, a1s, a1d, hsb, hdb, HH);
    k_alpha<<<dim3(NN / 4), 256, 0, stream>>>(offs, srcs, hsb, hdb, alpha);
    k_agg2<<<dim3(NN), 256, 0, stream>>>(offs, srcs, alpha, hb_bf, nullptr, aggb, HH, 1);
    k_gemm_bf<<<dim3(DDIM / 128, NN / 64), 256, 0, stream>>>(aggb, Wg2t, nullptr, hb_bf, HH, DDIM);
    k_node_dots_bf<<<dim3(NN / 4), 256, 0, stream>>>(hb_bf, a2s, a2d, hsb, hdb, DDIM);
    k_alpha<<<dim3(NN / 4), 256, 0, stream>>>(offs, srcs, hsb, hdb, alpha);
    k_agg2<<<dim3(NN), 256, 0, stream>>>(offs, srcs, alpha, hb_bf, hout, houtb, DDIM, 0);
  };
  run_gat(f1b, ei_s, h1, h1b);
  run_gat(f2b, ei_t, h2, h2b);

  // ---- mutual ----
  k_rninv<<<dim3(NN / 4), 256, 0, stream>>>(h1, n1inv);
  k_rninv<<<dim3(NN / 4), 256, 0, stream>>>(h2, n2inv);
  k_tr_bf16<<<dim3(DDIM / 32, NN / 32), 256, 0, stream>>>(h1, h1t, NN, DDIM, 0);
  k_tr_bf16<<<dim3(DDIM / 32, NN / 32), 256, 0, stream>>>(h2, h2t, NN, DDIM, 0);
  hipMemsetAsync(Rr, 0, NN * 4, stream);
  hipMemsetAsync(Ss, 0, NN * 4, stream);
  k_sums_bf<<<dim3(4, NN / 64), 256, 0, stream>>>(h1b, h2b, n1inv, n2inv, Rr, Ss);
  k_scj<<<dim3(NN / 256), 256, 0, stream>>>(Ss, Rr, n1inv, n2inv, scj1, scj2);
  hipMemsetAsync(h1m, 0, (size_t)NN * DDIM * 4, stream);
  k_apply_bf<<<dim3(4, NN / 64), 256, 0, stream>>>(h1b, h2b, h2t, n1inv, scj1, h1m);
  hipMemsetAsync(h2m, 0, (size_t)NN * DDIM * 4, stream);
  k_apply_bf<<<dim3(4, NN / 64), 256, 0, stream>>>(h2b, h1b, h1t, n2inv, scj2, h2m);

  // ---- readout group 1: h1, h2, h1m, h2m ----
  PLF g1l; g1l.p[0] = h1; g1l.p[1] = h2; g1l.p[2] = h1m; g1l.p[3] = h2m;
  hipMemsetAsync(mug1, 0, 4 * 256 * 4, stream);
  hipMemsetAsync(ogs, 0, 4 * 256 * 4, stream);
  k_bmu_f<<<dim3(64, 4), 256, 0, stream>>>(g1l, mug1);
  k_bgv<<<dim3(4), 256, 0, stream>>>(mug1, W_read, g1);
  k_bsc_f<<<dim3(256, 4), 256, 0, stream>>>(g1l, g1, ogs);

  // ---- matches ----
  hipMemsetAsync(v, 0, 2048 * 4, stream);
  // order: [miu1g, phi1g, psi1g, om1, miu2g, phi2g, psi2g, om2]
  k_match_bf2<<<dim3(2, NN / 64), 256, 0, stream>>>(h1, h1m, 0, 0, W2t, mb0);
  k_match_bf2<<<dim3(2, NN / 64), 256, 0, stream>>>(h1, h1mg, 0, 1, W2t, mb1);
  k_match_bf2<<<dim3(2, NN / 64), 256, 0, stream>>>(h1g, h1m, 1, 0, W2t, mb2);
  k_match_bf2<<<dim3(2, NN / 64), 256, 0, stream>>>(h2, h2m, 0, 0, W2t, mb3);
  k_match_bf2<<<dim3(2, NN / 64), 256, 0, stream>>>(h2, h2mg, 0, 1, W2t, mb4);
  k_match_bf2<<<dim3(2, NN / 64), 256, 0, stream>>>(h2g, h2m, 1, 0, W2t, mb5);
  k_match<<<dim3(DDIM / 64, 1), 256, 0, stream>>>(h1g, h1mg, W2, v + 768, 1, 1, 1);
  k_match<<<dim3(DDIM / 64, 1), 256, 0, stream>>>(h2g, h2mg, W2, v + 1792, 1, 1, 1);

  // ---- readout group 2: 6 bf16 match outputs -> v slots ----
  PLB g2l;
  g2l.p[0] = mb0; g2l.slot[0] = 0;
  g2l.p[1] = mb1; g2l.slot[1] = 256;
  g2l.p[2] = mb2; g2l.slot[2] = 512;
  g2l.p[3] = mb3; g2l.slot[3] = 1024;
  g2l.p[4] = mb4; g2l.slot[4] = 1280;
  g2l.p[5] = mb5; g2l.slot[5] = 1536;
  hipMemsetAsync(mug2, 0, 6 * 256 * 4, stream);
  k_bmu_b<<<dim3(64, 6), 256, 0, stream>>>(g2l, mug2);
  k_bgv<<<dim3(6), 256, 0, stream>>>(mug2, W_read, g2);
  k_bsc_b<<<dim3(256, 6), 256, 0, stream>>>(g2l, g2, v);

  // ---- MLP ----
  k_mlp<<<dim3(2), 256, 0, stream>>>(v, w1, b1, l1o, 2048, 512, 1);
  k_mlp<<<dim3(1), 256, 0, stream>>>(l1o, w2, b2, l2o, 512, 256, 1);
  k_mlp<<<dim3(1), 256, 0, stream>>>(l2o, w3, b3, l3o, 256, 128, 1);
  k_final<<<1, 128, 0, stream>>>(l3o, w4, b4, label, out);
}

// Round 5
// 1039.222 us; speedup vs baseline: 6.3946x; 1.2671x over previous
//
#include <hip/hip_runtime.h>
#include <hip/hip_bf16.h>
#include <math.h>
#include <stddef.h>

#define NN 8192
#define FF 128
#define HH 512
#define DDIM 256
#define EE 131072
#define ET (2*EE + NN)     // 270336 edges after symmetrize + self loops
#define FEPS 1e-8f

typedef float f32x4 __attribute__((ext_vector_type(4)));
typedef __bf16 bf16x8 __attribute__((ext_vector_type(8)));
typedef unsigned short u16;

static __device__ __forceinline__ u16 f2bf(float f) {
  union { float f; unsigned u; } v; v.f = f;
  return (u16)((v.u + 0x7fffu + ((v.u >> 16) & 1u)) >> 16);
}
static __device__ __forceinline__ float bf2f(u16 h) {
  union { unsigned u; float f; } v; v.u = ((unsigned)h) << 16;
  return v.f;
}
static __device__ __forceinline__ f32x4 mfma16(bf16x8 a, bf16x8 b, f32x4 c) {
  return __builtin_amdgcn_mfma_f32_16x16x32_bf16(a, b, c, 0, 0, 0);
}
// async global->LDS, 16B per lane.
static __device__ __forceinline__ void gload16(const void* g, void* lds) {
  __builtin_amdgcn_global_load_lds(
      (const __attribute__((address_space(1))) void*)(unsigned long long)(uintptr_t)g,
      (__attribute__((address_space(3))) void*)(unsigned int)(uintptr_t)lds,
      16, 0, 0);
}

struct PLF { const float* p[4]; };
struct PLB { const u16* p[6]; int slot[6]; };

// ======================= stage 0: global mean/std normalize =======================
__global__ void k_reduce(const float* __restrict__ x, int n, double* __restrict__ out) {
  __shared__ double s1[256], s2[256];
  double a = 0.0, b = 0.0;
  for (int i = blockIdx.x * blockDim.x + threadIdx.x; i < n; i += gridDim.x * blockDim.x) {
    double v = (double)x[i];
    a += v; b += v * v;
  }
  s1[threadIdx.x] = a; s2[threadIdx.x] = b;
  __syncthreads();
  for (int w = 128; w > 0; w >>= 1) {
    if (threadIdx.x < w) { s1[threadIdx.x] += s1[threadIdx.x + w]; s2[threadIdx.x] += s2[threadIdx.x + w]; }
    __syncthreads();
  }
  if (threadIdx.x == 0) { atomicAdd(&out[0], s1[0]); atomicAdd(&out[1], s2[0]); }
}

__global__ void k_normalize(const float* __restrict__ x, u16* __restrict__ y, int n,
                            const double* __restrict__ s) {
  double mean = s[0] / (double)n;
  double var = (s[1] - (double)n * mean * mean) / (double)(n - 1);  // ddof=1
  float mu = (float)mean;
  float inv = (float)(1.0 / sqrt(var));
  for (int i = blockIdx.x * blockDim.x + threadIdx.x; i < n; i += gridDim.x * blockDim.x)
    y[i] = f2bf((x[i] - mu) * inv);
}

// ======================= GAT: CSR build =======================
__global__ void k_hist(const int* __restrict__ ei, int* __restrict__ deg) {
  int t = blockIdx.x * blockDim.x + threadIdx.x;
  if (t >= ET) return;
  int dst = (t < EE) ? ei[EE + t] : ((t < 2*EE) ? ei[t - EE] : (t - 2*EE));
  atomicAdd(&deg[dst], 1);
}

__global__ void k_scan(const int* __restrict__ deg, int* __restrict__ offs, int* __restrict__ cursor) {
  __shared__ int ts[256];
  int tid = threadIdx.x;
  int loc[32];
  int s = 0;
  #pragma unroll
  for (int i = 0; i < 32; ++i) { loc[i] = s; s += deg[tid * 32 + i]; }
  ts[tid] = s;
  __syncthreads();
  for (int off = 1; off < 256; off <<= 1) {
    int v = (tid >= off) ? ts[tid - off] : 0;
    __syncthreads();
    ts[tid] += v;
    __syncthreads();
  }
  int pre = ts[tid] - s;
  #pragma unroll
  for (int i = 0; i < 32; ++i) {
    int o = pre + loc[i];
    offs[tid * 32 + i] = o;
    cursor[tid * 32 + i] = o;
  }
  if (tid == 255) offs[NN] = ts[255];
}

__global__ void k_scatter(const int* __restrict__ ei, int* __restrict__ cursor, int* __restrict__ srcs) {
  int t = blockIdx.x * blockDim.x + threadIdx.x;
  if (t >= ET) return;
  int src = (t < 2*EE) ? ei[t] : (t - 2*EE);
  int dst = (t < EE) ? ei[EE + t] : ((t < 2*EE) ? ei[t - EE] : (t - 2*EE));
  int pos = atomicAdd(&cursor[dst], 1);
  srcs[pos] = src;
}

// ======================= transpose f32 -> bf16 (optionally squared) =======================
__global__ __launch_bounds__(256) void k_tr_bf16(const float* __restrict__ src, u16* __restrict__ dst,
                                                 int R, int C, int sq) {
  __shared__ float T[32][33];
  int tx = threadIdx.x & 31, ty = threadIdx.x >> 5;
  int r0 = blockIdx.y * 32, c0 = blockIdx.x * 32;
  #pragma unroll
  for (int p = 0; p < 4; ++p)
    T[ty + 8 * p][tx] = src[(size_t)(r0 + ty + 8 * p) * C + c0 + tx];
  __syncthreads();
  #pragma unroll
  for (int p = 0; p < 4; ++p) {
    float v = T[tx][ty + 8 * p];
    if (sq) v *= v;
    dst[(size_t)(c0 + ty + 8 * p) * R + r0 + tx] = f2bf(v);
  }
}

// ======================= generic MFMA GEMM: C[M,N] = A[M,K] @ Bt[N,K]^T =======================
__global__ __launch_bounds__(256) void k_gemm_bf(const u16* __restrict__ A, const u16* __restrict__ Bt,
                                                 float* __restrict__ Cf, u16* __restrict__ Cb,
                                                 int K, int N) {
  int w = threadIdx.x >> 6, l = threadIdx.x & 63, r15 = l & 15, g = l >> 4;
  int i0 = blockIdx.y * 64 + w * 16;
  int n0 = blockIdx.x * 128;
  f32x4 zero = {0.f, 0.f, 0.f, 0.f};
  f32x4 acc[8];
  #pragma unroll
  for (int n = 0; n < 8; ++n) acc[n] = zero;
  int kcN = K >> 5;
  const u16* arow = A + (size_t)(i0 + r15) * K + g * 8;
  for (int kc = 0; kc < kcN; ++kc) {
    bf16x8 a = *reinterpret_cast<const bf16x8*>(arow + kc * 32);
    #pragma unroll
    for (int n = 0; n < 8; ++n) {
      bf16x8 b = *reinterpret_cast<const bf16x8*>(Bt + (size_t)(n0 + n * 16 + r15) * K + kc * 32 + g * 8);
      acc[n] = mfma16(a, b, acc[n]);
    }
  }
  int io = i0 + g * 4;
  #pragma unroll
  for (int n = 0; n < 8; ++n) {
    int c = n0 + n * 16 + r15;
    #pragma unroll
    for (int q = 0; q < 4; ++q) {
      float vv = acc[n][q];
      if (Cf) Cf[(size_t)(io + q) * N + c] = vv;
      Cb[(size_t)(io + q) * N + c] = f2bf(vv);
    }
  }
}

// ======================= GAT: attention =======================
__global__ void k_node_dots_bf(const u16* __restrict__ Hb, const float* __restrict__ as_,
                               const float* __restrict__ ad_, float* __restrict__ hs,
                               float* __restrict__ hd, int D) {
  int wid = (blockIdx.x * blockDim.x + threadIdx.x) >> 6;
  int lane = threadIdx.x & 63;
  if (wid >= NN) return;
  float s = 0.f, d = 0.f;
  if (D == 512) {
    const u16* row = Hb + (size_t)wid * 512 + lane * 8;
    ushort4 v0 = *reinterpret_cast<const ushort4*>(row);
    ushort4 v1 = *reinterpret_cast<const ushort4*>(row + 4);
    const float4* ap = reinterpret_cast<const float4*>(as_ + lane * 8);
    const float4* dp = reinterpret_cast<const float4*>(ad_ + lane * 8);
    float4 a0 = ap[0], a1 = ap[1], e0 = dp[0], e1 = dp[1];
    float h0 = bf2f(v0.x), h1 = bf2f(v0.y), h2 = bf2f(v0.z), h3 = bf2f(v0.w);
    float h4 = bf2f(v1.x), h5 = bf2f(v1.y), h6 = bf2f(v1.z), h7 = bf2f(v1.w);
    s = h0*a0.x + h1*a0.y + h2*a0.z + h3*a0.w + h4*a1.x + h5*a1.y + h6*a1.z + h7*a1.w;
    d = h0*e0.x + h1*e0.y + h2*e0.z + h3*e0.w + h4*e1.x + h5*e1.y + h6*e1.z + h7*e1.w;
  } else {
    const u16* row = Hb + (size_t)wid * 256 + lane * 4;
    ushort4 v0 = *reinterpret_cast<const ushort4*>(row);
    float4 a0 = *reinterpret_cast<const float4*>(as_ + lane * 4);
    float4 e0 = *reinterpret_cast<const float4*>(ad_ + lane * 4);
    float h0 = bf2f(v0.x), h1 = bf2f(v0.y), h2 = bf2f(v0.z), h3 = bf2f(v0.w);
    s = h0*a0.x + h1*a0.y + h2*a0.z + h3*a0.w;
    d = h0*e0.x + h1*e0.y + h2*e0.z + h3*e0.w;
  }
  #pragma unroll
  for (int o = 32; o > 0; o >>= 1) { s += __shfl_xor(s, o); d += __shfl_xor(d, o); }
  if (!lane) { hs[wid] = s; hd[wid] = d; }
}

__global__ void k_alpha(const int* __restrict__ offs, const int* __restrict__ srcs,
                        const float* __restrict__ hs, const float* __restrict__ hd,
                        float* __restrict__ alpha) {
  int wid = (blockIdx.x * blockDim.x + threadIdx.x) >> 6;
  int lane = threadIdx.x & 63;
  if (wid >= NN) return;
  int b = offs[wid], e = offs[wid + 1];
  float hdn = hd[wid];
  float m = -3.4e38f;
  for (int p = b + lane; p < e; p += 64) {
    float v = hs[srcs[p]] + hdn;
    v = v > 0.f ? v : 0.2f * v;        // leaky_relu 0.2
    alpha[p] = v;
    m = fmaxf(m, v);
  }
  #pragma unroll
  for (int o = 32; o > 0; o >>= 1) m = fmaxf(m, __shfl_xor(m, o));
  float den = 0.f;
  for (int p = b + lane; p < e; p += 64) {
    float ex = expf(alpha[p] - m);
    alpha[p] = ex;
    den += ex;
  }
  #pragma unroll
  for (int o = 32; o > 0; o >>= 1) den += __shfl_xor(den, o);
  float sc = 1.f / (den + 1e-16f);
  for (int p = b + lane; p < e; p += 64) alpha[p] *= sc;
}

// wave-per-edge aggregate with 16B vector gathers; 4-wave LDS reduce
__global__ __launch_bounds__(256) void k_agg2(const int* __restrict__ offs, const int* __restrict__ srcs,
                                              const float* __restrict__ alpha, const u16* __restrict__ Hb,
                                              float* __restrict__ outF, u16* __restrict__ outB,
                                              int D, int elu) {
  __shared__ float red[4][512];
  int n = blockIdx.x;
  int b = offs[n], e = offs[n + 1];
  int w = threadIdx.x >> 6, lane = threadIdx.x & 63;
  float acc[8];
  #pragma unroll
  for (int j = 0; j < 8; ++j) acc[j] = 0.f;
  if (D == 512) {
    const u16* base = Hb + lane * 8;
    for (int p = b + w; p < e; p += 4) {
      float a = alpha[p];
      const u16* row = base + (size_t)srcs[p] * 512;
      ushort4 v0 = *reinterpret_cast<const ushort4*>(row);
      ushort4 v1 = *reinterpret_cast<const ushort4*>(row + 4);
      acc[0] += a * bf2f(v0.x); acc[1] += a * bf2f(v0.y);
      acc[2] += a * bf2f(v0.z); acc[3] += a * bf2f(v0.w);
      acc[4] += a * bf2f(v1.x); acc[5] += a * bf2f(v1.y);
      acc[6] += a * bf2f(v1.z); acc[7] += a * bf2f(v1.w);
    }
    #pragma unroll
    for (int j = 0; j < 8; ++j) red[w][lane * 8 + j] = acc[j];
  } else {
    const u16* base = Hb + lane * 4;
    for (int p = b + w; p < e; p += 4) {
      float a = alpha[p];
      const u16* row = base + (size_t)srcs[p] * 256;
      ushort4 v0 = *reinterpret_cast<const ushort4*>(row);
      acc[0] += a * bf2f(v0.x); acc[1] += a * bf2f(v0.y);
      acc[2] += a * bf2f(v0.z); acc[3] += a * bf2f(v0.w);
    }
    #pragma unroll
    for (int j = 0; j < 4; ++j) red[w][lane * 4 + j] = acc[j];
  }
  __syncthreads();
  for (int dd = threadIdx.x; dd < D; dd += 256) {
    float sres = red[0][dd] + red[1][dd] + red[2][dd] + red[3][dd];
    if (elu) sres = sres > 0.f ? sres : (expf(sres) - 1.f);
    if (outF) outF[(size_t)n * D + dd] = sres;
    outB[(size_t)n * D + dd] = f2bf(sres);
  }
}

// ======================= mutual: inverse row norms =======================
__global__ void k_rninv(const float* __restrict__ h, float* __restrict__ nrinv) {
  int wid = (blockIdx.x * blockDim.x + threadIdx.x) >> 6;
  int lane = threadIdx.x & 63;
  if (wid >= NN) return;
  float4 v = *reinterpret_cast<const float4*>(h + (size_t)wid * DDIM + lane * 4);
  float a = v.x * v.x + v.y * v.y + v.z * v.z + v.w * v.w;
  #pragma unroll
  for (int o = 32; o > 0; o >>= 1) a += __shfl_xor(a, o);
  if (!lane) nrinv[wid] = 1.f / sqrtf(a);
}

// ======================= mutual sums: R[i]=sum_j cos, S[j]=sum_i cos =======================
__global__ __launch_bounds__(256, 2) void k_sums_bf(const u16* __restrict__ Ab, const u16* __restrict__ Bb,
                                                    const float* __restrict__ nainv, const float* __restrict__ nbinv,
                                                    float* __restrict__ R, float* __restrict__ S) {
  __shared__ uint4 Bs2[2][2048];
  __shared__ float Scol[2048];
  int tid = threadIdx.x;
  int w = tid >> 6, l = tid & 63, r15 = l & 15, g = l >> 4;
  int i0 = blockIdx.y * 64;
  int jc0 = blockIdx.x * 2048;
  for (int s = tid; s < 2048; s += 256) Scol[s] = 0.f;
  bf16x8 qf[8];
  const u16* arow = Ab + (size_t)(i0 + w * 16 + r15) * 256 + g * 8;
  #pragma unroll
  for (int kc = 0; kc < 8; ++kc) qf[kc] = *reinterpret_cast<const bf16x8*>(arow + kc * 32);
  float ni[4];
  #pragma unroll
  for (int q = 0; q < 4; ++q) ni[q] = nainv[i0 + w * 16 + g * 4 + q];
  int offS[8];
  #pragma unroll
  for (int p = 0; p < 8; ++p) {
    int c = p * 256 + tid;
    int frag = c >> 6, n = frag >> 3, kc = frag & 7;
    int ll = c & 63, gg = ll >> 4, jr = ll & 15;
    offS[p] = (n * 16 + jr) * 256 + kc * 32 + gg * 8;
  }
  auto stage = [&](int buf, int j0) {
    const u16* bs = Bb + (size_t)j0 * 256;
    #pragma unroll
    for (int p = 0; p < 8; ++p)
      gload16(bs + offS[p], &Bs2[buf][p * 256 + tid]);
  };
  float rowacc[4] = {0.f, 0.f, 0.f, 0.f};
  f32x4 zero = {0.f, 0.f, 0.f, 0.f};
  stage(0, jc0);
  __syncthreads();
  int cur = 0;
  for (int t = 0; t < 32; ++t) {
    if (t < 31) stage(cur ^ 1, jc0 + (t + 1) * 64);
    int j0 = jc0 + t * 64;
    f32x4 sacc[4];
    #pragma unroll
    for (int n = 0; n < 4; ++n) sacc[n] = zero;
    #pragma unroll
    for (int kc = 0; kc < 8; ++kc)
      #pragma unroll
      for (int n = 0; n < 4; ++n) {
        bf16x8 b = *reinterpret_cast<const bf16x8*>(&Bs2[cur][(n * 8 + kc) * 64 + l]);
        sacc[n] = mfma16(qf[kc], b, sacc[n]);
      }
    #pragma unroll
    for (int n = 0; n < 4; ++n) {
      float nb = nbinv[j0 + n * 16 + r15];
      float cs = 0.f;
      #pragma unroll
      for (int q = 0; q < 4; ++q) {
        float cv = sacc[n][q] * ni[q] * nb;
        rowacc[q] += cv;
        cs += cv;
      }
      cs += __shfl_xor(cs, 16);
      cs += __shfl_xor(cs, 32);
      if (l < 16) atomicAdd(&Scol[t * 64 + n * 16 + l], cs);
    }
    __syncthreads();
    cur ^= 1;
  }
  #pragma unroll
  for (int q = 0; q < 4; ++q) {
    float v = rowacc[q];
    v += __shfl_xor(v, 1); v += __shfl_xor(v, 2); v += __shfl_xor(v, 4); v += __shfl_xor(v, 8);
    if (r15 == 0) atomicAdd(&R[i0 + w * 16 + g * 4 + q], v);
  }
  for (int s = tid; s < 2048; s += 256) atomicAdd(&S[jc0 + s], Scol[s]);
}

__global__ void k_scj(const float* __restrict__ S, const float* __restrict__ R,
                      const float* __restrict__ n1inv, const float* __restrict__ n2inv,
                      float* __restrict__ scj1, float* __restrict__ scj2) {
  int j = blockIdx.x * blockDim.x + threadIdx.x;
  if (j >= NN) return;
  scj1[j] = n2inv[j] / S[j];
  scj2[j] = n1inv[j] / R[j];
}

// ======================= mutual apply (flash, MFMA, gload_lds dbuf, 32-row j-tiles, 2 blk/CU) =======================
// Out[i,:] += sum_j (dot(A_i,B_j)*nainv[i]*scj[j]) * B[j,:].  grid (4, 128), block 256.
__global__ __launch_bounds__(256, 2) void k_apply_bf(const u16* __restrict__ Ab, const u16* __restrict__ Bb,
                                                     const u16* __restrict__ Btg, const float* __restrict__ nainv,
                                                     const float* __restrict__ scj, float* __restrict__ Out) {
  __shared__ uint4 Bs2[2][1024];              // S-orientation frags (B[j][k]), 16KB/buf
  __shared__ uint4 Bt2[2][1024];              // PV-orientation frags (B^T), 16KB/buf
  __shared__ __align__(16) u16 Ps[4 * 16 * 36];  // per-wave P tile 16x32 (pad 36)
  int tid = threadIdx.x;
  int w = tid >> 6, l = tid & 63, r15 = l & 15, g = l >> 4;
  int i0 = blockIdx.y * 64;
  int jc0 = blockIdx.x * 2048;
  bf16x8 qf[8];
  const u16* arow = Ab + (size_t)(i0 + w * 16 + r15) * 256 + g * 8;
  #pragma unroll
  for (int kc = 0; kc < 8; ++kc) qf[kc] = *reinterpret_cast<const bf16x8*>(arow + kc * 32);
  float ni[4];
  #pragma unroll
  for (int q = 0; q < 4; ++q) ni[q] = nainv[i0 + w * 16 + g * 4 + q];
  int offS[4], offT[4];
  #pragma unroll
  for (int p = 0; p < 4; ++p) {
    int c = p * 256 + tid;
    int ll = c & 63, gg = ll >> 4, jr = ll & 15;
    int frag = c >> 6;                  // 0..15
    int n = frag >> 3, kc = frag & 7;   // Bs: 2 j-subtiles x 8 kc
    offS[p] = (n * 16 + jr) * 256 + kc * 32 + gg * 8;
    offT[p] = (frag * 16 + jr) * NN + gg * 8;   // Bt: 16 d-subtiles, k=j (32 wide)
  }
  auto stage = [&](int buf, int j0) {
    const u16* bs = Bb + (size_t)j0 * 256;
    const u16* ts = Btg + (size_t)j0;
    #pragma unroll
    for (int p = 0; p < 4; ++p) {
      gload16(bs + offS[p], &Bs2[buf][p * 256 + tid]);
      gload16(ts + offT[p], &Bt2[buf][p * 256 + tid]);
    }
  };
  f32x4 zero = {0.f, 0.f, 0.f, 0.f};
  f32x4 oacc[16];
  #pragma unroll
  for (int n = 0; n < 16; ++n) oacc[n] = zero;
  u16* PsW = Ps + w * 16 * 36;
  stage(0, jc0);
  __syncthreads();
  int cur = 0;
  for (int t = 0; t < 64; ++t) {
    if (t < 63) stage(cur ^ 1, jc0 + (t + 1) * 32);   // in flight during compute
    int j0 = jc0 + t * 32;
    // QK: scores for this wave's 16 rows x 32 j
    f32x4 sacc[2];
    sacc[0] = zero; sacc[1] = zero;
    #pragma unroll
    for (int kc = 0; kc < 8; ++kc)
      #pragma unroll
      for (int n = 0; n < 2; ++n) {
        bf16x8 b = *reinterpret_cast<const bf16x8*>(&Bs2[cur][(n * 8 + kc) * 64 + l]);
        sacc[n] = mfma16(qf[kc], b, sacc[n]);
      }
    // scale -> per-wave P tile (bf16) in LDS
    #pragma unroll
    for (int n = 0; n < 2; ++n) {
      float sc = scj[j0 + n * 16 + r15];
      #pragma unroll
      for (int q = 0; q < 4; ++q) {
        float val = sacc[n][q] * ni[q] * sc;
        PsW[(g * 4 + q) * 36 + n * 16 + r15] = f2bf(val);
      }
    }
    // PV: oacc[i, d] += P[i, j] * B[j, d]   (single K=32 step)
    {
      bf16x8 pa = *reinterpret_cast<const bf16x8*>(PsW + r15 * 36 + g * 8);
      #pragma unroll
      for (int n2 = 0; n2 < 16; ++n2) {
        bf16x8 b = *reinterpret_cast<const bf16x8*>(&Bt2[cur][n2 * 64 + l]);
        oacc[n2] = mfma16(pa, b, oacc[n2]);
      }
    }
    __syncthreads();   // drains vmcnt: next buffer staged & all reads of cur done
    cur ^= 1;
  }
  int io = i0 + w * 16 + g * 4;
  #pragma unroll
  for (int n2 = 0; n2 < 16; ++n2) {
    int c = n2 * 16 + r15;
    #pragma unroll
    for (int q = 0; q < 4; ++q)
      atomicAdd(&Out[(size_t)(io + q) * 256 + c], oacc[n2][q]);
  }
}

// ======================= match (fused prep, MFMA, bf16 out) =======================
__global__ __launch_bounds__(256) void k_match_bf2(const float* __restrict__ X, const float* __restrict__ Y,
                                                   int bx, int by, const u16* __restrict__ W2t,
                                                   u16* __restrict__ outb) {
  int w = threadIdx.x >> 6, l = threadIdx.x & 63, r15 = l & 15, g = l >> 4;
  int i0 = blockIdx.y * 64 + w * 16;
  int n0 = blockIdx.x * 128;
  f32x4 zero = {0.f, 0.f, 0.f, 0.f};
  f32x4 aU[8], aP[8], aQ[8];
  #pragma unroll
  for (int n = 0; n < 8; ++n) { aU[n] = zero; aP[n] = zero; aQ[n] = zero; }
  int row = i0 + r15;
  const float* xr = X + (size_t)(bx ? 0 : row) * 256;
  const float* yr = Y + (size_t)(by ? 0 : row) * 256;
  #pragma unroll 2
  for (int kc = 0; kc < 8; ++kc) {
    int base = kc * 32 + g * 8;
    float4 x0 = *reinterpret_cast<const float4*>(xr + base);
    float4 x1 = *reinterpret_cast<const float4*>(xr + base + 4);
    float4 y0 = *reinterpret_cast<const float4*>(yr + base);
    float4 y1 = *reinterpret_cast<const float4*>(yr + base + 4);
    bf16x8 fu, fp, fq;
    fu[0] = (__bf16)(x0.x * y0.x); fu[1] = (__bf16)(x0.y * y0.y);
    fu[2] = (__bf16)(x0.z * y0.z); fu[3] = (__bf16)(x0.w * y0.w);
    fu[4] = (__bf16)(x1.x * y1.x); fu[5] = (__bf16)(x1.y * y1.y);
    fu[6] = (__bf16)(x1.z * y1.z); fu[7] = (__bf16)(x1.w * y1.w);
    fp[0] = (__bf16)(x0.x * x0.x); fp[1] = (__bf16)(x0.y * x0.y);
    fp[2] = (__bf16)(x0.z * x0.z); fp[3] = (__bf16)(x0.w * x0.w);
    fp[4] = (__bf16)(x1.x * x1.x); fp[5] = (__bf16)(x1.y * x1.y);
    fp[6] = (__bf16)(x1.z * x1.z); fp[7] = (__bf16)(x1.w * x1.w);
    fq[0] = (__bf16)(y0.x * y0.x); fq[1] = (__bf16)(y0.y * y0.y);
    fq[2] = (__bf16)(y0.z * y0.z); fq[3] = (__bf16)(y0.w * y0.w);
    fq[4] = (__bf16)(y1.x * y1.x); fq[5] = (__bf16)(y1.y * y1.y);
    fq[6] = (__bf16)(y1.z * y1.z); fq[7] = (__bf16)(y1.w * y1.w);
    #pragma unroll
    for (int n = 0; n < 8; ++n) {
      bf16x8 b = *reinterpret_cast<const bf16x8*>(W2t + (size_t)(n0 + n * 16 + r15) * 256 + kc * 32 + g * 8);
      aU[n] = mfma16(fu, b, aU[n]);
      aP[n] = mfma16(fp, b, aP[n]);
      aQ[n] = mfma16(fq, b, aQ[n]);
    }
  }
  int io = i0 + g * 4;
  #pragma unroll
  for (int n = 0; n < 8; ++n) {
    int c = n0 + n * 16 + r15;
    #pragma unroll
    for (int q = 0; q < 4; ++q) {
      float s = sqrtf(aP[n][q]) * sqrtf(aQ[n][q]);
      outb[(size_t)(io + q) * 256 + c] = f2bf(aU[n][q] / fmaxf(s, FEPS));
    }
  }
}

// ======================= old f32 match (nout==1 only) =======================
__global__ __launch_bounds__(256) void k_match(const float* __restrict__ X, const float* __restrict__ Y,
                                               const float* __restrict__ W2, float* __restrict__ out,
                                               int nout, int bx, int by) {
  __shared__ float u[4][256], p[4][256], q[4][256];
  int nl = threadIdx.x >> 6;
  int ml = threadIdx.x & 63;
  int n = blockIdx.y * 4 + nl;
  int m = blockIdx.x * 64 + ml;
  for (int li = threadIdx.x; li < 4 * 256; li += 256) {
    int rr = li >> 8, dd = li & 255;
    int nn2 = blockIdx.y * 4 + rr;
    if (nn2 < nout) {
      float xv = X[(size_t)(bx ? 0 : nn2) * DDIM + dd];
      float yv = Y[(size_t)(by ? 0 : nn2) * DDIM + dd];
      u[rr][dd] = xv * yv; p[rr][dd] = xv * xv; q[rr][dd] = yv * yv;
    }
  }
  __syncthreads();
  if (n >= nout) return;
  float a = 0.f, b = 0.f, c = 0.f;
  #pragma unroll 4
  for (int d = 0; d < 256; ++d) {
    float wv = W2[(size_t)d * DDIM + m];
    a += u[nl][d] * wv; b += p[nl][d] * wv; c += q[nl][d] * wv;
  }
  out[(size_t)n * DDIM + m] = a / fmaxf(sqrtf(b) * sqrtf(c), FEPS);
}

__global__ void k_w2(const float* __restrict__ Wm, float* __restrict__ W2, int n) {
  int i = blockIdx.x * blockDim.x + threadIdx.x;
  if (i < n) { float v = Wm[i]; W2[i] = v * v; }
}

// ======================= batched readouts =======================
__global__ void k_bmu_f(PLF L, float* __restrict__ mu) {
  const float* h = L.p[blockIdx.y];
  int d = threadIdx.x;
  int r0 = blockIdx.x * 128;
  float acc = 0.f;
  for (int r = 0; r < 128; ++r) acc += h[(size_t)(r0 + r) * 256 + d];
  atomicAdd(&mu[blockIdx.y * 256 + d], acc);
}

__global__ void k_bmu_b(PLB L, float* __restrict__ mu) {
  const u16* h = L.p[blockIdx.y];
  int d = threadIdx.x;
  int r0 = blockIdx.x * 128;
  float acc = 0.f;
  for (int r = 0; r < 128; ++r) acc += bf2f(h[(size_t)(r0 + r) * 256 + d]);
  atomicAdd(&mu[blockIdx.y * 256 + d], acc);
}

__global__ void k_bgv(const float* __restrict__ mu, const float* __restrict__ Wr,
                      float* __restrict__ g) {
  __shared__ float ls[256];
  int m = blockIdx.x, t = threadIdx.x;
  ls[t] = mu[m * 256 + t] * (1.f / (float)NN);
  __syncthreads();
  float acc = 0.f;
  #pragma unroll 4
  for (int d = 0; d < 256; ++d) acc += ls[d] * Wr[(size_t)d * 256 + t];
  g[m * 256 + t] = tanhf(acc);
}

__global__ __launch_bounds__(256) void k_bsc_f(PLF L, const float* __restrict__ g,
                                               float* __restrict__ ogbase) {
  __shared__ __align__(16) float gs[256];
  __shared__ float sarr[32];
  int m = blockIdx.y;
  const float* h = L.p[m];
  int t = threadIdx.x, w = t >> 6, l = t & 63;
  gs[t] = g[m * 256 + t];
  __syncthreads();
  int r0 = blockIdx.x * 32;
  float4 gv4 = reinterpret_cast<const float4*>(gs)[l];
  for (int rr = w * 8; rr < w * 8 + 8; ++rr) {
    float4 hv = reinterpret_cast<const float4*>(h + (size_t)(r0 + rr) * 256)[l];
    float dot = hv.x * gv4.x + hv.y * gv4.y + hv.z * gv4.z + hv.w * gv4.w;
    #pragma unroll
    for (int o = 32; o > 0; o >>= 1) dot += __shfl_xor(dot, o);
    if (!l) sarr[rr] = 1.f / (1.f + expf(-dot));
  }
  __syncthreads();
  float acc = 0.f;
  for (int rr = 0; rr < 32; ++rr) acc += sarr[rr] * h[(size_t)(r0 + rr) * 256 + t];
  atomicAdd(&ogbase[m * 256 + t], acc);
}

__global__ __launch_bounds__(256) void k_bsc_b(PLB L, const float* __restrict__ g,
                                               float* __restrict__ v) {
  __shared__ __align__(16) float gs[256];
  __shared__ float sarr[32];
  int m = blockIdx.y;
  const u16* h = L.p[m];
  int t = threadIdx.x, w = t >> 6, l = t & 63;
  gs[t] = g[m * 256 + t];
  __syncthreads();
  int r0 = blockIdx.x * 32;
  float4 gv4 = reinterpret_cast<const float4*>(gs)[l];
  for (int rr = w * 8; rr < w * 8 + 8; ++rr) {
    ushort4 hv = *reinterpret_cast<const ushort4*>(h + (size_t)(r0 + rr) * 256 + l * 4);
    float dot = bf2f(hv.x) * gv4.x + bf2f(hv.y) * gv4.y + bf2f(hv.z) * gv4.z + bf2f(hv.w) * gv4.w;
    #pragma unroll
    for (int o = 32; o > 0; o >>= 1) dot += __shfl_xor(dot, o);
    if (!l) sarr[rr] = 1.f / (1.f + expf(-dot));
  }
  __syncthreads();
  float acc = 0.f;
  for (int rr = 0; rr < 32; ++rr) acc += sarr[rr] * bf2f(h[(size_t)(r0 + rr) * 256 + t]);
  atomicAdd(&v[L.slot[m] + t], acc);
}

// ======================= MLP (split-K parallel GEMV) =======================
__global__ void k_binit(const float* __restrict__ b1, const float* __restrict__ b2,
                        const float* __restrict__ b3, float* __restrict__ l1,
                        float* __restrict__ l2, float* __restrict__ l3) {
  int t = blockIdx.x * 256 + threadIdx.x;
  if (t < 512) l1[t] = b1[t];
  if (t < 256) l2[t] = b2[t];
  if (t < 128) l3[t] = b3[t];
}

// out[m] += sum_{k in chunk} act(v[k]) * w[k*M+m]; grid (ceil(M/256), KS)
__global__ void k_gemv(const float* __restrict__ vin, const float* __restrict__ w,
                       float* __restrict__ out, int K, int M, int Kc, int relu_in) {
  int m = blockIdx.x * 256 + threadIdx.x;
  if (m >= M) return;
  int k0 = blockIdx.y * Kc;
  float acc = 0.f;
  #pragma unroll 4
  for (int k = k0; k < k0 + Kc; ++k) {
    float x = vin[k];
    if (relu_in) x = fmaxf(x, 0.f);
    acc += x * w[(size_t)k * M + m];
  }
  atomicAdd(&out[m], acc);
}

__global__ void k_final(const float* __restrict__ l3, const float* __restrict__ w4,
                        const float* __restrict__ b4, const int* __restrict__ label,
                        float* __restrict__ out) {
  __shared__ float ls[128];
  int t = threadIdx.x;
  ls[t] = fmaxf(l3[t], 0.f) * w4[t];
  __syncthreads();
  for (int w = 64; w > 0; w >>= 1) { if (t < w) ls[t] += ls[t + w]; __syncthreads(); }
  if (t == 0) {
    float z = 1.f / (1.f + expf(-(ls[0] + b4[0])));
    out[0] = z;
    float lb = (float)label[0];
    out[1] = lb;
    out[2] = expf(-lb);
  }
}

// ======================= host =======================
extern "C" void kernel_launch(void* const* d_in, const int* in_sizes, int n_in,
                              void* d_out, int out_size, void* d_ws, size_t ws_size,
                              hipStream_t stream) {
  (void)in_sizes; (void)n_in; (void)out_size;
  const float* x_s   = (const float*)d_in[0];
  const float* x_t   = (const float*)d_in[1];
  const int*   ei_s  = (const int*)d_in[2];
  const int*   ei_t  = (const int*)d_in[3];
  const int*   label = (const int*)d_in[4];
  const float* W_g1  = (const float*)d_in[5];
  const float* a1s   = (const float*)d_in[6];
  const float* a1d   = (const float*)d_in[7];
  const float* W_g2  = (const float*)d_in[8];
  const float* a2s   = (const float*)d_in[9];
  const float* a2d   = (const float*)d_in[10];
  const float* W_read  = (const float*)d_in[11];
  const float* W_match = (const float*)d_in[12];
  const float* w1 = (const float*)d_in[13]; const float* b1 = (const float*)d_in[14];
  const float* w2 = (const float*)d_in[15]; const float* b2 = (const float*)d_in[16];
  const float* w3 = (const float*)d_in[17]; const float* b3 = (const float*)d_in[18];
  const float* w4 = (const float*)d_in[19]; const float* b4 = (const float*)d_in[20];
  float* out = (float*)d_out;

  char* base = (char*)d_ws;
  size_t off = 0;
  auto alloc = [&](size_t bytes) -> void* {
    void* pp = base + off;
    off = (off + bytes + 255) & ~(size_t)255;
    return pp;
  };
  double* dsum = (double*)alloc(4 * sizeof(double));
  u16*   hb_bf= (u16*)alloc((size_t)NN * HH * 2);
  u16*   aggb = (u16*)alloc((size_t)NN * HH * 2);
  float* h1   = (float*)alloc((size_t)NN * DDIM * 4);
  float* h2   = (float*)alloc((size_t)NN * DDIM * 4);
  float* h1m  = (float*)alloc((size_t)NN * DDIM * 4);
  float* h2m  = (float*)alloc((size_t)NN * DDIM * 4);
  u16*   f1b  = (u16*)alloc((size_t)NN * FF * 2);
  u16*   f2b  = (u16*)alloc((size_t)NN * FF * 2);
  u16*   h1b  = (u16*)alloc((size_t)NN * DDIM * 2);
  u16*   h2b  = (u16*)alloc((size_t)NN * DDIM * 2);
  u16*   h1t  = (u16*)alloc((size_t)NN * DDIM * 2);
  u16*   h2t  = (u16*)alloc((size_t)NN * DDIM * 2);
  u16*   mb0  = (u16*)alloc((size_t)NN * DDIM * 2);
  u16*   mb1  = (u16*)alloc((size_t)NN * DDIM * 2);
  u16*   mb2  = (u16*)alloc((size_t)NN * DDIM * 2);
  u16*   mb3  = (u16*)alloc((size_t)NN * DDIM * 2);
  u16*   mb4  = (u16*)alloc((size_t)NN * DDIM * 2);
  u16*   mb5  = (u16*)alloc((size_t)NN * DDIM * 2);
  float* alpha= (float*)alloc((size_t)ET * 4);
  int*   srcs = (int*)alloc((size_t)ET * 4);
  int*   deg  = (int*)alloc(NN * 4);
  int*   curs = (int*)alloc(NN * 4);
  int*   offs = (int*)alloc((NN + 1) * 4);
  float* n1inv= (float*)alloc(NN * 4);
  float* n2inv= (float*)alloc(NN * 4);
  float* Rr   = (float*)alloc(NN * 4);
  float* Ss   = (float*)alloc(NN * 4);
  float* scj1 = (float*)alloc(NN * 4);
  float* scj2 = (float*)alloc(NN * 4);
  float* hsb  = (float*)alloc(NN * 4);
  float* hdb  = (float*)alloc(NN * 4);
  float* W2   = (float*)alloc((size_t)DDIM * DDIM * 4);
  u16*   Wg1t = (u16*)alloc((size_t)HH * FF * 2);
  u16*   Wg2t = (u16*)alloc((size_t)DDIM * HH * 2);
  u16*   W2t  = (u16*)alloc((size_t)DDIM * DDIM * 2);
  float* mug1 = (float*)alloc(4 * 256 * 4);
  float* g1   = (float*)alloc(4 * 256 * 4);
  float* ogs  = (float*)alloc(4 * 256 * 4);
  float* mug2 = (float*)alloc(6 * 256 * 4);
  float* g2   = (float*)alloc(6 * 256 * 4);
  float* v    = (float*)alloc(2048 * 4);
  float* l1o  = (float*)alloc(512 * 4);
  float* l2o  = (float*)alloc(256 * 4);
  float* l3o  = (float*)alloc(128 * 4);
  if (off > ws_size) return;

  float* h1g  = ogs + 0;
  float* h2g  = ogs + 256;
  float* h1mg = ogs + 512;
  float* h2mg = ogs + 768;

  // ---- stage 0 ----
  hipMemsetAsync(dsum, 0, 4 * sizeof(double), stream);
  k_reduce<<<1024, 256, 0, stream>>>(x_s, NN * FF, dsum);
  k_reduce<<<1024, 256, 0, stream>>>(x_t, NN * FF, dsum + 2);
  k_normalize<<<1024, 256, 0, stream>>>(x_s, f1b, NN * FF, dsum);
  k_normalize<<<1024, 256, 0, stream>>>(x_t, f2b, NN * FF, dsum + 2);

  // ---- weight preps ----
  k_tr_bf16<<<dim3(HH / 32, FF / 32), 256, 0, stream>>>(W_g1, Wg1t, FF, HH, 0);
  k_tr_bf16<<<dim3(DDIM / 32, HH / 32), 256, 0, stream>>>(W_g2, Wg2t, HH, DDIM, 0);
  k_tr_bf16<<<dim3(DDIM / 32, DDIM / 32), 256, 0, stream>>>(W_match, W2t, DDIM, DDIM, 1);
  k_w2<<<dim3((DDIM * DDIM + 255) / 256), 256, 0, stream>>>(W_match, W2, DDIM * DDIM);

  // ---- GAT ----
  auto run_gat = [&](const u16* finb, const int* ei, float* hout, u16* houtb) {
    hipMemsetAsync(deg, 0, NN * 4, stream);
    k_hist<<<dim3((ET + 255) / 256), 256, 0, stream>>>(ei, deg);
    k_scan<<<1, 256, 0, stream>>>(deg, offs, curs);
    k_scatter<<<dim3((ET + 255) / 256), 256, 0, stream>>>(ei, curs, srcs);
    k_gemm_bf<<<dim3(HH / 128, NN / 64), 256, 0, stream>>>(finb, Wg1t, nullptr, hb_bf, FF, HH);
    k_node_dots_bf<<<dim3(NN / 4), 256, 0, stream>>>(hb_bf, a1s, a1d, hsb, hdb, HH);
    k_alpha<<<dim3(NN / 4), 256, 0, stream>>>(offs, srcs, hsb, hdb, alpha);
    k_agg2<<<dim3(NN), 256, 0, stream>>>(offs, srcs, alpha, hb_bf, nullptr, aggb, HH, 1);
    k_gemm_bf<<<dim3(DDIM / 128, NN / 64), 256, 0, stream>>>(aggb, Wg2t, nullptr, hb_bf, HH, DDIM);
    k_node_dots_bf<<<dim3(NN / 4), 256, 0, stream>>>(hb_bf, a2s, a2d, hsb, hdb, DDIM);
    k_alpha<<<dim3(NN / 4), 256, 0, stream>>>(offs, srcs, hsb, hdb, alpha);
    k_agg2<<<dim3(NN), 256, 0, stream>>>(offs, srcs, alpha, hb_bf, hout, houtb, DDIM, 0);
  };
  run_gat(f1b, ei_s, h1, h1b);
  run_gat(f2b, ei_t, h2, h2b);

  // ---- mutual ----
  k_rninv<<<dim3(NN / 4), 256, 0, stream>>>(h1, n1inv);
  k_rninv<<<dim3(NN / 4), 256, 0, stream>>>(h2, n2inv);
  k_tr_bf16<<<dim3(DDIM / 32, NN / 32), 256, 0, stream>>>(h1, h1t, NN, DDIM, 0);
  k_tr_bf16<<<dim3(DDIM / 32, NN / 32), 256, 0, stream>>>(h2, h2t, NN, DDIM, 0);
  hipMemsetAsync(Rr, 0, NN * 4, stream);
  hipMemsetAsync(Ss, 0, NN * 4, stream);
  k_sums_bf<<<dim3(4, NN / 64), 256, 0, stream>>>(h1b, h2b, n1inv, n2inv, Rr, Ss);
  k_scj<<<dim3(NN / 256), 256, 0, stream>>>(Ss, Rr, n1inv, n2inv, scj1, scj2);
  hipMemsetAsync(h1m, 0, (size_t)NN * DDIM * 4, stream);
  k_apply_bf<<<dim3(4, NN / 64), 256, 0, stream>>>(h1b, h2b, h2t, n1inv, scj1, h1m);
  hipMemsetAsync(h2m, 0, (size_t)NN * DDIM * 4, stream);
  k_apply_bf<<<dim3(4, NN / 64), 256, 0, stream>>>(h2b, h1b, h1t, n2inv, scj2, h2m);

  // ---- readout group 1: h1, h2, h1m, h2m ----
  PLF g1l; g1l.p[0] = h1; g1l.p[1] = h2; g1l.p[2] = h1m; g1l.p[3] = h2m;
  hipMemsetAsync(mug1, 0, 4 * 256 * 4, stream);
  hipMemsetAsync(ogs, 0, 4 * 256 * 4, stream);
  k_bmu_f<<<dim3(64, 4), 256, 0, stream>>>(g1l, mug1);
  k_bgv<<<dim3(4), 256, 0, stream>>>(mug1, W_read, g1);
  k_bsc_f<<<dim3(256, 4), 256, 0, stream>>>(g1l, g1, ogs);

  // ---- matches ----
  hipMemsetAsync(v, 0, 2048 * 4, stream);
  // order: [miu1g, phi1g, psi1g, om1, miu2g, phi2g, psi2g, om2]
  k_match_bf2<<<dim3(2, NN / 64), 256, 0, stream>>>(h1, h1m, 0, 0, W2t, mb0);
  k_match_bf2<<<dim3(2, NN / 64), 256, 0, stream>>>(h1, h1mg, 0, 1, W2t, mb1);
  k_match_bf2<<<dim3(2, NN / 64), 256, 0, stream>>>(h1g, h1m, 1, 0, W2t, mb2);
  k_match_bf2<<<dim3(2, NN / 64), 256, 0, stream>>>(h2, h2m, 0, 0, W2t, mb3);
  k_match_bf2<<<dim3(2, NN / 64), 256, 0, stream>>>(h2, h2mg, 0, 1, W2t, mb4);
  k_match_bf2<<<dim3(2, NN / 64), 256, 0, stream>>>(h2g, h2m, 1, 0, W2t, mb5);
  k_match<<<dim3(DDIM / 64, 1), 256, 0, stream>>>(h1g, h1mg, W2, v + 768, 1, 1, 1);
  k_match<<<dim3(DDIM / 64, 1), 256, 0, stream>>>(h2g, h2mg, W2, v + 1792, 1, 1, 1);

  // ---- readout group 2: 6 bf16 match outputs -> v slots ----
  PLB g2l;
  g2l.p[0] = mb0; g2l.slot[0] = 0;
  g2l.p[1] = mb1; g2l.slot[1] = 256;
  g2l.p[2] = mb2; g2l.slot[2] = 512;
  g2l.p[3] = mb3; g2l.slot[3] = 1024;
  g2l.p[4] = mb4; g2l.slot[4] = 1280;
  g2l.p[5] = mb5; g2l.slot[5] = 1536;
  hipMemsetAsync(mug2, 0, 6 * 256 * 4, stream);
  k_bmu_b<<<dim3(64, 6), 256, 0, stream>>>(g2l, mug2);
  k_bgv<<<dim3(6), 256, 0, stream>>>(mug2, W_read, g2);
  k_bsc_b<<<dim3(256, 6), 256, 0, stream>>>(g2l, g2, v);

  // ---- MLP (split-K gemv) ----
  k_binit<<<dim3(2), 256, 0, stream>>>(b1, b2, b3, l1o, l2o, l3o);
  k_gemv<<<dim3(2, 16), 256, 0, stream>>>(v, w1, l1o, 2048, 512, 128, 0);
  k_gemv<<<dim3(1, 8), 256, 0, stream>>>(l1o, w2, l2o, 512, 256, 64, 1);
  k_gemv<<<dim3(1, 8), 256, 0, stream>>>(l2o, w3, l3o, 256, 128, 32, 1);
  k_final<<<1, 128, 0, stream>>>(l3o, w4, b4, label, out);
}